// Round 7
// baseline (287.862 us; speedup 1.0000x reference)
//
#include <hip/hip_runtime.h>
#include <hip/hip_bf16.h>
#include <math.h>

// Transformer layer: B=2 S=2048 D=1024 H=16 HD=64 FF=4096, fp32 I/O.
// Heavy GEMMs: m97-style 128x128 bf16 MFMA tiles, >=3 blocks/CU via split-K,
// coalesced epilogues via LDS bounce. Attention: flash split-KV=2 + merge.

#define BB 2
#define SS 2048
#define DD 1024
#define HH 16
#define HDIM 64
#define FFD 4096
#define NTOK (BB*SS)
#define LOG2E 1.4426950408889634f

typedef __attribute__((ext_vector_type(8))) short bf16x8;
typedef __attribute__((ext_vector_type(4))) float f32x4;
typedef __attribute__((ext_vector_type(16))) float f32x16;
typedef __attribute__((ext_vector_type(4))) unsigned int u32x4;

#if __has_builtin(__builtin_amdgcn_exp2f)
#define EXP2(x) __builtin_amdgcn_exp2f(x)
#else
#define EXP2(x) exp2f(x)
#endif

__device__ __forceinline__ void gl_lds16(const void* g, void* l) {
  __builtin_amdgcn_global_load_lds(
      (const __attribute__((address_space(1))) unsigned int*)g,
      (__attribute__((address_space(3))) unsigned int*)l, 16, 0, 0);
}

// RNE float->bf16 bits (finite inputs only)
__device__ __forceinline__ short f2bf(float f) {
  unsigned int u = __builtin_bit_cast(unsigned int, f);
  unsigned int r = (u + 0x7fffu + ((u >> 16) & 1u)) >> 16;
  return (short)r;
}
__device__ __forceinline__ float bf2f(short s) {
  return __builtin_bit_cast(float, ((unsigned)(unsigned short)s) << 16);
}
// packed pair via HW cvt (RNE): lo in low 16, hi in high 16
__device__ __forceinline__ unsigned pk2(float lo, float hi) {
  unsigned r;
  asm("v_cvt_pk_bf16_f32 %0, %1, %2" : "=v"(r) : "v"(lo), "v"(hi));
  return r;
}

// ---------------- transpose + fp32->bf16 convert: wt[n][k] = bf16(w[k][n]) ----
__global__ __launch_bounds__(256) void convT(const float* __restrict__ w,
                                             __hip_bfloat16* __restrict__ wt,
                                             int K, int N) {
  __shared__ float tile[32][33];
  int k0 = blockIdx.y * 32, n0 = blockIdx.x * 32;
  int tx = threadIdx.x & 31, ty = threadIdx.x >> 5;
#pragma unroll
  for (int i = 0; i < 4; ++i) {
    int r = ty + i * 8;
    tile[r][tx] = w[(size_t)(k0 + r) * N + n0 + tx];
  }
  __syncthreads();
#pragma unroll
  for (int i = 0; i < 4; ++i) {
    int r = ty + i * 8;
    wt[(size_t)(n0 + r) * K + k0 + tx] = __float2bfloat16(tile[tx][r]);
  }
}

// ---------------- LayerNorm (fp32 in -> bf16 out), one wave per row ----------
__global__ __launch_bounds__(256) void ln_bf16(const float* __restrict__ x,
                                               const float* __restrict__ g,
                                               const float* __restrict__ be,
                                               __hip_bfloat16* __restrict__ out) {
  int w = threadIdx.x >> 6, lane = threadIdx.x & 63;
  int row = blockIdx.x * 4 + w;
  const float* xr = x + (size_t)row * DD;
  float4 v[4];
  float sum = 0.f, sq = 0.f;
#pragma unroll
  for (int i = 0; i < 4; ++i) {
    v[i] = *(const float4*)(xr + lane * 4 + i * 256);
    sum += v[i].x + v[i].y + v[i].z + v[i].w;
    sq += v[i].x * v[i].x + v[i].y * v[i].y + v[i].z * v[i].z + v[i].w * v[i].w;
  }
#pragma unroll
  for (int off = 1; off < 64; off <<= 1) {
    sum += __shfl_xor(sum, off);
    sq += __shfl_xor(sq, off);
  }
  float mu = sum * (1.f / 1024.f);
  float var = sq * (1.f / 1024.f) - mu * mu;
  float rs = rsqrtf(var + 1e-12f);
  __hip_bfloat16* orow = out + (size_t)row * DD;
#pragma unroll
  for (int i = 0; i < 4; ++i) {
    int c = lane * 4 + i * 256;
    float4 gg = *(const float4*)(g + c);
    float4 bb = *(const float4*)(be + c);
    short4 o;
    o.x = f2bf((v[i].x - mu) * rs * gg.x + bb.x);
    o.y = f2bf((v[i].y - mu) * rs * gg.y + bb.y);
    o.z = f2bf((v[i].z - mu) * rs * gg.z + bb.z);
    o.w = f2bf((v[i].w - mu) * rs * gg.w + bb.w);
    *(short4*)((short*)orow + c) = o;
  }
}

// ---------------- GEMM: C[M,N] = A[M,K] (bf16) * BT[N,K]^T + epilogue --------
// m97 structure: 128x128 tile, BK=32, 4 waves, gl_lds16 width 16.
// Epilogues bounce through LDS (272B-stride rows) for coalesced 16B stores.
// blockIdx.z = split-K slice.
// EPI 1: +bias, gelu-erf -> bf16                       [FF1]
// EPI 5: QKV fused (N=3072): Q,K +bias -> bf16; V +bias -> bf16 transposed
// EPI 7: raw -> bf16 partial @ C0 + z*4Mi elems        [O-proj split-K]
// EPI 8: raw -> bf16 partial @ C0 + {0,4Mi,12Mi} elems [FF2 split-K]
template <int EPI>
__global__ __launch_bounds__(256, 4) void gemm_bt(
    const __hip_bfloat16* __restrict__ A, const __hip_bfloat16* __restrict__ BT,
    const float* __restrict__ bA, const float* __restrict__ bB,
    const float* __restrict__ bC,
    void* __restrict__ C0, void* __restrict__ C1, void* __restrict__ C2,
    int M, int N, int K, int kSplit) {
  __shared__ __align__(16) char smem[34816];  // As@0 (8KB), Bs@8KB; epilogue arena
  short* As = (short*)smem;
  short* Bs = (short*)(smem + 8192);
  const int t = threadIdx.x, lane = t & 63, w = t >> 6;
  const int m0 = blockIdx.y * 128, n0 = blockIdx.x * 128;
  const int wm = (w >> 1) * 64, wn = (w & 1) * 64;
  const int row16 = lane & 15, grp = lane >> 4;
  const int arow = t >> 2, achunk = t & 3;
  f32x4 acc[4][4] = {};

  const int steps = K >> 5;
  const int z = blockIdx.z;
  const int sBeg = (z * steps) / kSplit, sEnd = ((z + 1) * steps) / kSplit;

  for (int s = sBeg; s < sEnd; ++s) {
    const int kt = s << 5;
    __syncthreads();
#pragma unroll
    for (int j = 0; j < 2; ++j) {
      int r = arow + j * 64;
      gl_lds16(A + (size_t)(m0 + r) * K + kt + achunk * 8,
               (char*)As + r * 64 + achunk * 16);
      gl_lds16(BT + (size_t)(n0 + r) * K + kt + achunk * 8,
               (char*)Bs + r * 64 + achunk * 16);
    }
    __syncthreads();
    bf16x8 af[4], bfr[4];
#pragma unroll
    for (int f = 0; f < 4; ++f) {
      af[f] = *(const bf16x8*)((const char*)As + (wm + f * 16 + row16) * 64 + grp * 16);
      bfr[f] = *(const bf16x8*)((const char*)Bs + (wn + f * 16 + row16) * 64 + grp * 16);
    }
#pragma unroll
    for (int mf = 0; mf < 4; ++mf)
#pragma unroll
      for (int nf = 0; nf < 4; ++nf)
        acc[mf][nf] =
            __builtin_amdgcn_mfma_f32_16x16x32_bf16(af[mf], bfr[nf], acc[mf][nf], 0, 0, 0);
  }

  __syncthreads();  // all LDS reads done before epilogue overwrites the arena

  // ---------------- V section of QKV: transposed bounce ----------------
  if constexpr (EPI == 5) {
    if (n0 >= 2048) {
#pragma unroll
      for (int nf = 0; nf < 4; ++nf) {
        int vloc = wn + nf * 16 + row16;           // local vr 0..127
        float bv = bC[n0 - 2048 + vloc];
#pragma unroll
        for (int mf = 0; mf < 4; ++mf) {
          int tloc = wm + mf * 16 + grp * 4;       // local token 0..124
          f32x4 a = acc[mf][nf];
          *(uint2*)(smem + vloc * 272 + tloc * 2) =
              make_uint2(pk2(a[0] + bv, a[1] + bv), pk2(a[2] + bv, a[3] + bv));
        }
      }
      __syncthreads();
      int vrBase = ((m0 >> 11) << 10) + (n0 - 2048);
      int mcol = m0 & 2047;
#pragma unroll
      for (int i = 0; i < 8; ++i) {
        int c = t + i * 256;
        int vr = c >> 4, tc = c & 15;
        u32x4 vv = *(const u32x4*)(smem + vr * 272 + tc * 16);
        *(u32x4*)((__hip_bfloat16*)C2 + (size_t)(vrBase + vr) * 2048 + mcol + tc * 8) = vv;
      }
      return;
    }
  }

  // ---------------- row-major bounce (EPI 1, 5-Q/K, 7, 8) ----------------
  __hip_bfloat16* outP = nullptr;
  int ldO = N, colB = n0;
  const float* bp = nullptr;
  if constexpr (EPI == 1) { outP = (__hip_bfloat16*)C0; bp = bA; }
  if constexpr (EPI == 5) {
    const bool isK = n0 >= 1024;
    outP = (__hip_bfloat16*)(isK ? C1 : C0);
    bp = isK ? bB : bA;
    ldO = 1024; colB = n0 & 1023;
  }
  if constexpr (EPI == 7) outP = (__hip_bfloat16*)C0 + (size_t)z * 4194304ull;
  if constexpr (EPI == 8)
    outP = (__hip_bfloat16*)C0 + ((z == 0) ? 0ull : ((z == 1) ? 4194304ull : 12582912ull));

#pragma unroll
  for (int nf = 0; nf < 4; ++nf) {
    int nn = wn + nf * 16 + row16;
    float bv = bp ? bp[colB + nn] : 0.f;
#pragma unroll
    for (int mf = 0; mf < 4; ++mf) {
      int mloc = wm + mf * 16 + grp * 4;
      f32x4 a = acc[mf][nf];
#pragma unroll
      for (int r = 0; r < 4; ++r) {
        float v = a[r] + bv;
        if constexpr (EPI == 1)
          v = 0.5f * v * (1.0f + erff(v * 0.70710678118654752f));
        *(short*)(smem + (mloc + r) * 272 + nn * 2) = f2bf(v);
      }
    }
  }
  __syncthreads();
#pragma unroll
  for (int i = 0; i < 8; ++i) {
    int c = t + i * 256;
    int mmr = c >> 4, nc = c & 15;
    u32x4 vv = *(const u32x4*)(smem + mmr * 272 + nc * 16);
    *(u32x4*)(outP + (size_t)(m0 + mmr) * ldO + colB + nc * 8) = vv;
  }
}

// ---------------- FF2 split-K reduce: out = h1 + b2 + sum(3 partials) --------
__global__ __launch_bounds__(256) void reduce3(const __hip_bfloat16* __restrict__ p0,
                                               const __hip_bfloat16* __restrict__ p1,
                                               const __hip_bfloat16* __restrict__ p2,
                                               const float* __restrict__ h1,
                                               const float* __restrict__ b2,
                                               float* __restrict__ out) {
  int idx = (blockIdx.x * 256 + threadIdx.x) * 8;
  int n = idx & 1023;
  bf16x8 a = *(const bf16x8*)(p0 + idx);
  bf16x8 b = *(const bf16x8*)(p1 + idx);
  bf16x8 c = *(const bf16x8*)(p2 + idx);
  float4 hA = *(const float4*)(h1 + idx), hB = *(const float4*)(h1 + idx + 4);
  float4 bA = *(const float4*)(b2 + n), bB = *(const float4*)(b2 + n + 4);
  float o[8];
#pragma unroll
  for (int j = 0; j < 8; ++j) o[j] = bf2f(a[j]) + bf2f(b[j]) + bf2f(c[j]);
  float4 r0 = make_float4(o[0] + hA.x + bA.x, o[1] + hA.y + bA.y,
                          o[2] + hA.z + bA.z, o[3] + hA.w + bA.w);
  float4 r1 = make_float4(o[4] + hB.x + bB.x, o[5] + hB.y + bB.y,
                          o[6] + hB.z + bB.z, o[7] + hB.w + bB.w);
  *(float4*)(out + idx) = r0;
  *(float4*)(out + idx + 4) = r1;
}

// ---------------- O-proj split-K reduce: h1 = x + bo + sum(4 partials) -------
__global__ __launch_bounds__(256) void reduce4(const __hip_bfloat16* __restrict__ p0,
                                               const __hip_bfloat16* __restrict__ p1,
                                               const __hip_bfloat16* __restrict__ p2,
                                               const __hip_bfloat16* __restrict__ p3,
                                               const float* __restrict__ x,
                                               const float* __restrict__ bo,
                                               float* __restrict__ out) {
  int idx = (blockIdx.x * 256 + threadIdx.x) * 8;
  int n = idx & 1023;
  bf16x8 a = *(const bf16x8*)(p0 + idx);
  bf16x8 b = *(const bf16x8*)(p1 + idx);
  bf16x8 c = *(const bf16x8*)(p2 + idx);
  bf16x8 d = *(const bf16x8*)(p3 + idx);
  float4 hA = *(const float4*)(x + idx), hB = *(const float4*)(x + idx + 4);
  float4 bA = *(const float4*)(bo + n), bB = *(const float4*)(bo + n + 4);
  float o[8];
#pragma unroll
  for (int j = 0; j < 8; ++j)
    o[j] = (bf2f(a[j]) + bf2f(b[j])) + (bf2f(c[j]) + bf2f(d[j]));
  float4 r0 = make_float4(o[0] + hA.x + bA.x, o[1] + hA.y + bA.y,
                          o[2] + hA.z + bA.z, o[3] + hA.w + bA.w);
  float4 r1 = make_float4(o[4] + hB.x + bB.x, o[5] + hB.y + bB.y,
                          o[6] + hB.z + bB.z, o[7] + hB.w + bB.w);
  *(float4*)(out + idx) = r0;
  *(float4*)(out + idx + 4) = r1;
}

// ---------------- Flash attention, split-KV=2: partial ctx + (m,l) ----------
__global__ __launch_bounds__(512) void flash_attn2(
    const __hip_bfloat16* __restrict__ Q,
    const __hip_bfloat16* __restrict__ Kg,
    const __hip_bfloat16* __restrict__ VTg,
    const float* __restrict__ mask,
    __hip_bfloat16* __restrict__ pctx0,
    __hip_bfloat16* __restrict__ pctx1,
    float2* __restrict__ ml) {
  __shared__ __align__(16) char lds[33280];
  const int t = threadIdx.x, lane = t & 63, w = t >> 6;
  const int l31 = lane & 31, hi = lane >> 5;
  const int q0 = blockIdx.x * 256;
  const int bh = blockIdx.y, b = bh >> 4, h = bh & 15;
  const int z = blockIdx.z;
  const int kvBase = z * (SS / 2);
  __hip_bfloat16* pctx = z ? pctx1 : pctx0;
  const int qrow = q0 + w * 32 + l31;

  bf16x8 qf[4];
  {
    const __hip_bfloat16* qp = Q + ((size_t)(b * SS + qrow)) * DD + h * HDIM + hi * 8;
    qf[0] = *(const bf16x8*)(qp);
    qf[1] = *(const bf16x8*)(qp + 16);
    qf[2] = *(const bf16x8*)(qp + 32);
    qf[3] = *(const bf16x8*)(qp + 48);
  }
  f32x16 ctx0 = {}, ctx1 = {};
  float m = -1e30f, l = 0.f, mC = -1.44e30f;

  auto stage = [&](int buf, int kv0) {
    int r = t >> 3, c = t & 7;
    gl_lds16(Kg + ((size_t)(b * SS + kv0 + r)) * DD + h * HDIM + ((c ^ (r & 7)) * 8),
             lds + buf * 8192 + t * 16);
    gl_lds16(VTg + ((size_t)(bh * 64 + r)) * 2048 + kv0 + ((c ^ (r & 7)) * 8),
             lds + 16384 + buf * 8192 + t * 16);
    if (t < 64) *(float*)(lds + 32768 + buf * 256 + t * 4) = mask[b * SS + kv0 + t];
  };

  stage(0, kvBase);
  const int NIT = SS / 128;  // 16 tiles of 64 over half the sequence
  for (int it = 0; it < NIT; ++it) {
    __syncthreads();
    if (it + 1 < NIT) stage((it + 1) & 1, kvBase + (it + 1) * 64);
    const char* Kb = lds + (it & 1) * 8192;
    const char* Vb = lds + 16384 + (it & 1) * 8192;
    const float* mk = (const float*)(lds + 32768 + (it & 1) * 256);

    f32x16 s0 = {}, s1 = {};
#pragma unroll
    for (int kc = 0; kc < 4; ++kc) {
      int c = kc * 2 + hi;
      int r0 = l31, r1 = 32 + l31;
      bf16x8 ka0 = *(const bf16x8*)(Kb + r0 * 128 + ((c ^ (r0 & 7)) << 4));
      bf16x8 ka1 = *(const bf16x8*)(Kb + r1 * 128 + ((c ^ (r1 & 7)) << 4));
      s0 = __builtin_amdgcn_mfma_f32_32x32x16_bf16(ka0, qf[kc], s0, 0, 0, 0);
      s1 = __builtin_amdgcn_mfma_f32_32x32x16_bf16(ka1, qf[kc], s1, 0, 0, 0);
    }
#pragma unroll
    for (int g = 0; g < 4; ++g) {
      float4 mg0 = *(const float4*)(mk + g * 8 + hi * 4);
      float4 mg1 = *(const float4*)(mk + 32 + g * 8 + hi * 4);
      const float* m0p = (const float*)&mg0;
      const float* m1p = (const float*)&mg1;
#pragma unroll
      for (int i = 0; i < 4; ++i) {
        s0[g * 4 + i] = fmaf(s0[g * 4 + i], 0.125f, m0p[i]);
        s1[g * 4 + i] = fmaf(s1[g * 4 + i], 0.125f, m1p[i]);
      }
    }
    float pmax;
    {
      f32x16 q8;
#pragma unroll
      for (int r = 0; r < 16; ++r) q8[r] = fmaxf(s0[r], s1[r]);
#pragma unroll
      for (int r = 0; r < 8; ++r) q8[r] = fmaxf(q8[r], q8[r + 8]);
#pragma unroll
      for (int r = 0; r < 4; ++r) q8[r] = fmaxf(q8[r], q8[r + 4]);
      pmax = fmaxf(fmaxf(q8[0], q8[1]), fmaxf(q8[2], q8[3]));
      pmax = fmaxf(pmax, __shfl_xor(pmax, 32));
    }
    if (__any(pmax > m + 8.0f)) {
      float mnew = fmaxf(m, pmax);
      float fac = EXP2((m - mnew) * LOG2E);
      l *= fac;
#pragma unroll
      for (int r = 0; r < 16; ++r) { ctx0[r] *= fac; ctx1[r] *= fac; }
      m = mnew;
      mC = m * LOG2E;
    }
    float rsA = 0.f, rsB = 0.f;
#pragma unroll
    for (int r = 0; r < 16; ++r) {
      s0[r] = EXP2(fmaf(s0[r], LOG2E, -mC));
      s1[r] = EXP2(fmaf(s1[r], LOG2E, -mC));
      rsA += s0[r];
      rsB += s1[r];
    }
    rsA += rsB;
    rsA += __shfl_xor(rsA, 32);
    l += rsA;

    unsigned W0[8], W1[8];
#pragma unroll
    for (int g = 0; g < 4; ++g) {
      W0[g * 2] = pk2(s0[g * 4 + 0], s0[g * 4 + 1]);
      W0[g * 2 + 1] = pk2(s0[g * 4 + 2], s0[g * 4 + 3]);
      W1[g * 2] = pk2(s1[g * 4 + 0], s1[g * 4 + 1]);
      W1[g * 2 + 1] = pk2(s1[g * 4 + 2], s1[g * 4 + 3]);
    }
    unsigned swA0 = __shfl_xor(hi ? W0[0] : W0[2], 32);
    unsigned swA1 = __shfl_xor(hi ? W0[1] : W0[3], 32);
    unsigned swB0 = __shfl_xor(hi ? W0[4] : W0[6], 32);
    unsigned swB1 = __shfl_xor(hi ? W0[5] : W0[7], 32);
    unsigned swC0 = __shfl_xor(hi ? W1[0] : W1[2], 32);
    unsigned swC1 = __shfl_xor(hi ? W1[1] : W1[3], 32);
    unsigned swD0 = __shfl_xor(hi ? W1[4] : W1[6], 32);
    unsigned swD1 = __shfl_xor(hi ? W1[5] : W1[7], 32);
    u32x4 pb[4];
    pb[0] = hi ? (u32x4){swA0, swA1, W0[2], W0[3]} : (u32x4){W0[0], W0[1], swA0, swA1};
    pb[1] = hi ? (u32x4){swB0, swB1, W0[6], W0[7]} : (u32x4){W0[4], W0[5], swB0, swB1};
    pb[2] = hi ? (u32x4){swC0, swC1, W1[2], W1[3]} : (u32x4){W1[0], W1[1], swC0, swC1};
    pb[3] = hi ? (u32x4){swD0, swD1, W1[6], W1[7]} : (u32x4){W1[4], W1[5], swD0, swD1};

#pragma unroll
    for (int kc = 0; kc < 4; ++kc) {
      bf16x8 pbf = __builtin_bit_cast(bf16x8, pb[kc]);
      int c = kc * 2 + hi;
      int r0 = l31, r1 = 32 + l31;
      bf16x8 va0 = *(const bf16x8*)(Vb + r0 * 128 + ((c ^ (r0 & 7)) << 4));
      bf16x8 va1 = *(const bf16x8*)(Vb + r1 * 128 + ((c ^ (r1 & 7)) << 4));
      ctx0 = __builtin_amdgcn_mfma_f32_32x32x16_bf16(va0, pbf, ctx0, 0, 0, 0);
      ctx1 = __builtin_amdgcn_mfma_f32_32x32x16_bf16(va1, pbf, ctx1, 0, 0, 0);
    }
  }

  // store (m, l) per q-row-head (one lane per row)
  if (hi == 0) ml[((size_t)z * NTOK + b * SS + qrow) * HH + h] = make_float2(m, l);

  // stage UNNORMALIZED ctx (bf16, swizzled) in LDS, coalesced partial store
  __syncthreads();
  {
    int row = w * 32 + l31;
#pragma unroll
    for (int dt = 0; dt < 2; ++dt) {
#pragma unroll
      for (int g = 0; g < 4; ++g) {
        unsigned lo2 = dt ? pk2(ctx1[g * 4 + 0], ctx1[g * 4 + 1]) : pk2(ctx0[g * 4 + 0], ctx0[g * 4 + 1]);
        unsigned hi2 = dt ? pk2(ctx1[g * 4 + 2], ctx1[g * 4 + 3]) : pk2(ctx0[g * 4 + 2], ctx0[g * 4 + 3]);
        int c = dt * 4 + g;
        *(uint2*)(lds + row * 128 + ((c ^ (row & 7)) << 4) + hi * 8) = make_uint2(lo2, hi2);
      }
    }
  }
  __syncthreads();
  {
    int r = t >> 1;
    size_t tok = (size_t)(b * SS + q0 + r);
#pragma unroll
    for (int i = 0; i < 4; ++i) {
      int c = (t & 1) * 4 + i;
      u32x4 vv = *(const u32x4*)(lds + r * 128 + ((c ^ (r & 7)) << 4));
      *(u32x4*)((short*)pctx + tok * DD + h * HDIM + c * 8) = vv;
    }
  }
}

// ---------------- merge two KV-half partials -> ctxb (bf16) ------------------
__global__ __launch_bounds__(256) void mergeAttn(
    const __hip_bfloat16* __restrict__ p0, const __hip_bfloat16* __restrict__ p1,
    const float2* __restrict__ ml, __hip_bfloat16* __restrict__ out) {
  int tok = blockIdx.x, tid = threadIdx.x;
  int h = tid >> 4;  // d = tid*4 -> head = d>>6
  float2 a = ml[(size_t)tok * HH + h];
  float2 b = ml[(size_t)(NTOK + tok) * HH + h];
  float M = fmaxf(a.x, b.x);
  float w0 = EXP2((a.x - M) * LOG2E), w1 = EXP2((b.x - M) * LOG2E);
  float inv = 1.0f / (w0 * a.y + w1 * b.y);
  w0 *= inv; w1 *= inv;
  size_t idx = (size_t)tok * DD + tid * 4;
  short4 c0 = *(const short4*)((const short*)p0 + idx);
  short4 c1 = *(const short4*)((const short*)p1 + idx);
  unsigned lo = pk2(w0 * bf2f(c0.x) + w1 * bf2f(c1.x),
                    w0 * bf2f(c0.y) + w1 * bf2f(c1.y));
  unsigned hi2 = pk2(w0 * bf2f(c0.z) + w1 * bf2f(c1.z),
                     w0 * bf2f(c0.w) + w1 * bf2f(c1.w));
  *(uint2*)((short*)out + idx) = make_uint2(lo, hi2);
}

// ---------------- host-side orchestration ------------------------------------
extern "C" void kernel_launch(void* const* d_in, const int* in_sizes, int n_in,
                              void* d_out, int out_size, void* d_ws, size_t ws_size,
                              hipStream_t stream) {
  const float* x = (const float*)d_in[0];
  const float* mask = (const float*)d_in[1];
  const float* wq = (const float*)d_in[2];
  const float* bq = (const float*)d_in[3];
  const float* wk = (const float*)d_in[4];
  const float* bk = (const float*)d_in[5];
  const float* wv = (const float*)d_in[6];
  const float* bv = (const float*)d_in[7];
  const float* wo = (const float*)d_in[8];
  const float* bo = (const float*)d_in[9];
  const float* w1 = (const float*)d_in[10];
  const float* b1 = (const float*)d_in[11];
  const float* w2 = (const float*)d_in[12];
  const float* b2 = (const float*)d_in[13];
  const float* g1 = (const float*)d_in[14];
  const float* be1 = (const float*)d_in[15];
  const float* g2 = (const float*)d_in[16];
  const float* be2 = (const float*)d_in[17];

  char* ws = (char*)d_ws;
  const size_t MB = 1024ull * 1024ull;
  __hip_bfloat16* wqkvT = (__hip_bfloat16*)(ws + 0 * MB);   // [3072][1024], 6MB
  __hip_bfloat16* woT = (__hip_bfloat16*)(ws + 6 * MB);     // 2MB
  __hip_bfloat16* w1T = (__hip_bfloat16*)(ws + 8 * MB);     // 8MB
  __hip_bfloat16* w2T = (__hip_bfloat16*)(ws + 16 * MB);    // 8MB
  __hip_bfloat16* xn = (__hip_bfloat16*)(ws + 24 * MB);     // 8MB; later h2
  __hip_bfloat16* qb = (__hip_bfloat16*)(ws + 32 * MB);
  __hip_bfloat16* kb = (__hip_bfloat16*)(ws + 40 * MB);
  __hip_bfloat16* vtb = (__hip_bfloat16*)(ws + 48 * MB);    // V^T [32][64][2048]
  __hip_bfloat16* ctxb = (__hip_bfloat16*)(ws + 56 * MB);
  float* h1 = (float*)(ws + 64 * MB);                       // 16MB
  __hip_bfloat16* h2 = xn;
  __hip_bfloat16* a1 = qb;                                  // 32MB @ 32..64
  // attention partials: pctx0 @24MB (xn dead), pctx1 @64MB, ml @72MB
  //   (h1 region 64..80 written only later by reduce4)
  __hip_bfloat16* pctx0 = (__hip_bfloat16*)(ws + 24 * MB);
  __hip_bfloat16* pctx1 = (__hip_bfloat16*)(ws + 64 * MB);
  float2* mlbuf = (float2*)(ws + 72 * MB);                  // 2*4096*16*8B = 1MB
  // O-proj bf16 partials: 24,32,40,48 MB; FF2 partials: 0, 8, 24 MB

  convT<<<dim3(32, 32), 256, 0, stream>>>(wq, wqkvT, 1024, 1024);
  convT<<<dim3(32, 32), 256, 0, stream>>>(wk, wqkvT + 1024 * 1024, 1024, 1024);
  convT<<<dim3(32, 32), 256, 0, stream>>>(wv, wqkvT + 2 * 1024 * 1024, 1024, 1024);
  convT<<<dim3(32, 32), 256, 0, stream>>>(wo, woT, 1024, 1024);
  convT<<<dim3(128, 32), 256, 0, stream>>>(w1, w1T, 1024, 4096);
  convT<<<dim3(32, 128), 256, 0, stream>>>(w2, w2T, 4096, 1024);

  ln_bf16<<<1024, 256, 0, stream>>>(x, g1, be1, xn);

  // fused QKV: M=4096, N=3072, K=1024 -> 768 blocks (3/CU)
  gemm_bt<5><<<dim3(24, 32), 256, 0, stream>>>(
      xn, wqkvT, bq, bk, bv, qb, kb, vtb, NTOK, 3072, 1024, 1);

  // flash attention split-KV=2 -> partials, then merge
  flash_attn2<<<dim3(8, 32, 2), 512, 0, stream>>>(qb, kb, vtb, mask,
                                                  pctx0, pctx1, mlbuf);
  mergeAttn<<<4096, 256, 0, stream>>>(pctx0, pctx1, mlbuf, ctxb);

  // O-proj split-K=4 -> bf16 partials @ 24+8z MB (1024 blocks)
  gemm_bt<7><<<dim3(8, 32, 4), 256, 0, stream>>>(
      ctxb, woT, nullptr, nullptr, nullptr, ws + 24 * MB, nullptr, nullptr,
      NTOK, 1024, 1024, 4);

  reduce4<<<2048, 256, 0, stream>>>((__hip_bfloat16*)(ws + 24 * MB),
                                    (__hip_bfloat16*)(ws + 32 * MB),
                                    (__hip_bfloat16*)(ws + 40 * MB),
                                    (__hip_bfloat16*)(ws + 48 * MB),
                                    x, bo, h1);

  ln_bf16<<<1024, 256, 0, stream>>>(h1, g2, be2, h2);

  // FF1 + gelu: M=4096, N=4096, K=1024 -> 1024 blocks (4/CU)
  gemm_bt<1><<<dim3(32, 32), 256, 0, stream>>>(
      h2, w1T, b1, nullptr, nullptr, a1, nullptr, nullptr, NTOK, FFD, 1024, 1);

  // FF2 split-K=3 -> bf16 partials @ 0/8/24 MB (768 blocks)
  gemm_bt<8><<<dim3(8, 32, 3), 256, 0, stream>>>(
      a1, w2T, nullptr, nullptr, nullptr, ws, nullptr, nullptr,
      NTOK, 1024, FFD, 3);

  reduce3<<<2048, 256, 0, stream>>>((__hip_bfloat16*)(ws + 0 * MB),
                                    (__hip_bfloat16*)(ws + 8 * MB),
                                    (__hip_bfloat16*)(ws + 24 * MB),
                                    h1, b2, (float*)d_out);
}

// Round 8
// 283.412 us; speedup vs baseline: 1.0157x; 1.0157x over previous
//
#include <hip/hip_runtime.h>
#include <hip/hip_bf16.h>
#include <math.h>

// Transformer layer: B=2 S=2048 D=1024 H=16 HD=64 FF=4096, fp32 I/O.
// Heavy GEMMs: 128x128 bf16 MFMA tiles, 3-buffer LDS software pipeline
// (counted vmcnt(4), raw s_barrier), coalesced epilogues via LDS bounce.
// Attention: flash split-KV=2 + merge.

#define BB 2
#define SS 2048
#define DD 1024
#define HH 16
#define HDIM 64
#define FFD 4096
#define NTOK (BB*SS)
#define LOG2E 1.4426950408889634f

typedef __attribute__((ext_vector_type(8))) short bf16x8;
typedef __attribute__((ext_vector_type(4))) float f32x4;
typedef __attribute__((ext_vector_type(16))) float f32x16;
typedef __attribute__((ext_vector_type(4))) unsigned int u32x4;

#if __has_builtin(__builtin_amdgcn_exp2f)
#define EXP2(x) __builtin_amdgcn_exp2f(x)
#else
#define EXP2(x) exp2f(x)
#endif

#define BAR __builtin_amdgcn_s_barrier
#define SCB __builtin_amdgcn_sched_barrier
#define VM4 asm volatile("s_waitcnt vmcnt(4)" ::: "memory")
#define VM0 asm volatile("s_waitcnt vmcnt(0)" ::: "memory")
#define LGK0 asm volatile("s_waitcnt lgkmcnt(0)" ::: "memory")

__device__ __forceinline__ void gl_lds16(const void* g, void* l) {
  __builtin_amdgcn_global_load_lds(
      (const __attribute__((address_space(1))) unsigned int*)g,
      (__attribute__((address_space(3))) unsigned int*)l, 16, 0, 0);
}

// RNE float->bf16 bits (finite inputs only)
__device__ __forceinline__ short f2bf(float f) {
  unsigned int u = __builtin_bit_cast(unsigned int, f);
  unsigned int r = (u + 0x7fffu + ((u >> 16) & 1u)) >> 16;
  return (short)r;
}
__device__ __forceinline__ float bf2f(short s) {
  return __builtin_bit_cast(float, ((unsigned)(unsigned short)s) << 16);
}
// packed pair via HW cvt (RNE): lo in low 16, hi in high 16
__device__ __forceinline__ unsigned pk2(float lo, float hi) {
  unsigned r;
  asm("v_cvt_pk_bf16_f32 %0, %1, %2" : "=v"(r) : "v"(lo), "v"(hi));
  return r;
}

// ---------------- transpose + fp32->bf16 convert: wt[n][k] = bf16(w[k][n]) ----
__global__ __launch_bounds__(256) void convT(const float* __restrict__ w,
                                             __hip_bfloat16* __restrict__ wt,
                                             int K, int N) {
  __shared__ float tile[32][33];
  int k0 = blockIdx.y * 32, n0 = blockIdx.x * 32;
  int tx = threadIdx.x & 31, ty = threadIdx.x >> 5;
#pragma unroll
  for (int i = 0; i < 4; ++i) {
    int r = ty + i * 8;
    tile[r][tx] = w[(size_t)(k0 + r) * N + n0 + tx];
  }
  __syncthreads();
#pragma unroll
  for (int i = 0; i < 4; ++i) {
    int r = ty + i * 8;
    wt[(size_t)(n0 + r) * K + k0 + tx] = __float2bfloat16(tile[tx][r]);
  }
}

// ---------------- LayerNorm (fp32 in -> bf16 out), one wave per row ----------
__global__ __launch_bounds__(256) void ln_bf16(const float* __restrict__ x,
                                               const float* __restrict__ g,
                                               const float* __restrict__ be,
                                               __hip_bfloat16* __restrict__ out) {
  int w = threadIdx.x >> 6, lane = threadIdx.x & 63;
  int row = blockIdx.x * 4 + w;
  const float* xr = x + (size_t)row * DD;
  float4 v[4];
  float sum = 0.f, sq = 0.f;
#pragma unroll
  for (int i = 0; i < 4; ++i) {
    v[i] = *(const float4*)(xr + lane * 4 + i * 256);
    sum += v[i].x + v[i].y + v[i].z + v[i].w;
    sq += v[i].x * v[i].x + v[i].y * v[i].y + v[i].z * v[i].z + v[i].w * v[i].w;
  }
#pragma unroll
  for (int off = 1; off < 64; off <<= 1) {
    sum += __shfl_xor(sum, off);
    sq += __shfl_xor(sq, off);
  }
  float mu = sum * (1.f / 1024.f);
  float var = sq * (1.f / 1024.f) - mu * mu;
  float rs = rsqrtf(var + 1e-12f);
  __hip_bfloat16* orow = out + (size_t)row * DD;
#pragma unroll
  for (int i = 0; i < 4; ++i) {
    int c = lane * 4 + i * 256;
    float4 gg = *(const float4*)(g + c);
    float4 bb = *(const float4*)(be + c);
    short4 o;
    o.x = f2bf((v[i].x - mu) * rs * gg.x + bb.x);
    o.y = f2bf((v[i].y - mu) * rs * gg.y + bb.y);
    o.z = f2bf((v[i].z - mu) * rs * gg.z + bb.z);
    o.w = f2bf((v[i].w - mu) * rs * gg.w + bb.w);
    *(short4*)((short*)orow + c) = o;
  }
}

// ---------------- GEMM: C[M,N] = A[M,K] (bf16) * BT[N,K]^T + epilogue --------
// 128x128 tile, BK=32, 4 waves. 3-buffer LDS pipeline:
//   step t: ds_read frags from buf[t%3]; stage step t+2 -> buf[(t+2)%3];
//           lgkmcnt(0); 16 MFMA; vmcnt(4) (keeps newest 4 loads in flight);
//           raw s_barrier.  Loads get >= 1 full step of flight time.
// Ledger: stage(t)'s loads (issued at t-2) are older than stage(t+1)'s, so
// the vmcnt(4) at end of t-1 guarantees them done; WAR on buf[(t+2)%3] is
// protected by the end-of-(t-1) barrier (its readers finished before it).
// Epilogues bounce through LDS (272B-stride rows) for coalesced 16B stores.
// EPI 1: +bias, gelu-erf -> bf16                       [FF1]
// EPI 5: QKV fused (N=3072): Q,K +bias -> bf16; V +bias -> bf16 transposed
// EPI 7: raw -> bf16 partial @ C0 + z*4Mi elems        [O-proj split-K]
// EPI 8: raw -> bf16 partial @ C0 + {0,4Mi,12Mi} elems [FF2 split-K]
template <int EPI>
__global__ __launch_bounds__(256, 3) void gemm_bt(
    const __hip_bfloat16* __restrict__ A, const __hip_bfloat16* __restrict__ BT,
    const float* __restrict__ bA, const float* __restrict__ bB,
    const float* __restrict__ bC,
    void* __restrict__ C0, void* __restrict__ C1, void* __restrict__ C2,
    int M, int N, int K, int kSplit) {
  __shared__ __align__(16) char smem[49152];  // 3 x {A 8KB | B 8KB}; epi arena
  const int t = threadIdx.x, lane = t & 63, w = t >> 6;
  const int m0 = blockIdx.y * 128, n0 = blockIdx.x * 128;
  const int wm = (w >> 1) * 64, wn = (w & 1) * 64;
  const int row16 = lane & 15, grp = lane >> 4;
  const int arow = t >> 2, achunk = t & 3;
  f32x4 acc[4][4] = {};

  const int steps = K >> 5;
  const int z = blockIdx.z;
  const int sBeg = (z * steps) / kSplit, sEnd = ((z + 1) * steps) / kSplit;
  const int NT = sEnd - sBeg;

  // per-thread staging addresses (A row pair, B row pair)
  const __hip_bfloat16* gA0 = A + (size_t)(m0 + arow) * K + achunk * 8;
  const __hip_bfloat16* gA1 = A + (size_t)(m0 + arow + 64) * K + achunk * 8;
  const __hip_bfloat16* gB0 = BT + (size_t)(n0 + arow) * K + achunk * 8;
  const __hip_bfloat16* gB1 = BT + (size_t)(n0 + arow + 64) * K + achunk * 8;
  char* ldsA0 = smem + arow * 64 + achunk * 16;
  char* ldsA1 = smem + (arow + 64) * 64 + achunk * 16;
  char* ldsB0 = smem + 8192 + arow * 64 + achunk * 16;
  char* ldsB1 = smem + 8192 + (arow + 64) * 64 + achunk * 16;

  auto stage = [&](int st, int buf) {
    int kt = (sBeg + st) << 5;
    char* o = (char*)0 + buf * 16384;
    gl_lds16(gA0 + kt, ldsA0 + (size_t)(o - (char*)0));
    gl_lds16(gA1 + kt, ldsA1 + (size_t)(o - (char*)0));
    gl_lds16(gB0 + kt, ldsB0 + (size_t)(o - (char*)0));
    gl_lds16(gB1 + kt, ldsB1 + (size_t)(o - (char*)0));
  };

  // prologue: stage steps 0 and 1; drain step 0's loads; barrier
  stage(0, 0);
  if (NT > 1) stage(1, 1);
  VM4; SCB(0);
  BAR(); SCB(0);

  for (int tt = 0; tt < NT; ++tt) {
    const char* bufR = smem + (tt % 3) * 16384;
    // fragment ds_reads from current buffer
    bf16x8 af[4], bfr[4];
#pragma unroll
    for (int f = 0; f < 4; ++f) {
      af[f] = *(const bf16x8*)(bufR + (wm + f * 16 + row16) * 64 + grp * 16);
      bfr[f] = *(const bf16x8*)(bufR + 8192 + (wn + f * 16 + row16) * 64 + grp * 16);
    }
    // stage step tt+2 into buf[(tt+2)%3]
    const bool more = (tt + 2 < NT);
    if (more) stage(tt + 2, (tt + 2) % 3);
    LGK0; SCB(0);
#pragma unroll
    for (int mf = 0; mf < 4; ++mf)
#pragma unroll
      for (int nf = 0; nf < 4; ++nf)
        acc[mf][nf] =
            __builtin_amdgcn_mfma_f32_16x16x32_bf16(af[mf], bfr[nf], acc[mf][nf], 0, 0, 0);
    SCB(0);
    if (more) { VM4; } else { VM0; }
    SCB(0);
    BAR(); SCB(0);
  }

  __syncthreads();  // epilogue arena reuse

  // ---------------- V section of QKV: transposed bounce ----------------
  if constexpr (EPI == 5) {
    if (n0 >= 2048) {
#pragma unroll
      for (int nf = 0; nf < 4; ++nf) {
        int vloc = wn + nf * 16 + row16;           // local vr 0..127
        float bv = bC[n0 - 2048 + vloc];
#pragma unroll
        for (int mf = 0; mf < 4; ++mf) {
          int tloc = wm + mf * 16 + grp * 4;       // local token 0..124
          f32x4 a = acc[mf][nf];
          *(uint2*)(smem + vloc * 272 + tloc * 2) =
              make_uint2(pk2(a[0] + bv, a[1] + bv), pk2(a[2] + bv, a[3] + bv));
        }
      }
      __syncthreads();
      int vrBase = ((m0 >> 11) << 10) + (n0 - 2048);
      int mcol = m0 & 2047;
#pragma unroll
      for (int i = 0; i < 8; ++i) {
        int c = t + i * 256;
        int vr = c >> 4, tc = c & 15;
        u32x4 vv = *(const u32x4*)(smem + vr * 272 + tc * 16);
        *(u32x4*)((__hip_bfloat16*)C2 + (size_t)(vrBase + vr) * 2048 + mcol + tc * 8) = vv;
      }
      return;
    }
  }

  // ---------------- row-major bounce (EPI 1, 5-Q/K, 7, 8) ----------------
  __hip_bfloat16* outP = nullptr;
  int ldO = N, colB = n0;
  const float* bp = nullptr;
  if constexpr (EPI == 1) { outP = (__hip_bfloat16*)C0; bp = bA; }
  if constexpr (EPI == 5) {
    const bool isK = n0 >= 1024;
    outP = (__hip_bfloat16*)(isK ? C1 : C0);
    bp = isK ? bB : bA;
    ldO = 1024; colB = n0 & 1023;
  }
  if constexpr (EPI == 7) outP = (__hip_bfloat16*)C0 + (size_t)z * 4194304ull;
  if constexpr (EPI == 8)
    outP = (__hip_bfloat16*)C0 + ((z == 0) ? 0ull : ((z == 1) ? 4194304ull : 12582912ull));

#pragma unroll
  for (int nf = 0; nf < 4; ++nf) {
    int nn = wn + nf * 16 + row16;
    float bv = bp ? bp[colB + nn] : 0.f;
#pragma unroll
    for (int mf = 0; mf < 4; ++mf) {
      int mloc = wm + mf * 16 + grp * 4;
      f32x4 a = acc[mf][nf];
#pragma unroll
      for (int r = 0; r < 4; ++r) {
        float v = a[r] + bv;
        if constexpr (EPI == 1)
          v = 0.5f * v * (1.0f + erff(v * 0.70710678118654752f));
        *(short*)(smem + (mloc + r) * 272 + nn * 2) = f2bf(v);
      }
    }
  }
  __syncthreads();
#pragma unroll
  for (int i = 0; i < 8; ++i) {
    int c = t + i * 256;
    int mmr = c >> 4, nc = c & 15;
    u32x4 vv = *(const u32x4*)(smem + mmr * 272 + nc * 16);
    *(u32x4*)(outP + (size_t)(m0 + mmr) * ldO + colB + nc * 8) = vv;
  }
}

// ---------------- FF2 split-K reduce: out = h1 + b2 + sum(3 partials) --------
__global__ __launch_bounds__(256) void reduce3(const __hip_bfloat16* __restrict__ p0,
                                               const __hip_bfloat16* __restrict__ p1,
                                               const __hip_bfloat16* __restrict__ p2,
                                               const float* __restrict__ h1,
                                               const float* __restrict__ b2,
                                               float* __restrict__ out) {
  int idx = (blockIdx.x * 256 + threadIdx.x) * 8;
  int n = idx & 1023;
  bf16x8 a = *(const bf16x8*)(p0 + idx);
  bf16x8 b = *(const bf16x8*)(p1 + idx);
  bf16x8 c = *(const bf16x8*)(p2 + idx);
  float4 hA = *(const float4*)(h1 + idx), hB = *(const float4*)(h1 + idx + 4);
  float4 bA = *(const float4*)(b2 + n), bB = *(const float4*)(b2 + n + 4);
  float o[8];
#pragma unroll
  for (int j = 0; j < 8; ++j) o[j] = bf2f(a[j]) + bf2f(b[j]) + bf2f(c[j]);
  float4 r0 = make_float4(o[0] + hA.x + bA.x, o[1] + hA.y + bA.y,
                          o[2] + hA.z + bA.z, o[3] + hA.w + bA.w);
  float4 r1 = make_float4(o[4] + hB.x + bB.x, o[5] + hB.y + bB.y,
                          o[6] + hB.z + bB.z, o[7] + hB.w + bB.w);
  *(float4*)(out + idx) = r0;
  *(float4*)(out + idx + 4) = r1;
}

// ---------------- O-proj split-K reduce: h1 = x + bo + sum(4 partials) -------
__global__ __launch_bounds__(256) void reduce4(const __hip_bfloat16* __restrict__ p0,
                                               const __hip_bfloat16* __restrict__ p1,
                                               const __hip_bfloat16* __restrict__ p2,
                                               const __hip_bfloat16* __restrict__ p3,
                                               const float* __restrict__ x,
                                               const float* __restrict__ bo,
                                               float* __restrict__ out) {
  int idx = (blockIdx.x * 256 + threadIdx.x) * 8;
  int n = idx & 1023;
  bf16x8 a = *(const bf16x8*)(p0 + idx);
  bf16x8 b = *(const bf16x8*)(p1 + idx);
  bf16x8 c = *(const bf16x8*)(p2 + idx);
  bf16x8 d = *(const bf16x8*)(p3 + idx);
  float4 hA = *(const float4*)(x + idx), hB = *(const float4*)(x + idx + 4);
  float4 bA = *(const float4*)(bo + n), bB = *(const float4*)(bo + n + 4);
  float o[8];
#pragma unroll
  for (int j = 0; j < 8; ++j)
    o[j] = (bf2f(a[j]) + bf2f(b[j])) + (bf2f(c[j]) + bf2f(d[j]));
  float4 r0 = make_float4(o[0] + hA.x + bA.x, o[1] + hA.y + bA.y,
                          o[2] + hA.z + bA.z, o[3] + hA.w + bA.w);
  float4 r1 = make_float4(o[4] + hB.x + bB.x, o[5] + hB.y + bB.y,
                          o[6] + hB.z + bB.z, o[7] + hB.w + bB.w);
  *(float4*)(out + idx) = r0;
  *(float4*)(out + idx + 4) = r1;
}

// ---------------- Flash attention, split-KV=2: partial ctx + (m,l) ----------
__global__ __launch_bounds__(512) void flash_attn2(
    const __hip_bfloat16* __restrict__ Q,
    const __hip_bfloat16* __restrict__ Kg,
    const __hip_bfloat16* __restrict__ VTg,
    const float* __restrict__ mask,
    __hip_bfloat16* __restrict__ pctx0,
    __hip_bfloat16* __restrict__ pctx1,
    float2* __restrict__ ml) {
  __shared__ __align__(16) char lds[33280];
  const int t = threadIdx.x, lane = t & 63, w = t >> 6;
  const int l31 = lane & 31, hi = lane >> 5;
  const int q0 = blockIdx.x * 256;
  const int bh = blockIdx.y, b = bh >> 4, h = bh & 15;
  const int z = blockIdx.z;
  const int kvBase = z * (SS / 2);
  __hip_bfloat16* pctx = z ? pctx1 : pctx0;
  const int qrow = q0 + w * 32 + l31;

  bf16x8 qf[4];
  {
    const __hip_bfloat16* qp = Q + ((size_t)(b * SS + qrow)) * DD + h * HDIM + hi * 8;
    qf[0] = *(const bf16x8*)(qp);
    qf[1] = *(const bf16x8*)(qp + 16);
    qf[2] = *(const bf16x8*)(qp + 32);
    qf[3] = *(const bf16x8*)(qp + 48);
  }
  f32x16 ctx0 = {}, ctx1 = {};
  float m = -1e30f, l = 0.f, mC = -1.44e30f;

  auto stage = [&](int buf, int kv0) {
    int r = t >> 3, c = t & 7;
    gl_lds16(Kg + ((size_t)(b * SS + kv0 + r)) * DD + h * HDIM + ((c ^ (r & 7)) * 8),
             lds + buf * 8192 + t * 16);
    gl_lds16(VTg + ((size_t)(bh * 64 + r)) * 2048 + kv0 + ((c ^ (r & 7)) * 8),
             lds + 16384 + buf * 8192 + t * 16);
    if (t < 64) *(float*)(lds + 32768 + buf * 256 + t * 4) = mask[b * SS + kv0 + t];
  };

  stage(0, kvBase);
  const int NIT = SS / 128;  // 16 tiles of 64 over half the sequence
  for (int it = 0; it < NIT; ++it) {
    __syncthreads();
    if (it + 1 < NIT) stage((it + 1) & 1, kvBase + (it + 1) * 64);
    const char* Kb = lds + (it & 1) * 8192;
    const char* Vb = lds + 16384 + (it & 1) * 8192;
    const float* mk = (const float*)(lds + 32768 + (it & 1) * 256);

    f32x16 s0 = {}, s1 = {};
#pragma unroll
    for (int kc = 0; kc < 4; ++kc) {
      int c = kc * 2 + hi;
      int r0 = l31, r1 = 32 + l31;
      bf16x8 ka0 = *(const bf16x8*)(Kb + r0 * 128 + ((c ^ (r0 & 7)) << 4));
      bf16x8 ka1 = *(const bf16x8*)(Kb + r1 * 128 + ((c ^ (r1 & 7)) << 4));
      s0 = __builtin_amdgcn_mfma_f32_32x32x16_bf16(ka0, qf[kc], s0, 0, 0, 0);
      s1 = __builtin_amdgcn_mfma_f32_32x32x16_bf16(ka1, qf[kc], s1, 0, 0, 0);
    }
#pragma unroll
    for (int g = 0; g < 4; ++g) {
      float4 mg0 = *(const float4*)(mk + g * 8 + hi * 4);
      float4 mg1 = *(const float4*)(mk + 32 + g * 8 + hi * 4);
      const float* m0p = (const float*)&mg0;
      const float* m1p = (const float*)&mg1;
#pragma unroll
      for (int i = 0; i < 4; ++i) {
        s0[g * 4 + i] = fmaf(s0[g * 4 + i], 0.125f, m0p[i]);
        s1[g * 4 + i] = fmaf(s1[g * 4 + i], 0.125f, m1p[i]);
      }
    }
    float pmax;
    {
      f32x16 q8;
#pragma unroll
      for (int r = 0; r < 16; ++r) q8[r] = fmaxf(s0[r], s1[r]);
#pragma unroll
      for (int r = 0; r < 8; ++r) q8[r] = fmaxf(q8[r], q8[r + 8]);
#pragma unroll
      for (int r = 0; r < 4; ++r) q8[r] = fmaxf(q8[r], q8[r + 4]);
      pmax = fmaxf(fmaxf(q8[0], q8[1]), fmaxf(q8[2], q8[3]));
      pmax = fmaxf(pmax, __shfl_xor(pmax, 32));
    }
    if (__any(pmax > m + 8.0f)) {
      float mnew = fmaxf(m, pmax);
      float fac = EXP2((m - mnew) * LOG2E);
      l *= fac;
#pragma unroll
      for (int r = 0; r < 16; ++r) { ctx0[r] *= fac; ctx1[r] *= fac; }
      m = mnew;
      mC = m * LOG2E;
    }
    float rsA = 0.f, rsB = 0.f;
#pragma unroll
    for (int r = 0; r < 16; ++r) {
      s0[r] = EXP2(fmaf(s0[r], LOG2E, -mC));
      s1[r] = EXP2(fmaf(s1[r], LOG2E, -mC));
      rsA += s0[r];
      rsB += s1[r];
    }
    rsA += rsB;
    rsA += __shfl_xor(rsA, 32);
    l += rsA;

    unsigned W0[8], W1[8];
#pragma unroll
    for (int g = 0; g < 4; ++g) {
      W0[g * 2] = pk2(s0[g * 4 + 0], s0[g * 4 + 1]);
      W0[g * 2 + 1] = pk2(s0[g * 4 + 2], s0[g * 4 + 3]);
      W1[g * 2] = pk2(s1[g * 4 + 0], s1[g * 4 + 1]);
      W1[g * 2 + 1] = pk2(s1[g * 4 + 2], s1[g * 4 + 3]);
    }
    unsigned swA0 = __shfl_xor(hi ? W0[0] : W0[2], 32);
    unsigned swA1 = __shfl_xor(hi ? W0[1] : W0[3], 32);
    unsigned swB0 = __shfl_xor(hi ? W0[4] : W0[6], 32);
    unsigned swB1 = __shfl_xor(hi ? W0[5] : W0[7], 32);
    unsigned swC0 = __shfl_xor(hi ? W1[0] : W1[2], 32);
    unsigned swC1 = __shfl_xor(hi ? W1[1] : W1[3], 32);
    unsigned swD0 = __shfl_xor(hi ? W1[4] : W1[6], 32);
    unsigned swD1 = __shfl_xor(hi ? W1[5] : W1[7], 32);
    u32x4 pb[4];
    pb[0] = hi ? (u32x4){swA0, swA1, W0[2], W0[3]} : (u32x4){W0[0], W0[1], swA0, swA1};
    pb[1] = hi ? (u32x4){swB0, swB1, W0[6], W0[7]} : (u32x4){W0[4], W0[5], swB0, swB1};
    pb[2] = hi ? (u32x4){swC0, swC1, W1[2], W1[3]} : (u32x4){W1[0], W1[1], swC0, swC1};
    pb[3] = hi ? (u32x4){swD0, swD1, W1[6], W1[7]} : (u32x4){W1[4], W1[5], swD0, swD1};

#pragma unroll
    for (int kc = 0; kc < 4; ++kc) {
      bf16x8 pbf = __builtin_bit_cast(bf16x8, pb[kc]);
      int c = kc * 2 + hi;
      int r0 = l31, r1 = 32 + l31;
      bf16x8 va0 = *(const bf16x8*)(Vb + r0 * 128 + ((c ^ (r0 & 7)) << 4));
      bf16x8 va1 = *(const bf16x8*)(Vb + r1 * 128 + ((c ^ (r1 & 7)) << 4));
      ctx0 = __builtin_amdgcn_mfma_f32_32x32x16_bf16(va0, pbf, ctx0, 0, 0, 0);
      ctx1 = __builtin_amdgcn_mfma_f32_32x32x16_bf16(va1, pbf, ctx1, 0, 0, 0);
    }
  }

  // store (m, l) per q-row-head (one lane per row)
  if (hi == 0) ml[((size_t)z * NTOK + b * SS + qrow) * HH + h] = make_float2(m, l);

  // stage UNNORMALIZED ctx (bf16, swizzled) in LDS, coalesced partial store
  __syncthreads();
  {
    int row = w * 32 + l31;
#pragma unroll
    for (int dt = 0; dt < 2; ++dt) {
#pragma unroll
      for (int g = 0; g < 4; ++g) {
        unsigned lo2 = dt ? pk2(ctx1[g * 4 + 0], ctx1[g * 4 + 1]) : pk2(ctx0[g * 4 + 0], ctx0[g * 4 + 1]);
        unsigned hi2 = dt ? pk2(ctx1[g * 4 + 2], ctx1[g * 4 + 3]) : pk2(ctx0[g * 4 + 2], ctx0[g * 4 + 3]);
        int c = dt * 4 + g;
        *(uint2*)(lds + row * 128 + ((c ^ (row & 7)) << 4) + hi * 8) = make_uint2(lo2, hi2);
      }
    }
  }
  __syncthreads();
  {
    int r = t >> 1;
    size_t tok = (size_t)(b * SS + q0 + r);
#pragma unroll
    for (int i = 0; i < 4; ++i) {
      int c = (t & 1) * 4 + i;
      u32x4 vv = *(const u32x4*)(lds + r * 128 + ((c ^ (r & 7)) << 4));
      *(u32x4*)((short*)pctx + tok * DD + h * HDIM + c * 8) = vv;
    }
  }
}

// ---------------- merge two KV-half partials -> ctxb (bf16) ------------------
__global__ __launch_bounds__(256) void mergeAttn(
    const __hip_bfloat16* __restrict__ p0, const __hip_bfloat16* __restrict__ p1,
    const float2* __restrict__ ml, __hip_bfloat16* __restrict__ out) {
  int tok = blockIdx.x, tid = threadIdx.x;
  int h = tid >> 4;  // d = tid*4 -> head = d>>6
  float2 a = ml[(size_t)tok * HH + h];
  float2 b = ml[(size_t)(NTOK + tok) * HH + h];
  float M = fmaxf(a.x, b.x);
  float w0 = EXP2((a.x - M) * LOG2E), w1 = EXP2((b.x - M) * LOG2E);
  float inv = 1.0f / (w0 * a.y + w1 * b.y);
  w0 *= inv; w1 *= inv;
  size_t idx = (size_t)tok * DD + tid * 4;
  short4 c0 = *(const short4*)((const short*)p0 + idx);
  short4 c1 = *(const short4*)((const short*)p1 + idx);
  unsigned lo = pk2(w0 * bf2f(c0.x) + w1 * bf2f(c1.x),
                    w0 * bf2f(c0.y) + w1 * bf2f(c1.y));
  unsigned hi2 = pk2(w0 * bf2f(c0.z) + w1 * bf2f(c1.z),
                     w0 * bf2f(c0.w) + w1 * bf2f(c1.w));
  *(uint2*)((short*)out + idx) = make_uint2(lo, hi2);
}

// ---------------- host-side orchestration ------------------------------------
extern "C" void kernel_launch(void* const* d_in, const int* in_sizes, int n_in,
                              void* d_out, int out_size, void* d_ws, size_t ws_size,
                              hipStream_t stream) {
  const float* x = (const float*)d_in[0];
  const float* mask = (const float*)d_in[1];
  const float* wq = (const float*)d_in[2];
  const float* bq = (const float*)d_in[3];
  const float* wk = (const float*)d_in[4];
  const float* bk = (const float*)d_in[5];
  const float* wv = (const float*)d_in[6];
  const float* bv = (const float*)d_in[7];
  const float* wo = (const float*)d_in[8];
  const float* bo = (const float*)d_in[9];
  const float* w1 = (const float*)d_in[10];
  const float* b1 = (const float*)d_in[11];
  const float* w2 = (const float*)d_in[12];
  const float* b2 = (const float*)d_in[13];
  const float* g1 = (const float*)d_in[14];
  const float* be1 = (const float*)d_in[15];
  const float* g2 = (const float*)d_in[16];
  const float* be2 = (const float*)d_in[17];

  char* ws = (char*)d_ws;
  const size_t MB = 1024ull * 1024ull;
  __hip_bfloat16* wqkvT = (__hip_bfloat16*)(ws + 0 * MB);   // [3072][1024], 6MB
  __hip_bfloat16* woT = (__hip_bfloat16*)(ws + 6 * MB);     // 2MB
  __hip_bfloat16* w1T = (__hip_bfloat16*)(ws + 8 * MB);     // 8MB
  __hip_bfloat16* w2T = (__hip_bfloat16*)(ws + 16 * MB);    // 8MB
  __hip_bfloat16* xn = (__hip_bfloat16*)(ws + 24 * MB);     // 8MB; later h2
  __hip_bfloat16* qb = (__hip_bfloat16*)(ws + 32 * MB);
  __hip_bfloat16* kb = (__hip_bfloat16*)(ws + 40 * MB);
  __hip_bfloat16* vtb = (__hip_bfloat16*)(ws + 48 * MB);    // V^T [32][64][2048]
  __hip_bfloat16* ctxb = (__hip_bfloat16*)(ws + 56 * MB);
  float* h1 = (float*)(ws + 64 * MB);                       // 16MB
  __hip_bfloat16* h2 = xn;
  __hip_bfloat16* a1 = qb;                                  // 32MB @ 32..64
  // attention partials: pctx0 @24MB (xn dead), pctx1 @64MB, ml @72MB
  __hip_bfloat16* pctx0 = (__hip_bfloat16*)(ws + 24 * MB);
  __hip_bfloat16* pctx1 = (__hip_bfloat16*)(ws + 64 * MB);
  float2* mlbuf = (float2*)(ws + 72 * MB);                  // 1MB
  // O-proj bf16 partials: 24,32,40,48 MB; FF2 partials: 0, 8, 24 MB

  convT<<<dim3(32, 32), 256, 0, stream>>>(wq, wqkvT, 1024, 1024);
  convT<<<dim3(32, 32), 256, 0, stream>>>(wk, wqkvT + 1024 * 1024, 1024, 1024);
  convT<<<dim3(32, 32), 256, 0, stream>>>(wv, wqkvT + 2 * 1024 * 1024, 1024, 1024);
  convT<<<dim3(32, 32), 256, 0, stream>>>(wo, woT, 1024, 1024);
  convT<<<dim3(128, 32), 256, 0, stream>>>(w1, w1T, 1024, 4096);
  convT<<<dim3(32, 128), 256, 0, stream>>>(w2, w2T, 4096, 1024);

  ln_bf16<<<1024, 256, 0, stream>>>(x, g1, be1, xn);

  // fused QKV: M=4096, N=3072, K=1024 -> 768 blocks (3/CU)
  gemm_bt<5><<<dim3(24, 32), 256, 0, stream>>>(
      xn, wqkvT, bq, bk, bv, qb, kb, vtb, NTOK, 3072, 1024, 1);

  // flash attention split-KV=2 -> partials, then merge
  flash_attn2<<<dim3(8, 32, 2), 512, 0, stream>>>(qb, kb, vtb, mask,
                                                  pctx0, pctx1, mlbuf);
  mergeAttn<<<4096, 256, 0, stream>>>(pctx0, pctx1, mlbuf, ctxb);

  // O-proj split-K=4 -> bf16 partials @ 24+8z MB (1024 blocks)
  gemm_bt<7><<<dim3(8, 32, 4), 256, 0, stream>>>(
      ctxb, woT, nullptr, nullptr, nullptr, ws + 24 * MB, nullptr, nullptr,
      NTOK, 1024, 1024, 4);

  reduce4<<<2048, 256, 0, stream>>>((__hip_bfloat16*)(ws + 24 * MB),
                                    (__hip_bfloat16*)(ws + 32 * MB),
                                    (__hip_bfloat16*)(ws + 40 * MB),
                                    (__hip_bfloat16*)(ws + 48 * MB),
                                    x, bo, h1);

  ln_bf16<<<1024, 256, 0, stream>>>(h1, g2, be2, h2);

  // FF1 + gelu: M=4096, N=4096, K=1024 -> 1024 blocks
  gemm_bt<1><<<dim3(32, 32), 256, 0, stream>>>(
      h2, w1T, b1, nullptr, nullptr, a1, nullptr, nullptr, NTOK, FFD, 1024, 1);

  // FF2 split-K=3 -> bf16 partials @ 0/8/24 MB (768 blocks)
  gemm_bt<8><<<dim3(8, 32, 3), 256, 0, stream>>>(
      a1, w2T, nullptr, nullptr, nullptr, ws, nullptr, nullptr,
      NTOK, 1024, FFD, 3);

  reduce3<<<2048, 256, 0, stream>>>((__hip_bfloat16*)(ws + 0 * MB),
                                    (__hip_bfloat16*)(ws + 8 * MB),
                                    (__hip_bfloat16*)(ws + 24 * MB),
                                    h1, b2, (float*)d_out);
}

// Round 9
// 273.573 us; speedup vs baseline: 1.0522x; 1.0360x over previous
//
#include <hip/hip_runtime.h>
#include <hip/hip_bf16.h>
#include <math.h>

// Transformer layer: B=2 S=2048 D=1024 H=16 HD=64 FF=4096, fp32 I/O.
// Heavy GEMMs: m97-style 128x128 bf16 MFMA tiles (2-barrier loop, 4 blocks/CU),
// coalesced epilogues via LDS bounce, fast tanh-gelu.
// Attention: flash split-KV=2 + merge. Fused reduce4+LN2.

#define BB 2
#define SS 2048
#define DD 1024
#define HH 16
#define HDIM 64
#define FFD 4096
#define NTOK (BB*SS)
#define LOG2E 1.4426950408889634f

typedef __attribute__((ext_vector_type(8))) short bf16x8;
typedef __attribute__((ext_vector_type(4))) float f32x4;
typedef __attribute__((ext_vector_type(16))) float f32x16;
typedef __attribute__((ext_vector_type(4))) unsigned int u32x4;

#if __has_builtin(__builtin_amdgcn_exp2f)
#define EXP2(x) __builtin_amdgcn_exp2f(x)
#else
#define EXP2(x) exp2f(x)
#endif

__device__ __forceinline__ void gl_lds16(const void* g, void* l) {
  __builtin_amdgcn_global_load_lds(
      (const __attribute__((address_space(1))) unsigned int*)g,
      (__attribute__((address_space(3))) unsigned int*)l, 16, 0, 0);
}

// RNE float->bf16 bits (finite inputs only)
__device__ __forceinline__ short f2bf(float f) {
  unsigned int u = __builtin_bit_cast(unsigned int, f);
  unsigned int r = (u + 0x7fffu + ((u >> 16) & 1u)) >> 16;
  return (short)r;
}
__device__ __forceinline__ float bf2f(short s) {
  return __builtin_bit_cast(float, ((unsigned)(unsigned short)s) << 16);
}
// packed pair via HW cvt (RNE)
__device__ __forceinline__ unsigned pk2(float lo, float hi) {
  unsigned r;
  asm("v_cvt_pk_bf16_f32 %0, %1, %2" : "=v"(r) : "v"(lo), "v"(hi));
  return r;
}
// gelu, tanh form via exp2 (max dev vs erf-gelu ~3e-4)
__device__ __forceinline__ float gelu_fast(float v) {
  float v2 = v * v;
  float u = v * (0.7978845608028654f + 0.03567740814183427f * v2);
  float e = EXP2(u * 2.8853900817779268f);  // e^(2u)
  return v * (1.0f - 1.0f / (e + 1.0f));
}

// ---------------- transpose + fp32->bf16 convert: wt[n][k] = bf16(w[k][n]) ----
__global__ __launch_bounds__(256) void convT(const float* __restrict__ w,
                                             __hip_bfloat16* __restrict__ wt,
                                             int K, int N) {
  __shared__ float tile[32][33];
  int k0 = blockIdx.y * 32, n0 = blockIdx.x * 32;
  int tx = threadIdx.x & 31, ty = threadIdx.x >> 5;
#pragma unroll
  for (int i = 0; i < 4; ++i) {
    int r = ty + i * 8;
    tile[r][tx] = w[(size_t)(k0 + r) * N + n0 + tx];
  }
  __syncthreads();
#pragma unroll
  for (int i = 0; i < 4; ++i) {
    int r = ty + i * 8;
    wt[(size_t)(n0 + r) * K + k0 + tx] = __float2bfloat16(tile[tx][r]);
  }
}

// batched 1024x1024 transpose-convert: z selects {wq,wk,wv,wo} -> out + z*1Mi
__global__ __launch_bounds__(256) void convT4(const float* __restrict__ w0,
                                              const float* __restrict__ w1,
                                              const float* __restrict__ w2,
                                              const float* __restrict__ w3,
                                              __hip_bfloat16* __restrict__ out) {
  __shared__ float tile[32][33];
  int z = blockIdx.z;
  const float* w = (z == 0) ? w0 : (z == 1) ? w1 : (z == 2) ? w2 : w3;
  __hip_bfloat16* wt = out + (size_t)z * 1024 * 1024;
  int k0 = blockIdx.y * 32, n0 = blockIdx.x * 32;
  int tx = threadIdx.x & 31, ty = threadIdx.x >> 5;
#pragma unroll
  for (int i = 0; i < 4; ++i) {
    int r = ty + i * 8;
    tile[r][tx] = w[(size_t)(k0 + r) * 1024 + n0 + tx];
  }
  __syncthreads();
#pragma unroll
  for (int i = 0; i < 4; ++i) {
    int r = ty + i * 8;
    wt[(size_t)(n0 + r) * 1024 + k0 + tx] = __float2bfloat16(tile[tx][r]);
  }
}

// ---------------- LayerNorm (fp32 in -> bf16 out), one wave per row ----------
__global__ __launch_bounds__(256) void ln_bf16(const float* __restrict__ x,
                                               const float* __restrict__ g,
                                               const float* __restrict__ be,
                                               __hip_bfloat16* __restrict__ out) {
  int w = threadIdx.x >> 6, lane = threadIdx.x & 63;
  int row = blockIdx.x * 4 + w;
  const float* xr = x + (size_t)row * DD;
  float4 v[4];
  float sum = 0.f, sq = 0.f;
#pragma unroll
  for (int i = 0; i < 4; ++i) {
    v[i] = *(const float4*)(xr + lane * 4 + i * 256);
    sum += v[i].x + v[i].y + v[i].z + v[i].w;
    sq += v[i].x * v[i].x + v[i].y * v[i].y + v[i].z * v[i].z + v[i].w * v[i].w;
  }
#pragma unroll
  for (int off = 1; off < 64; off <<= 1) {
    sum += __shfl_xor(sum, off);
    sq += __shfl_xor(sq, off);
  }
  float mu = sum * (1.f / 1024.f);
  float var = sq * (1.f / 1024.f) - mu * mu;
  float rs = rsqrtf(var + 1e-12f);
  __hip_bfloat16* orow = out + (size_t)row * DD;
#pragma unroll
  for (int i = 0; i < 4; ++i) {
    int c = lane * 4 + i * 256;
    float4 gg = *(const float4*)(g + c);
    float4 bb = *(const float4*)(be + c);
    short4 o;
    o.x = f2bf((v[i].x - mu) * rs * gg.x + bb.x);
    o.y = f2bf((v[i].y - mu) * rs * gg.y + bb.y);
    o.z = f2bf((v[i].z - mu) * rs * gg.z + bb.z);
    o.w = f2bf((v[i].w - mu) * rs * gg.w + bb.w);
    *(short4*)((short*)orow + c) = o;
  }
}

// ---------------- GEMM: C[M,N] = A[M,K] (bf16) * BT[N,K]^T + epilogue --------
// m97 structure: 128x128 tile, BK=32, 4 waves, gl_lds16 width 16.
// Epilogues bounce through LDS (272B-stride rows) for coalesced 16B stores.
// EPI 1: +bias, fast-gelu -> bf16                      [FF1]
// EPI 5: QKV fused (N=3072): Q,K +bias -> bf16; V +bias -> bf16 transposed
// EPI 7: raw -> bf16 partial @ C0 + z*4Mi elems        [O-proj split-K]
// EPI 8: raw -> bf16 partial @ C0 + {0,4Mi,12Mi} elems [FF2 split-K]
template <int EPI>
__global__ __launch_bounds__(256, 4) void gemm_bt(
    const __hip_bfloat16* __restrict__ A, const __hip_bfloat16* __restrict__ BT,
    const float* __restrict__ bA, const float* __restrict__ bB,
    const float* __restrict__ bC,
    void* __restrict__ C0, void* __restrict__ C1, void* __restrict__ C2,
    int M, int N, int K, int kSplit) {
  __shared__ __align__(16) char smem[34816];  // As@0 (8KB), Bs@8KB; epi arena
  short* As = (short*)smem;
  short* Bs = (short*)(smem + 8192);
  const int t = threadIdx.x, lane = t & 63, w = t >> 6;
  const int m0 = blockIdx.y * 128, n0 = blockIdx.x * 128;
  const int wm = (w >> 1) * 64, wn = (w & 1) * 64;
  const int row16 = lane & 15, grp = lane >> 4;
  const int arow = t >> 2, achunk = t & 3;
  f32x4 acc[4][4] = {};

  const int steps = K >> 5;
  const int z = blockIdx.z;
  const int sBeg = (z * steps) / kSplit, sEnd = ((z + 1) * steps) / kSplit;

  for (int s = sBeg; s < sEnd; ++s) {
    const int kt = s << 5;
    __syncthreads();
#pragma unroll
    for (int j = 0; j < 2; ++j) {
      int r = arow + j * 64;
      gl_lds16(A + (size_t)(m0 + r) * K + kt + achunk * 8,
               (char*)As + r * 64 + achunk * 16);
      gl_lds16(BT + (size_t)(n0 + r) * K + kt + achunk * 8,
               (char*)Bs + r * 64 + achunk * 16);
    }
    __syncthreads();
    bf16x8 af[4], bfr[4];
#pragma unroll
    for (int f = 0; f < 4; ++f) {
      af[f] = *(const bf16x8*)((const char*)As + (wm + f * 16 + row16) * 64 + grp * 16);
      bfr[f] = *(const bf16x8*)((const char*)Bs + (wn + f * 16 + row16) * 64 + grp * 16);
    }
#pragma unroll
    for (int mf = 0; mf < 4; ++mf)
#pragma unroll
      for (int nf = 0; nf < 4; ++nf)
        acc[mf][nf] =
            __builtin_amdgcn_mfma_f32_16x16x32_bf16(af[mf], bfr[nf], acc[mf][nf], 0, 0, 0);
  }

  __syncthreads();  // all LDS reads done before epilogue overwrites the arena

  // ---------------- V section of QKV: transposed bounce ----------------
  if constexpr (EPI == 5) {
    if (n0 >= 2048) {
#pragma unroll
      for (int nf = 0; nf < 4; ++nf) {
        int vloc = wn + nf * 16 + row16;           // local vr 0..127
        float bv = bC[n0 - 2048 + vloc];
#pragma unroll
        for (int mf = 0; mf < 4; ++mf) {
          int tloc = wm + mf * 16 + grp * 4;       // local token
          f32x4 a = acc[mf][nf];
          *(uint2*)(smem + vloc * 272 + tloc * 2) =
              make_uint2(pk2(a[0] + bv, a[1] + bv), pk2(a[2] + bv, a[3] + bv));
        }
      }
      __syncthreads();
      int vrBase = ((m0 >> 11) << 10) + (n0 - 2048);
      int mcol = m0 & 2047;
#pragma unroll
      for (int i = 0; i < 8; ++i) {
        int c = t + i * 256;
        int vr = c >> 4, tc = c & 15;
        u32x4 vv = *(const u32x4*)(smem + vr * 272 + tc * 16);
        *(u32x4*)((__hip_bfloat16*)C2 + (size_t)(vrBase + vr) * 2048 + mcol + tc * 8) = vv;
      }
      return;
    }
  }

  // ---------------- row-major bounce (EPI 1, 5-Q/K, 7, 8) ----------------
  __hip_bfloat16* outP = nullptr;
  int ldO = N, colB = n0;
  const float* bp = nullptr;
  if constexpr (EPI == 1) { outP = (__hip_bfloat16*)C0; bp = bA; }
  if constexpr (EPI == 5) {
    const bool isK = n0 >= 1024;
    outP = (__hip_bfloat16*)(isK ? C1 : C0);
    bp = isK ? bB : bA;
    ldO = 1024; colB = n0 & 1023;
  }
  if constexpr (EPI == 7) outP = (__hip_bfloat16*)C0 + (size_t)z * 4194304ull;
  if constexpr (EPI == 8)
    outP = (__hip_bfloat16*)C0 + ((z == 0) ? 0ull : ((z == 1) ? 4194304ull : 12582912ull));

#pragma unroll
  for (int nf = 0; nf < 4; ++nf) {
    int nn = wn + nf * 16 + row16;
    float bv = bp ? bp[colB + nn] : 0.f;
#pragma unroll
    for (int mf = 0; mf < 4; ++mf) {
      int mloc = wm + mf * 16 + grp * 4;
      f32x4 a = acc[mf][nf];
#pragma unroll
      for (int r = 0; r < 4; ++r) {
        float v = a[r] + bv;
        if constexpr (EPI == 1) v = gelu_fast(v);
        *(short*)(smem + (mloc + r) * 272 + nn * 2) = f2bf(v);
      }
    }
  }
  __syncthreads();
#pragma unroll
  for (int i = 0; i < 8; ++i) {
    int c = t + i * 256;
    int mmr = c >> 4, nc = c & 15;
    u32x4 vv = *(const u32x4*)(smem + mmr * 272 + nc * 16);
    *(u32x4*)(outP + (size_t)(m0 + mmr) * ldO + colB + nc * 8) = vv;
  }
}

// ---------------- FF2 split-K reduce: out = h1 + b2 + sum(3 partials) --------
__global__ __launch_bounds__(256) void reduce3(const __hip_bfloat16* __restrict__ p0,
                                               const __hip_bfloat16* __restrict__ p1,
                                               const __hip_bfloat16* __restrict__ p2,
                                               const float* __restrict__ h1,
                                               const float* __restrict__ b2,
                                               float* __restrict__ out) {
  int idx = (blockIdx.x * 256 + threadIdx.x) * 8;
  int n = idx & 1023;
  bf16x8 a = *(const bf16x8*)(p0 + idx);
  bf16x8 b = *(const bf16x8*)(p1 + idx);
  bf16x8 c = *(const bf16x8*)(p2 + idx);
  float4 hA = *(const float4*)(h1 + idx), hB = *(const float4*)(h1 + idx + 4);
  float4 bA = *(const float4*)(b2 + n), bB = *(const float4*)(b2 + n + 4);
  float o[8];
#pragma unroll
  for (int j = 0; j < 8; ++j) o[j] = bf2f(a[j]) + bf2f(b[j]) + bf2f(c[j]);
  float4 r0 = make_float4(o[0] + hA.x + bA.x, o[1] + hA.y + bA.y,
                          o[2] + hA.z + bA.z, o[3] + hA.w + bA.w);
  float4 r1 = make_float4(o[4] + hB.x + bB.x, o[5] + hB.y + bB.y,
                          o[6] + hB.z + bB.z, o[7] + hB.w + bB.w);
  *(float4*)(out + idx) = r0;
  *(float4*)(out + idx + 4) = r1;
}

// -------- fused O-proj reduce + LN2: h1 = x+bo+sum(4 partials); h2 = LN(h1) --
// 2 token rows per block; 128 threads (2 waves) per row, 8 elems each.
__global__ __launch_bounds__(256) void reduce4_ln(
    const __hip_bfloat16* __restrict__ p0, const __hip_bfloat16* __restrict__ p1,
    const __hip_bfloat16* __restrict__ p2, const __hip_bfloat16* __restrict__ p3,
    const float* __restrict__ x, const float* __restrict__ bo,
    const float* __restrict__ g, const float* __restrict__ be,
    float* __restrict__ h1, __hip_bfloat16* __restrict__ h2) {
  __shared__ float red[4][2];
  const int tid = threadIdx.x;
  const int rowHalf = tid >> 7, tloc = tid & 127, wv = tid >> 6;
  const size_t idx = ((size_t)blockIdx.x * 2 + rowHalf) * 1024 + tloc * 8;
  const int n = tloc * 8;
  bf16x8 a = *(const bf16x8*)(p0 + idx);
  bf16x8 b = *(const bf16x8*)(p1 + idx);
  bf16x8 c = *(const bf16x8*)(p2 + idx);
  bf16x8 d = *(const bf16x8*)(p3 + idx);
  float4 xA = *(const float4*)(x + idx), xB = *(const float4*)(x + idx + 4);
  float4 bA = *(const float4*)(bo + n), bB = *(const float4*)(bo + n + 4);
  float o[8];
#pragma unroll
  for (int j = 0; j < 8; ++j)
    o[j] = (bf2f(a[j]) + bf2f(b[j])) + (bf2f(c[j]) + bf2f(d[j]));
  o[0] += xA.x + bA.x; o[1] += xA.y + bA.y; o[2] += xA.z + bA.z; o[3] += xA.w + bA.w;
  o[4] += xB.x + bB.x; o[5] += xB.y + bB.y; o[6] += xB.z + bB.z; o[7] += xB.w + bB.w;
  *(float4*)(h1 + idx) = make_float4(o[0], o[1], o[2], o[3]);
  *(float4*)(h1 + idx + 4) = make_float4(o[4], o[5], o[6], o[7]);
  float s = 0.f, sq = 0.f;
#pragma unroll
  for (int j = 0; j < 8; ++j) { s += o[j]; sq += o[j] * o[j]; }
#pragma unroll
  for (int off = 1; off < 64; off <<= 1) {
    s += __shfl_xor(s, off);
    sq += __shfl_xor(sq, off);
  }
  if ((tid & 63) == 0) { red[wv][0] = s; red[wv][1] = sq; }
  __syncthreads();
  float S = red[rowHalf * 2][0] + red[rowHalf * 2 + 1][0];
  float SQ = red[rowHalf * 2][1] + red[rowHalf * 2 + 1][1];
  float mu = S * (1.f / 1024.f);
  float var = SQ * (1.f / 1024.f) - mu * mu;
  float rs = rsqrtf(var + 1e-12f);
  float4 gA = *(const float4*)(g + n), gB = *(const float4*)(g + n + 4);
  float4 eA = *(const float4*)(be + n), eB = *(const float4*)(be + n + 4);
  u32x4 pkd;
  pkd[0] = pk2((o[0] - mu) * rs * gA.x + eA.x, (o[1] - mu) * rs * gA.y + eA.y);
  pkd[1] = pk2((o[2] - mu) * rs * gA.z + eA.z, (o[3] - mu) * rs * gA.w + eA.w);
  pkd[2] = pk2((o[4] - mu) * rs * gB.x + eB.x, (o[5] - mu) * rs * gB.y + eB.y);
  pkd[3] = pk2((o[6] - mu) * rs * gB.z + eB.z, (o[7] - mu) * rs * gB.w + eB.w);
  *(u32x4*)((short*)h2 + idx) = pkd;
}

// ---------------- Flash attention, split-KV=2: partial ctx + (m,l) ----------
__global__ __launch_bounds__(512) void flash_attn2(
    const __hip_bfloat16* __restrict__ Q,
    const __hip_bfloat16* __restrict__ Kg,
    const __hip_bfloat16* __restrict__ VTg,
    const float* __restrict__ mask,
    __hip_bfloat16* __restrict__ pctx0,
    __hip_bfloat16* __restrict__ pctx1,
    float2* __restrict__ ml) {
  __shared__ __align__(16) char lds[33280];
  const int t = threadIdx.x, lane = t & 63, w = t >> 6;
  const int l31 = lane & 31, hi = lane >> 5;
  const int q0 = blockIdx.x * 256;
  const int bh = blockIdx.y, b = bh >> 4, h = bh & 15;
  const int z = blockIdx.z;
  const int kvBase = z * (SS / 2);
  __hip_bfloat16* pctx = z ? pctx1 : pctx0;
  const int qrow = q0 + w * 32 + l31;

  bf16x8 qf[4];
  {
    const __hip_bfloat16* qp = Q + ((size_t)(b * SS + qrow)) * DD + h * HDIM + hi * 8;
    qf[0] = *(const bf16x8*)(qp);
    qf[1] = *(const bf16x8*)(qp + 16);
    qf[2] = *(const bf16x8*)(qp + 32);
    qf[3] = *(const bf16x8*)(qp + 48);
  }
  f32x16 ctx0 = {}, ctx1 = {};
  float m = -1e30f, l = 0.f, mC = -1.44e30f;

  auto stage = [&](int buf, int kv0) {
    int r = t >> 3, c = t & 7;
    gl_lds16(Kg + ((size_t)(b * SS + kv0 + r)) * DD + h * HDIM + ((c ^ (r & 7)) * 8),
             lds + buf * 8192 + t * 16);
    gl_lds16(VTg + ((size_t)(bh * 64 + r)) * 2048 + kv0 + ((c ^ (r & 7)) * 8),
             lds + 16384 + buf * 8192 + t * 16);
    if (t < 64) *(float*)(lds + 32768 + buf * 256 + t * 4) = mask[b * SS + kv0 + t];
  };

  stage(0, kvBase);
  const int NIT = SS / 128;
  for (int it = 0; it < NIT; ++it) {
    __syncthreads();
    if (it + 1 < NIT) stage((it + 1) & 1, kvBase + (it + 1) * 64);
    const char* Kb = lds + (it & 1) * 8192;
    const char* Vb = lds + 16384 + (it & 1) * 8192;
    const float* mk = (const float*)(lds + 32768 + (it & 1) * 256);

    f32x16 s0 = {}, s1 = {};
#pragma unroll
    for (int kc = 0; kc < 4; ++kc) {
      int c = kc * 2 + hi;
      int r0 = l31, r1 = 32 + l31;
      bf16x8 ka0 = *(const bf16x8*)(Kb + r0 * 128 + ((c ^ (r0 & 7)) << 4));
      bf16x8 ka1 = *(const bf16x8*)(Kb + r1 * 128 + ((c ^ (r1 & 7)) << 4));
      s0 = __builtin_amdgcn_mfma_f32_32x32x16_bf16(ka0, qf[kc], s0, 0, 0, 0);
      s1 = __builtin_amdgcn_mfma_f32_32x32x16_bf16(ka1, qf[kc], s1, 0, 0, 0);
    }
#pragma unroll
    for (int g = 0; g < 4; ++g) {
      float4 mg0 = *(const float4*)(mk + g * 8 + hi * 4);
      float4 mg1 = *(const float4*)(mk + 32 + g * 8 + hi * 4);
      const float* m0p = (const float*)&mg0;
      const float* m1p = (const float*)&mg1;
#pragma unroll
      for (int i = 0; i < 4; ++i) {
        s0[g * 4 + i] = fmaf(s0[g * 4 + i], 0.125f, m0p[i]);
        s1[g * 4 + i] = fmaf(s1[g * 4 + i], 0.125f, m1p[i]);
      }
    }
    float pmax;
    {
      f32x16 q8;
#pragma unroll
      for (int r = 0; r < 16; ++r) q8[r] = fmaxf(s0[r], s1[r]);
#pragma unroll
      for (int r = 0; r < 8; ++r) q8[r] = fmaxf(q8[r], q8[r + 8]);
#pragma unroll
      for (int r = 0; r < 4; ++r) q8[r] = fmaxf(q8[r], q8[r + 4]);
      pmax = fmaxf(fmaxf(q8[0], q8[1]), fmaxf(q8[2], q8[3]));
      pmax = fmaxf(pmax, __shfl_xor(pmax, 32));
    }
    if (__any(pmax > m + 8.0f)) {
      float mnew = fmaxf(m, pmax);
      float fac = EXP2((m - mnew) * LOG2E);
      l *= fac;
#pragma unroll
      for (int r = 0; r < 16; ++r) { ctx0[r] *= fac; ctx1[r] *= fac; }
      m = mnew;
      mC = m * LOG2E;
    }
    float rsA = 0.f, rsB = 0.f;
#pragma unroll
    for (int r = 0; r < 16; ++r) {
      s0[r] = EXP2(fmaf(s0[r], LOG2E, -mC));
      s1[r] = EXP2(fmaf(s1[r], LOG2E, -mC));
      rsA += s0[r];
      rsB += s1[r];
    }
    rsA += rsB;
    rsA += __shfl_xor(rsA, 32);
    l += rsA;

    unsigned W0[8], W1[8];
#pragma unroll
    for (int g = 0; g < 4; ++g) {
      W0[g * 2] = pk2(s0[g * 4 + 0], s0[g * 4 + 1]);
      W0[g * 2 + 1] = pk2(s0[g * 4 + 2], s0[g * 4 + 3]);
      W1[g * 2] = pk2(s1[g * 4 + 0], s1[g * 4 + 1]);
      W1[g * 2 + 1] = pk2(s1[g * 4 + 2], s1[g * 4 + 3]);
    }
    unsigned swA0 = __shfl_xor(hi ? W0[0] : W0[2], 32);
    unsigned swA1 = __shfl_xor(hi ? W0[1] : W0[3], 32);
    unsigned swB0 = __shfl_xor(hi ? W0[4] : W0[6], 32);
    unsigned swB1 = __shfl_xor(hi ? W0[5] : W0[7], 32);
    unsigned swC0 = __shfl_xor(hi ? W1[0] : W1[2], 32);
    unsigned swC1 = __shfl_xor(hi ? W1[1] : W1[3], 32);
    unsigned swD0 = __shfl_xor(hi ? W1[4] : W1[6], 32);
    unsigned swD1 = __shfl_xor(hi ? W1[5] : W1[7], 32);
    u32x4 pb[4];
    pb[0] = hi ? (u32x4){swA0, swA1, W0[2], W0[3]} : (u32x4){W0[0], W0[1], swA0, swA1};
    pb[1] = hi ? (u32x4){swB0, swB1, W0[6], W0[7]} : (u32x4){W0[4], W0[5], swB0, swB1};
    pb[2] = hi ? (u32x4){swC0, swC1, W1[2], W1[3]} : (u32x4){W1[0], W1[1], swC0, swC1};
    pb[3] = hi ? (u32x4){swD0, swD1, W1[6], W1[7]} : (u32x4){W1[4], W1[5], swD0, swD1};

#pragma unroll
    for (int kc = 0; kc < 4; ++kc) {
      bf16x8 pbf = __builtin_bit_cast(bf16x8, pb[kc]);
      int c = kc * 2 + hi;
      int r0 = l31, r1 = 32 + l31;
      bf16x8 va0 = *(const bf16x8*)(Vb + r0 * 128 + ((c ^ (r0 & 7)) << 4));
      bf16x8 va1 = *(const bf16x8*)(Vb + r1 * 128 + ((c ^ (r1 & 7)) << 4));
      ctx0 = __builtin_amdgcn_mfma_f32_32x32x16_bf16(va0, pbf, ctx0, 0, 0, 0);
      ctx1 = __builtin_amdgcn_mfma_f32_32x32x16_bf16(va1, pbf, ctx1, 0, 0, 0);
    }
  }

  if (hi == 0) ml[((size_t)z * NTOK + b * SS + qrow) * HH + h] = make_float2(m, l);

  __syncthreads();
  {
    int row = w * 32 + l31;
#pragma unroll
    for (int dt = 0; dt < 2; ++dt) {
#pragma unroll
      for (int g = 0; g < 4; ++g) {
        unsigned lo2 = dt ? pk2(ctx1[g * 4 + 0], ctx1[g * 4 + 1]) : pk2(ctx0[g * 4 + 0], ctx0[g * 4 + 1]);
        unsigned hi2 = dt ? pk2(ctx1[g * 4 + 2], ctx1[g * 4 + 3]) : pk2(ctx0[g * 4 + 2], ctx0[g * 4 + 3]);
        int c = dt * 4 + g;
        *(uint2*)(lds + row * 128 + ((c ^ (row & 7)) << 4) + hi * 8) = make_uint2(lo2, hi2);
      }
    }
  }
  __syncthreads();
  {
    int r = t >> 1;
    size_t tok = (size_t)(b * SS + q0 + r);
#pragma unroll
    for (int i = 0; i < 4; ++i) {
      int c = (t & 1) * 4 + i;
      u32x4 vv = *(const u32x4*)(lds + r * 128 + ((c ^ (r & 7)) << 4));
      *(u32x4*)((short*)pctx + tok * DD + h * HDIM + c * 8) = vv;
    }
  }
}

// ---------------- merge two KV-half partials -> ctxb (bf16) ------------------
__global__ __launch_bounds__(256) void mergeAttn(
    const __hip_bfloat16* __restrict__ p0, const __hip_bfloat16* __restrict__ p1,
    const float2* __restrict__ ml, __hip_bfloat16* __restrict__ out) {
  int tok = blockIdx.x, tid = threadIdx.x;
  int h = tid >> 4;
  float2 a = ml[(size_t)tok * HH + h];
  float2 b = ml[(size_t)(NTOK + tok) * HH + h];
  float M = fmaxf(a.x, b.x);
  float w0 = EXP2((a.x - M) * LOG2E), w1 = EXP2((b.x - M) * LOG2E);
  float inv = 1.0f / (w0 * a.y + w1 * b.y);
  w0 *= inv; w1 *= inv;
  size_t idx = (size_t)tok * DD + tid * 4;
  short4 c0 = *(const short4*)((const short*)p0 + idx);
  short4 c1 = *(const short4*)((const short*)p1 + idx);
  unsigned lo = pk2(w0 * bf2f(c0.x) + w1 * bf2f(c1.x),
                    w0 * bf2f(c0.y) + w1 * bf2f(c1.y));
  unsigned hi2 = pk2(w0 * bf2f(c0.z) + w1 * bf2f(c1.z),
                     w0 * bf2f(c0.w) + w1 * bf2f(c1.w));
  *(uint2*)((short*)out + idx) = make_uint2(lo, hi2);
}

// ---------------- host-side orchestration ------------------------------------
extern "C" void kernel_launch(void* const* d_in, const int* in_sizes, int n_in,
                              void* d_out, int out_size, void* d_ws, size_t ws_size,
                              hipStream_t stream) {
  const float* x = (const float*)d_in[0];
  const float* mask = (const float*)d_in[1];
  const float* wq = (const float*)d_in[2];
  const float* bq = (const float*)d_in[3];
  const float* wk = (const float*)d_in[4];
  const float* bk = (const float*)d_in[5];
  const float* wv = (const float*)d_in[6];
  const float* bv = (const float*)d_in[7];
  const float* wo = (const float*)d_in[8];
  const float* bo = (const float*)d_in[9];
  const float* w1 = (const float*)d_in[10];
  const float* b1 = (const float*)d_in[11];
  const float* w2 = (const float*)d_in[12];
  const float* b2 = (const float*)d_in[13];
  const float* g1 = (const float*)d_in[14];
  const float* be1 = (const float*)d_in[15];
  const float* g2 = (const float*)d_in[16];
  const float* be2 = (const float*)d_in[17];

  char* ws = (char*)d_ws;
  const size_t MB = 1024ull * 1024ull;
  __hip_bfloat16* wqkvT = (__hip_bfloat16*)(ws + 0 * MB);   // [3072][1024] + woT
  __hip_bfloat16* woT = (__hip_bfloat16*)(ws + 6 * MB);
  __hip_bfloat16* w1T = (__hip_bfloat16*)(ws + 8 * MB);
  __hip_bfloat16* w2T = (__hip_bfloat16*)(ws + 16 * MB);
  __hip_bfloat16* xn = (__hip_bfloat16*)(ws + 24 * MB);     // later h2
  __hip_bfloat16* qb = (__hip_bfloat16*)(ws + 32 * MB);
  __hip_bfloat16* kb = (__hip_bfloat16*)(ws + 40 * MB);
  __hip_bfloat16* vtb = (__hip_bfloat16*)(ws + 48 * MB);    // V^T [32][64][2048]
  __hip_bfloat16* ctxb = (__hip_bfloat16*)(ws + 56 * MB);
  float* h1 = (float*)(ws + 64 * MB);
  __hip_bfloat16* h2 = xn;
  __hip_bfloat16* a1 = qb;
  __hip_bfloat16* pctx0 = (__hip_bfloat16*)(ws + 24 * MB);
  __hip_bfloat16* pctx1 = (__hip_bfloat16*)(ws + 64 * MB);
  float2* mlbuf = (float2*)(ws + 72 * MB);

  // wq,wk,wv -> wqkvT (0..6MB), wo -> woT (6..8MB) in one launch
  convT4<<<dim3(32, 32, 4), 256, 0, stream>>>(wq, wk, wv, wo, wqkvT);
  convT<<<dim3(128, 32), 256, 0, stream>>>(w1, w1T, 1024, 4096);
  convT<<<dim3(32, 128), 256, 0, stream>>>(w2, w2T, 4096, 1024);

  ln_bf16<<<1024, 256, 0, stream>>>(x, g1, be1, xn);

  // fused QKV: M=4096, N=3072, K=1024 -> 768 blocks (3/CU)
  gemm_bt<5><<<dim3(24, 32), 256, 0, stream>>>(
      xn, wqkvT, bq, bk, bv, qb, kb, vtb, NTOK, 3072, 1024, 1);

  // flash attention split-KV=2 -> partials, then merge
  flash_attn2<<<dim3(8, 32, 2), 512, 0, stream>>>(qb, kb, vtb, mask,
                                                  pctx0, pctx1, mlbuf);
  mergeAttn<<<4096, 256, 0, stream>>>(pctx0, pctx1, mlbuf, ctxb);

  // O-proj split-K=4 -> bf16 partials @ 24+8z MB (1024 blocks)
  gemm_bt<7><<<dim3(8, 32, 4), 256, 0, stream>>>(
      ctxb, woT, nullptr, nullptr, nullptr, ws + 24 * MB, nullptr, nullptr,
      NTOK, 1024, 1024, 4);

  // fused reduce4 + LN2 -> h1 (f32) and h2 (bf16)
  reduce4_ln<<<2048, 256, 0, stream>>>((__hip_bfloat16*)(ws + 24 * MB),
                                       (__hip_bfloat16*)(ws + 32 * MB),
                                       (__hip_bfloat16*)(ws + 40 * MB),
                                       (__hip_bfloat16*)(ws + 48 * MB),
                                       x, bo, g2, be2, h1, h2);

  // FF1 + fast gelu: M=4096, N=4096, K=1024 -> 1024 blocks
  gemm_bt<1><<<dim3(32, 32), 256, 0, stream>>>(
      h2, w1T, b1, nullptr, nullptr, a1, nullptr, nullptr, NTOK, FFD, 1024, 1);

  // FF2 split-K=3 -> bf16 partials @ 0/8/24 MB (768 blocks)
  gemm_bt<8><<<dim3(8, 32, 3), 256, 0, stream>>>(
      a1, w2T, nullptr, nullptr, nullptr, ws, nullptr, nullptr,
      NTOK, 1024, FFD, 3);

  reduce3<<<2048, 256, 0, stream>>>((__hip_bfloat16*)(ws + 0 * MB),
                                    (__hip_bfloat16*)(ws + 8 * MB),
                                    (__hip_bfloat16*)(ws + 24 * MB),
                                    h1, b2, (float*)d_out);
}

// Round 10
// 262.033 us; speedup vs baseline: 1.0986x; 1.0440x over previous
//
#include <hip/hip_runtime.h>
#include <hip/hip_bf16.h>
#include <math.h>

// Transformer layer: B=2 S=2048 D=1024 H=16 HD=64 FF=4096, fp32 I/O.
// Heavy GEMMs: m97-style 128x128 bf16 MFMA tiles (2-barrier loop, 4 blocks/CU),
// coalesced epilogues via LDS bounce, fast tanh-gelu.
// Attention: flash split-KV=2 (reg-capped to 128 for 16 waves/CU, XCD-grouped
// K/V reuse) + merge. Fused reduce4+LN2.

#define BB 2
#define SS 2048
#define DD 1024
#define HH 16
#define HDIM 64
#define FFD 4096
#define NTOK (BB*SS)
#define LOG2E 1.4426950408889634f

typedef __attribute__((ext_vector_type(8))) short bf16x8;
typedef __attribute__((ext_vector_type(4))) float f32x4;
typedef __attribute__((ext_vector_type(16))) float f32x16;
typedef __attribute__((ext_vector_type(4))) unsigned int u32x4;

#if __has_builtin(__builtin_amdgcn_exp2f)
#define EXP2(x) __builtin_amdgcn_exp2f(x)
#else
#define EXP2(x) exp2f(x)
#endif

__device__ __forceinline__ void gl_lds16(const void* g, void* l) {
  __builtin_amdgcn_global_load_lds(
      (const __attribute__((address_space(1))) unsigned int*)g,
      (__attribute__((address_space(3))) unsigned int*)l, 16, 0, 0);
}

// RNE float->bf16 bits (finite inputs only)
__device__ __forceinline__ short f2bf(float f) {
  unsigned int u = __builtin_bit_cast(unsigned int, f);
  unsigned int r = (u + 0x7fffu + ((u >> 16) & 1u)) >> 16;
  return (short)r;
}
__device__ __forceinline__ float bf2f(short s) {
  return __builtin_bit_cast(float, ((unsigned)(unsigned short)s) << 16);
}
// packed pair via HW cvt (RNE)
__device__ __forceinline__ unsigned pk2(float lo, float hi) {
  unsigned r;
  asm("v_cvt_pk_bf16_f32 %0, %1, %2" : "=v"(r) : "v"(lo), "v"(hi));
  return r;
}
// gelu, tanh form via exp2 (max dev vs erf-gelu ~3e-4)
__device__ __forceinline__ float gelu_fast(float v) {
  float v2 = v * v;
  float u = v * (0.7978845608028654f + 0.03567740814183427f * v2);
  float e = EXP2(u * 2.8853900817779268f);  // e^(2u)
  return v * (1.0f - 1.0f / (e + 1.0f));
}

// ---------------- transpose + fp32->bf16 convert: wt[n][k] = bf16(w[k][n]) ----
__global__ __launch_bounds__(256) void convT(const float* __restrict__ w,
                                             __hip_bfloat16* __restrict__ wt,
                                             int K, int N) {
  __shared__ float tile[32][33];
  int k0 = blockIdx.y * 32, n0 = blockIdx.x * 32;
  int tx = threadIdx.x & 31, ty = threadIdx.x >> 5;
#pragma unroll
  for (int i = 0; i < 4; ++i) {
    int r = ty + i * 8;
    tile[r][tx] = w[(size_t)(k0 + r) * N + n0 + tx];
  }
  __syncthreads();
#pragma unroll
  for (int i = 0; i < 4; ++i) {
    int r = ty + i * 8;
    wt[(size_t)(n0 + r) * K + k0 + tx] = __float2bfloat16(tile[tx][r]);
  }
}

// batched 1024x1024 transpose-convert: z selects {wq,wk,wv,wo} -> out + z*1Mi
__global__ __launch_bounds__(256) void convT4(const float* __restrict__ w0,
                                              const float* __restrict__ w1,
                                              const float* __restrict__ w2,
                                              const float* __restrict__ w3,
                                              __hip_bfloat16* __restrict__ out) {
  __shared__ float tile[32][33];
  int z = blockIdx.z;
  const float* w = (z == 0) ? w0 : (z == 1) ? w1 : (z == 2) ? w2 : w3;
  __hip_bfloat16* wt = out + (size_t)z * 1024 * 1024;
  int k0 = blockIdx.y * 32, n0 = blockIdx.x * 32;
  int tx = threadIdx.x & 31, ty = threadIdx.x >> 5;
#pragma unroll
  for (int i = 0; i < 4; ++i) {
    int r = ty + i * 8;
    tile[r][tx] = w[(size_t)(k0 + r) * 1024 + n0 + tx];
  }
  __syncthreads();
#pragma unroll
  for (int i = 0; i < 4; ++i) {
    int r = ty + i * 8;
    wt[(size_t)(n0 + r) * 1024 + k0 + tx] = __float2bfloat16(tile[tx][r]);
  }
}

// ---------------- LayerNorm (fp32 in -> bf16 out), one wave per row ----------
__global__ __launch_bounds__(256) void ln_bf16(const float* __restrict__ x,
                                               const float* __restrict__ g,
                                               const float* __restrict__ be,
                                               __hip_bfloat16* __restrict__ out) {
  int w = threadIdx.x >> 6, lane = threadIdx.x & 63;
  int row = blockIdx.x * 4 + w;
  const float* xr = x + (size_t)row * DD;
  float4 v[4];
  float sum = 0.f, sq = 0.f;
#pragma unroll
  for (int i = 0; i < 4; ++i) {
    v[i] = *(const float4*)(xr + lane * 4 + i * 256);
    sum += v[i].x + v[i].y + v[i].z + v[i].w;
    sq += v[i].x * v[i].x + v[i].y * v[i].y + v[i].z * v[i].z + v[i].w * v[i].w;
  }
#pragma unroll
  for (int off = 1; off < 64; off <<= 1) {
    sum += __shfl_xor(sum, off);
    sq += __shfl_xor(sq, off);
  }
  float mu = sum * (1.f / 1024.f);
  float var = sq * (1.f / 1024.f) - mu * mu;
  float rs = rsqrtf(var + 1e-12f);
  __hip_bfloat16* orow = out + (size_t)row * DD;
#pragma unroll
  for (int i = 0; i < 4; ++i) {
    int c = lane * 4 + i * 256;
    float4 gg = *(const float4*)(g + c);
    float4 bb = *(const float4*)(be + c);
    short4 o;
    o.x = f2bf((v[i].x - mu) * rs * gg.x + bb.x);
    o.y = f2bf((v[i].y - mu) * rs * gg.y + bb.y);
    o.z = f2bf((v[i].z - mu) * rs * gg.z + bb.z);
    o.w = f2bf((v[i].w - mu) * rs * gg.w + bb.w);
    *(short4*)((short*)orow + c) = o;
  }
}

// ---------------- GEMM: C[M,N] = A[M,K] (bf16) * BT[N,K]^T + epilogue --------
// m97 structure: 128x128 tile, BK=32, 4 waves, gl_lds16 width 16.
// Epilogues bounce through LDS (272B-stride rows) for coalesced 16B stores.
// EPI 1: +bias, fast-gelu -> bf16                      [FF1]
// EPI 5: QKV fused (N=3072): Q,K +bias -> bf16; V +bias -> bf16 transposed
// EPI 7: raw -> bf16 partial @ C0 + z*4Mi elems        [O-proj split-K]
// EPI 8: raw -> bf16 partial @ C0 + {0,4Mi,12Mi} elems [FF2 split-K]
template <int EPI>
__global__ __launch_bounds__(256, 4) void gemm_bt(
    const __hip_bfloat16* __restrict__ A, const __hip_bfloat16* __restrict__ BT,
    const float* __restrict__ bA, const float* __restrict__ bB,
    const float* __restrict__ bC,
    void* __restrict__ C0, void* __restrict__ C1, void* __restrict__ C2,
    int M, int N, int K, int kSplit) {
  __shared__ __align__(16) char smem[34816];  // As@0 (8KB), Bs@8KB; epi arena
  short* As = (short*)smem;
  short* Bs = (short*)(smem + 8192);
  const int t = threadIdx.x, lane = t & 63, w = t >> 6;
  const int m0 = blockIdx.y * 128, n0 = blockIdx.x * 128;
  const int wm = (w >> 1) * 64, wn = (w & 1) * 64;
  const int row16 = lane & 15, grp = lane >> 4;
  const int arow = t >> 2, achunk = t & 3;
  f32x4 acc[4][4] = {};

  const int steps = K >> 5;
  const int z = blockIdx.z;
  const int sBeg = (z * steps) / kSplit, sEnd = ((z + 1) * steps) / kSplit;

  for (int s = sBeg; s < sEnd; ++s) {
    const int kt = s << 5;
    __syncthreads();
#pragma unroll
    for (int j = 0; j < 2; ++j) {
      int r = arow + j * 64;
      gl_lds16(A + (size_t)(m0 + r) * K + kt + achunk * 8,
               (char*)As + r * 64 + achunk * 16);
      gl_lds16(BT + (size_t)(n0 + r) * K + kt + achunk * 8,
               (char*)Bs + r * 64 + achunk * 16);
    }
    __syncthreads();
    bf16x8 af[4], bfr[4];
#pragma unroll
    for (int f = 0; f < 4; ++f) {
      af[f] = *(const bf16x8*)((const char*)As + (wm + f * 16 + row16) * 64 + grp * 16);
      bfr[f] = *(const bf16x8*)((const char*)Bs + (wn + f * 16 + row16) * 64 + grp * 16);
    }
#pragma unroll
    for (int mf = 0; mf < 4; ++mf)
#pragma unroll
      for (int nf = 0; nf < 4; ++nf)
        acc[mf][nf] =
            __builtin_amdgcn_mfma_f32_16x16x32_bf16(af[mf], bfr[nf], acc[mf][nf], 0, 0, 0);
  }

  __syncthreads();  // all LDS reads done before epilogue overwrites the arena

  // ---------------- V section of QKV: transposed bounce ----------------
  if constexpr (EPI == 5) {
    if (n0 >= 2048) {
#pragma unroll
      for (int nf = 0; nf < 4; ++nf) {
        int vloc = wn + nf * 16 + row16;           // local vr 0..127
        float bv = bC[n0 - 2048 + vloc];
#pragma unroll
        for (int mf = 0; mf < 4; ++mf) {
          int tloc = wm + mf * 16 + grp * 4;       // local token
          f32x4 a = acc[mf][nf];
          *(uint2*)(smem + vloc * 272 + tloc * 2) =
              make_uint2(pk2(a[0] + bv, a[1] + bv), pk2(a[2] + bv, a[3] + bv));
        }
      }
      __syncthreads();
      int vrBase = ((m0 >> 11) << 10) + (n0 - 2048);
      int mcol = m0 & 2047;
#pragma unroll
      for (int i = 0; i < 8; ++i) {
        int c = t + i * 256;
        int vr = c >> 4, tc = c & 15;
        u32x4 vv = *(const u32x4*)(smem + vr * 272 + tc * 16);
        *(u32x4*)((__hip_bfloat16*)C2 + (size_t)(vrBase + vr) * 2048 + mcol + tc * 8) = vv;
      }
      return;
    }
  }

  // ---------------- row-major bounce (EPI 1, 5-Q/K, 7, 8) ----------------
  __hip_bfloat16* outP = nullptr;
  int ldO = N, colB = n0;
  const float* bp = nullptr;
  if constexpr (EPI == 1) { outP = (__hip_bfloat16*)C0; bp = bA; }
  if constexpr (EPI == 5) {
    const bool isK = n0 >= 1024;
    outP = (__hip_bfloat16*)(isK ? C1 : C0);
    bp = isK ? bB : bA;
    ldO = 1024; colB = n0 & 1023;
  }
  if constexpr (EPI == 7) outP = (__hip_bfloat16*)C0 + (size_t)z * 4194304ull;
  if constexpr (EPI == 8)
    outP = (__hip_bfloat16*)C0 + ((z == 0) ? 0ull : ((z == 1) ? 4194304ull : 12582912ull));

#pragma unroll
  for (int nf = 0; nf < 4; ++nf) {
    int nn = wn + nf * 16 + row16;
    float bv = bp ? bp[colB + nn] : 0.f;
#pragma unroll
    for (int mf = 0; mf < 4; ++mf) {
      int mloc = wm + mf * 16 + grp * 4;
      f32x4 a = acc[mf][nf];
#pragma unroll
      for (int r = 0; r < 4; ++r) {
        float v = a[r] + bv;
        if constexpr (EPI == 1) v = gelu_fast(v);
        *(short*)(smem + (mloc + r) * 272 + nn * 2) = f2bf(v);
      }
    }
  }
  __syncthreads();
#pragma unroll
  for (int i = 0; i < 8; ++i) {
    int c = t + i * 256;
    int mmr = c >> 4, nc = c & 15;
    u32x4 vv = *(const u32x4*)(smem + mmr * 272 + nc * 16);
    *(u32x4*)(outP + (size_t)(m0 + mmr) * ldO + colB + nc * 8) = vv;
  }
}

// ---------------- FF2 split-K reduce: out = h1 + b2 + sum(3 partials) --------
__global__ __launch_bounds__(256) void reduce3(const __hip_bfloat16* __restrict__ p0,
                                               const __hip_bfloat16* __restrict__ p1,
                                               const __hip_bfloat16* __restrict__ p2,
                                               const float* __restrict__ h1,
                                               const float* __restrict__ b2,
                                               float* __restrict__ out) {
  int idx = (blockIdx.x * 256 + threadIdx.x) * 8;
  int n = idx & 1023;
  bf16x8 a = *(const bf16x8*)(p0 + idx);
  bf16x8 b = *(const bf16x8*)(p1 + idx);
  bf16x8 c = *(const bf16x8*)(p2 + idx);
  float4 hA = *(const float4*)(h1 + idx), hB = *(const float4*)(h1 + idx + 4);
  float4 bA = *(const float4*)(b2 + n), bB = *(const float4*)(b2 + n + 4);
  float o[8];
#pragma unroll
  for (int j = 0; j < 8; ++j) o[j] = bf2f(a[j]) + bf2f(b[j]) + bf2f(c[j]);
  float4 r0 = make_float4(o[0] + hA.x + bA.x, o[1] + hA.y + bA.y,
                          o[2] + hA.z + bA.z, o[3] + hA.w + bA.w);
  float4 r1 = make_float4(o[4] + hB.x + bB.x, o[5] + hB.y + bB.y,
                          o[6] + hB.z + bB.z, o[7] + hB.w + bB.w);
  *(float4*)(out + idx) = r0;
  *(float4*)(out + idx + 4) = r1;
}

// -------- fused O-proj reduce + LN2: h1 = x+bo+sum(4 partials); h2 = LN(h1) --
__global__ __launch_bounds__(256) void reduce4_ln(
    const __hip_bfloat16* __restrict__ p0, const __hip_bfloat16* __restrict__ p1,
    const __hip_bfloat16* __restrict__ p2, const __hip_bfloat16* __restrict__ p3,
    const float* __restrict__ x, const float* __restrict__ bo,
    const float* __restrict__ g, const float* __restrict__ be,
    float* __restrict__ h1, __hip_bfloat16* __restrict__ h2) {
  __shared__ float red[4][2];
  const int tid = threadIdx.x;
  const int rowHalf = tid >> 7, tloc = tid & 127, wv = tid >> 6;
  const size_t idx = ((size_t)blockIdx.x * 2 + rowHalf) * 1024 + tloc * 8;
  const int n = tloc * 8;
  bf16x8 a = *(const bf16x8*)(p0 + idx);
  bf16x8 b = *(const bf16x8*)(p1 + idx);
  bf16x8 c = *(const bf16x8*)(p2 + idx);
  bf16x8 d = *(const bf16x8*)(p3 + idx);
  float4 xA = *(const float4*)(x + idx), xB = *(const float4*)(x + idx + 4);
  float4 bA = *(const float4*)(bo + n), bB = *(const float4*)(bo + n + 4);
  float o[8];
#pragma unroll
  for (int j = 0; j < 8; ++j)
    o[j] = (bf2f(a[j]) + bf2f(b[j])) + (bf2f(c[j]) + bf2f(d[j]));
  o[0] += xA.x + bA.x; o[1] += xA.y + bA.y; o[2] += xA.z + bA.z; o[3] += xA.w + bA.w;
  o[4] += xB.x + bB.x; o[5] += xB.y + bB.y; o[6] += xB.z + bB.z; o[7] += xB.w + bB.w;
  *(float4*)(h1 + idx) = make_float4(o[0], o[1], o[2], o[3]);
  *(float4*)(h1 + idx + 4) = make_float4(o[4], o[5], o[6], o[7]);
  float s = 0.f, sq = 0.f;
#pragma unroll
  for (int j = 0; j < 8; ++j) { s += o[j]; sq += o[j] * o[j]; }
#pragma unroll
  for (int off = 1; off < 64; off <<= 1) {
    s += __shfl_xor(s, off);
    sq += __shfl_xor(sq, off);
  }
  if ((tid & 63) == 0) { red[wv][0] = s; red[wv][1] = sq; }
  __syncthreads();
  float S = red[rowHalf * 2][0] + red[rowHalf * 2 + 1][0];
  float SQ = red[rowHalf * 2][1] + red[rowHalf * 2 + 1][1];
  float mu = S * (1.f / 1024.f);
  float var = SQ * (1.f / 1024.f) - mu * mu;
  float rs = rsqrtf(var + 1e-12f);
  float4 gA = *(const float4*)(g + n), gB = *(const float4*)(g + n + 4);
  float4 eA = *(const float4*)(be + n), eB = *(const float4*)(be + n + 4);
  u32x4 pkd;
  pkd[0] = pk2((o[0] - mu) * rs * gA.x + eA.x, (o[1] - mu) * rs * gA.y + eA.y);
  pkd[1] = pk2((o[2] - mu) * rs * gA.z + eA.z, (o[3] - mu) * rs * gA.w + eA.w);
  pkd[2] = pk2((o[4] - mu) * rs * gB.x + eB.x, (o[5] - mu) * rs * gB.y + eB.y);
  pkd[3] = pk2((o[6] - mu) * rs * gB.z + eB.z, (o[7] - mu) * rs * gB.w + eB.w);
  *(u32x4*)((short*)h2 + idx) = pkd;
}

// ---------------- Flash attention, split-KV=2: partial ctx + (m,l) ----------
// 1-D grid of 512; decode groups the 8 q0-blocks of one (bh,z) onto one XCD
// (block i -> XCD i%8 idiom) so K/V re-reads hit that XCD's L2.
// launch_bounds(512,4): cap regs at 128/wave -> 16 waves/CU (2 blocks co-res).
__global__ __launch_bounds__(512, 4) void flash_attn2(
    const __hip_bfloat16* __restrict__ Q,
    const __hip_bfloat16* __restrict__ Kg,
    const __hip_bfloat16* __restrict__ VTg,
    const float* __restrict__ mask,
    __hip_bfloat16* __restrict__ pctx0,
    __hip_bfloat16* __restrict__ pctx1,
    float2* __restrict__ ml) {
  __shared__ __align__(16) char lds[33280];
  const int t = threadIdx.x, lane = t & 63, w = t >> 6;
  const int l31 = lane & 31, hi = lane >> 5;
  // decode: i%8 selects the (bh,z)-group's XCD slot; j/8 picks group page
  const int i = blockIdx.x;
  const int xcd = i & 7, j = i >> 3;
  const int q0i = j & 7, pg = j >> 3;
  const int p = pg * 8 + xcd;
  const int bh = p >> 1, z = p & 1;
  const int q0 = q0i * 256;
  const int b = bh >> 4, h = bh & 15;
  const int kvBase = z * (SS / 2);
  __hip_bfloat16* pctx = z ? pctx1 : pctx0;
  const int qrow = q0 + w * 32 + l31;

  bf16x8 qf[4];
  {
    const __hip_bfloat16* qp = Q + ((size_t)(b * SS + qrow)) * DD + h * HDIM + hi * 8;
    qf[0] = *(const bf16x8*)(qp);
    qf[1] = *(const bf16x8*)(qp + 16);
    qf[2] = *(const bf16x8*)(qp + 32);
    qf[3] = *(const bf16x8*)(qp + 48);
  }
  f32x16 ctx0 = {}, ctx1 = {};
  float m = -1e30f, l = 0.f, mC = -1.44e30f;

  auto stage = [&](int buf, int kv0) {
    int r = t >> 3, c = t & 7;
    gl_lds16(Kg + ((size_t)(b * SS + kv0 + r)) * DD + h * HDIM + ((c ^ (r & 7)) * 8),
             lds + buf * 8192 + t * 16);
    gl_lds16(VTg + ((size_t)(bh * 64 + r)) * 2048 + kv0 + ((c ^ (r & 7)) * 8),
             lds + 16384 + buf * 8192 + t * 16);
    if (t < 64) *(float*)(lds + 32768 + buf * 256 + t * 4) = mask[b * SS + kv0 + t];
  };

  stage(0, kvBase);
  const int NIT = SS / 128;
  for (int it = 0; it < NIT; ++it) {
    __syncthreads();
    if (it + 1 < NIT) stage((it + 1) & 1, kvBase + (it + 1) * 64);
    const char* Kb = lds + (it & 1) * 8192;
    const char* Vb = lds + 16384 + (it & 1) * 8192;
    const float* mk = (const float*)(lds + 32768 + (it & 1) * 256);

    f32x16 s0 = {}, s1 = {};
#pragma unroll
    for (int kc = 0; kc < 4; ++kc) {
      int c = kc * 2 + hi;
      int r0 = l31, r1 = 32 + l31;
      bf16x8 ka0 = *(const bf16x8*)(Kb + r0 * 128 + ((c ^ (r0 & 7)) << 4));
      bf16x8 ka1 = *(const bf16x8*)(Kb + r1 * 128 + ((c ^ (r1 & 7)) << 4));
      s0 = __builtin_amdgcn_mfma_f32_32x32x16_bf16(ka0, qf[kc], s0, 0, 0, 0);
      s1 = __builtin_amdgcn_mfma_f32_32x32x16_bf16(ka1, qf[kc], s1, 0, 0, 0);
    }
#pragma unroll
    for (int g = 0; g < 4; ++g) {
      float4 mg0 = *(const float4*)(mk + g * 8 + hi * 4);
      float4 mg1 = *(const float4*)(mk + 32 + g * 8 + hi * 4);
      const float* m0p = (const float*)&mg0;
      const float* m1p = (const float*)&mg1;
#pragma unroll
      for (int i2 = 0; i2 < 4; ++i2) {
        s0[g * 4 + i2] = fmaf(s0[g * 4 + i2], 0.125f, m0p[i2]);
        s1[g * 4 + i2] = fmaf(s1[g * 4 + i2], 0.125f, m1p[i2]);
      }
    }
    float pmax;
    {
      f32x16 q8;
#pragma unroll
      for (int r = 0; r < 16; ++r) q8[r] = fmaxf(s0[r], s1[r]);
#pragma unroll
      for (int r = 0; r < 8; ++r) q8[r] = fmaxf(q8[r], q8[r + 8]);
#pragma unroll
      for (int r = 0; r < 4; ++r) q8[r] = fmaxf(q8[r], q8[r + 4]);
      pmax = fmaxf(fmaxf(q8[0], q8[1]), fmaxf(q8[2], q8[3]));
      pmax = fmaxf(pmax, __shfl_xor(pmax, 32));
    }
    if (__any(pmax > m + 8.0f)) {
      float mnew = fmaxf(m, pmax);
      float fac = EXP2((m - mnew) * LOG2E);
      l *= fac;
#pragma unroll
      for (int r = 0; r < 16; ++r) { ctx0[r] *= fac; ctx1[r] *= fac; }
      m = mnew;
      mC = m * LOG2E;
    }
    float rsA = 0.f, rsB = 0.f;
#pragma unroll
    for (int r = 0; r < 16; ++r) {
      s0[r] = EXP2(fmaf(s0[r], LOG2E, -mC));
      s1[r] = EXP2(fmaf(s1[r], LOG2E, -mC));
      rsA += s0[r];
      rsB += s1[r];
    }
    rsA += rsB;
    rsA += __shfl_xor(rsA, 32);
    l += rsA;

    unsigned W0[8], W1[8];
#pragma unroll
    for (int g = 0; g < 4; ++g) {
      W0[g * 2] = pk2(s0[g * 4 + 0], s0[g * 4 + 1]);
      W0[g * 2 + 1] = pk2(s0[g * 4 + 2], s0[g * 4 + 3]);
      W1[g * 2] = pk2(s1[g * 4 + 0], s1[g * 4 + 1]);
      W1[g * 2 + 1] = pk2(s1[g * 4 + 2], s1[g * 4 + 3]);
    }
    unsigned swA0 = __shfl_xor(hi ? W0[0] : W0[2], 32);
    unsigned swA1 = __shfl_xor(hi ? W0[1] : W0[3], 32);
    unsigned swB0 = __shfl_xor(hi ? W0[4] : W0[6], 32);
    unsigned swB1 = __shfl_xor(hi ? W0[5] : W0[7], 32);
    unsigned swC0 = __shfl_xor(hi ? W1[0] : W1[2], 32);
    unsigned swC1 = __shfl_xor(hi ? W1[1] : W1[3], 32);
    unsigned swD0 = __shfl_xor(hi ? W1[4] : W1[6], 32);
    unsigned swD1 = __shfl_xor(hi ? W1[5] : W1[7], 32);
    u32x4 pb[4];
    pb[0] = hi ? (u32x4){swA0, swA1, W0[2], W0[3]} : (u32x4){W0[0], W0[1], swA0, swA1};
    pb[1] = hi ? (u32x4){swB0, swB1, W0[6], W0[7]} : (u32x4){W0[4], W0[5], swB0, swB1};
    pb[2] = hi ? (u32x4){swC0, swC1, W1[2], W1[3]} : (u32x4){W1[0], W1[1], swC0, swC1};
    pb[3] = hi ? (u32x4){swD0, swD1, W1[6], W1[7]} : (u32x4){W1[4], W1[5], swD0, swD1};

#pragma unroll
    for (int kc = 0; kc < 4; ++kc) {
      bf16x8 pbf = __builtin_bit_cast(bf16x8, pb[kc]);
      int c = kc * 2 + hi;
      int r0 = l31, r1 = 32 + l31;
      bf16x8 va0 = *(const bf16x8*)(Vb + r0 * 128 + ((c ^ (r0 & 7)) << 4));
      bf16x8 va1 = *(const bf16x8*)(Vb + r1 * 128 + ((c ^ (r1 & 7)) << 4));
      ctx0 = __builtin_amdgcn_mfma_f32_32x32x16_bf16(va0, pbf, ctx0, 0, 0, 0);
      ctx1 = __builtin_amdgcn_mfma_f32_32x32x16_bf16(va1, pbf, ctx1, 0, 0, 0);
    }
  }

  if (hi == 0) ml[((size_t)z * NTOK + b * SS + qrow) * HH + h] = make_float2(m, l);

  __syncthreads();
  {
    int row = w * 32 + l31;
#pragma unroll
    for (int dt = 0; dt < 2; ++dt) {
#pragma unroll
      for (int g = 0; g < 4; ++g) {
        unsigned lo2 = dt ? pk2(ctx1[g * 4 + 0], ctx1[g * 4 + 1]) : pk2(ctx0[g * 4 + 0], ctx0[g * 4 + 1]);
        unsigned hi2 = dt ? pk2(ctx1[g * 4 + 2], ctx1[g * 4 + 3]) : pk2(ctx0[g * 4 + 2], ctx0[g * 4 + 3]);
        int c = dt * 4 + g;
        *(uint2*)(lds + row * 128 + ((c ^ (row & 7)) << 4) + hi * 8) = make_uint2(lo2, hi2);
      }
    }
  }
  __syncthreads();
  {
    int r = t >> 1;
    size_t tok = (size_t)(b * SS + q0 + r);
#pragma unroll
    for (int i2 = 0; i2 < 4; ++i2) {
      int c = (t & 1) * 4 + i2;
      u32x4 vv = *(const u32x4*)(lds + r * 128 + ((c ^ (r & 7)) << 4));
      *(u32x4*)((short*)pctx + tok * DD + h * HDIM + c * 8) = vv;
    }
  }
}

// ---------------- merge two KV-half partials -> ctxb (bf16) ------------------
__global__ __launch_bounds__(256) void mergeAttn(
    const __hip_bfloat16* __restrict__ p0, const __hip_bfloat16* __restrict__ p1,
    const float2* __restrict__ ml, __hip_bfloat16* __restrict__ out) {
  int tok = blockIdx.x, tid = threadIdx.x;
  int h = tid >> 4;
  float2 a = ml[(size_t)tok * HH + h];
  float2 b = ml[(size_t)(NTOK + tok) * HH + h];
  float M = fmaxf(a.x, b.x);
  float w0 = EXP2((a.x - M) * LOG2E), w1 = EXP2((b.x - M) * LOG2E);
  float inv = 1.0f / (w0 * a.y + w1 * b.y);
  w0 *= inv; w1 *= inv;
  size_t idx = (size_t)tok * DD + tid * 4;
  short4 c0 = *(const short4*)((const short*)p0 + idx);
  short4 c1 = *(const short4*)((const short*)p1 + idx);
  unsigned lo = pk2(w0 * bf2f(c0.x) + w1 * bf2f(c1.x),
                    w0 * bf2f(c0.y) + w1 * bf2f(c1.y));
  unsigned hi2 = pk2(w0 * bf2f(c0.z) + w1 * bf2f(c1.z),
                     w0 * bf2f(c0.w) + w1 * bf2f(c1.w));
  *(uint2*)((short*)out + idx) = make_uint2(lo, hi2);
}

// ---------------- host-side orchestration ------------------------------------
extern "C" void kernel_launch(void* const* d_in, const int* in_sizes, int n_in,
                              void* d_out, int out_size, void* d_ws, size_t ws_size,
                              hipStream_t stream) {
  const float* x = (const float*)d_in[0];
  const float* mask = (const float*)d_in[1];
  const float* wq = (const float*)d_in[2];
  const float* bq = (const float*)d_in[3];
  const float* wk = (const float*)d_in[4];
  const float* bk = (const float*)d_in[5];
  const float* wv = (const float*)d_in[6];
  const float* bv = (const float*)d_in[7];
  const float* wo = (const float*)d_in[8];
  const float* bo = (const float*)d_in[9];
  const float* w1 = (const float*)d_in[10];
  const float* b1 = (const float*)d_in[11];
  const float* w2 = (const float*)d_in[12];
  const float* b2 = (const float*)d_in[13];
  const float* g1 = (const float*)d_in[14];
  const float* be1 = (const float*)d_in[15];
  const float* g2 = (const float*)d_in[16];
  const float* be2 = (const float*)d_in[17];

  char* ws = (char*)d_ws;
  const size_t MB = 1024ull * 1024ull;
  __hip_bfloat16* wqkvT = (__hip_bfloat16*)(ws + 0 * MB);   // [3072][1024] + woT
  __hip_bfloat16* woT = (__hip_bfloat16*)(ws + 6 * MB);
  __hip_bfloat16* w1T = (__hip_bfloat16*)(ws + 8 * MB);
  __hip_bfloat16* w2T = (__hip_bfloat16*)(ws + 16 * MB);
  __hip_bfloat16* xn = (__hip_bfloat16*)(ws + 24 * MB);     // later h2
  __hip_bfloat16* qb = (__hip_bfloat16*)(ws + 32 * MB);
  __hip_bfloat16* kb = (__hip_bfloat16*)(ws + 40 * MB);
  __hip_bfloat16* vtb = (__hip_bfloat16*)(ws + 48 * MB);    // V^T [32][64][2048]
  __hip_bfloat16* ctxb = (__hip_bfloat16*)(ws + 56 * MB);
  float* h1 = (float*)(ws + 64 * MB);
  __hip_bfloat16* h2 = xn;
  __hip_bfloat16* a1 = qb;
  __hip_bfloat16* pctx0 = (__hip_bfloat16*)(ws + 24 * MB);
  __hip_bfloat16* pctx1 = (__hip_bfloat16*)(ws + 64 * MB);
  float2* mlbuf = (float2*)(ws + 72 * MB);

  // wq,wk,wv -> wqkvT (0..6MB), wo -> woT (6..8MB) in one launch
  convT4<<<dim3(32, 32, 4), 256, 0, stream>>>(wq, wk, wv, wo, wqkvT);
  convT<<<dim3(128, 32), 256, 0, stream>>>(w1, w1T, 1024, 4096);
  convT<<<dim3(32, 128), 256, 0, stream>>>(w2, w2T, 4096, 1024);

  ln_bf16<<<1024, 256, 0, stream>>>(x, g1, be1, xn);

  // fused QKV: M=4096, N=3072, K=1024 -> 768 blocks (3/CU)
  gemm_bt<5><<<dim3(24, 32), 256, 0, stream>>>(
      xn, wqkvT, bq, bk, bv, qb, kb, vtb, NTOK, 3072, 1024, 1);

  // flash attention split-KV=2 (XCD-grouped 1-D grid) -> partials, then merge
  flash_attn2<<<512, 512, 0, stream>>>(qb, kb, vtb, mask, pctx0, pctx1, mlbuf);
  mergeAttn<<<4096, 256, 0, stream>>>(pctx0, pctx1, mlbuf, ctxb);

  // O-proj split-K=4 -> bf16 partials @ 24+8z MB (1024 blocks)
  gemm_bt<7><<<dim3(8, 32, 4), 256, 0, stream>>>(
      ctxb, woT, nullptr, nullptr, nullptr, ws + 24 * MB, nullptr, nullptr,
      NTOK, 1024, 1024, 4);

  // fused reduce4 + LN2 -> h1 (f32) and h2 (bf16)
  reduce4_ln<<<2048, 256, 0, stream>>>((__hip_bfloat16*)(ws + 24 * MB),
                                       (__hip_bfloat16*)(ws + 32 * MB),
                                       (__hip_bfloat16*)(ws + 40 * MB),
                                       (__hip_bfloat16*)(ws + 48 * MB),
                                       x, bo, g2, be2, h1, h2);

  // FF1 + fast gelu: M=4096, N=4096, K=1024 -> 1024 blocks
  gemm_bt<1><<<dim3(32, 32), 256, 0, stream>>>(
      h2, w1T, b1, nullptr, nullptr, a1, nullptr, nullptr, NTOK, FFD, 1024, 1);

  // FF2 split-K=3 -> bf16 partials @ 0/8/24 MB (768 blocks)
  gemm_bt<8><<<dim3(8, 32, 3), 256, 0, stream>>>(
      a1, w2T, nullptr, nullptr, nullptr, ws, nullptr, nullptr,
      NTOK, 1024, FFD, 3);

  reduce3<<<2048, 256, 0, stream>>>((__hip_bfloat16*)(ws + 0 * MB),
                                    (__hip_bfloat16*)(ws + 8 * MB),
                                    (__hip_bfloat16*)(ws + 24 * MB),
                                    h1, b2, (float*)d_out);
}

// Round 11
// 259.605 us; speedup vs baseline: 1.1088x; 1.0094x over previous
//
#include <hip/hip_runtime.h>
#include <hip/hip_bf16.h>
#include <math.h>

// Transformer layer: B=2 S=2048 D=1024 H=16 HD=64 FF=4096, fp32 I/O.
// Heavy GEMMs: 128x128 bf16 MFMA tiles, double-buffered LDS with stage-early
// single-barrier K-loop (T3 minimum 2-phase), coalesced epilogues, fast gelu.
// Attention: flash split-KV=2 (128-reg cap, XCD-grouped) + merge. Fused LN2.

#define BB 2
#define SS 2048
#define DD 1024
#define HH 16
#define HDIM 64
#define FFD 4096
#define NTOK (BB*SS)
#define LOG2E 1.4426950408889634f

typedef __attribute__((ext_vector_type(8))) short bf16x8;
typedef __attribute__((ext_vector_type(4))) float f32x4;
typedef __attribute__((ext_vector_type(16))) float f32x16;
typedef __attribute__((ext_vector_type(4))) unsigned int u32x4;

#if __has_builtin(__builtin_amdgcn_exp2f)
#define EXP2(x) __builtin_amdgcn_exp2f(x)
#else
#define EXP2(x) exp2f(x)
#endif

__device__ __forceinline__ void gl_lds16(const void* g, void* l) {
  __builtin_amdgcn_global_load_lds(
      (const __attribute__((address_space(1))) unsigned int*)g,
      (__attribute__((address_space(3))) unsigned int*)l, 16, 0, 0);
}

// RNE float->bf16 bits (finite inputs only)
__device__ __forceinline__ short f2bf(float f) {
  unsigned int u = __builtin_bit_cast(unsigned int, f);
  unsigned int r = (u + 0x7fffu + ((u >> 16) & 1u)) >> 16;
  return (short)r;
}
__device__ __forceinline__ float bf2f(short s) {
  return __builtin_bit_cast(float, ((unsigned)(unsigned short)s) << 16);
}
// packed pair via HW cvt (RNE)
__device__ __forceinline__ unsigned pk2(float lo, float hi) {
  unsigned r;
  asm("v_cvt_pk_bf16_f32 %0, %1, %2" : "=v"(r) : "v"(lo), "v"(hi));
  return r;
}
// gelu, tanh form via exp2 (max dev vs erf-gelu ~3e-4)
__device__ __forceinline__ float gelu_fast(float v) {
  float v2 = v * v;
  float u = v * (0.7978845608028654f + 0.03567740814183427f * v2);
  float e = EXP2(u * 2.8853900817779268f);  // e^(2u)
  return v * (1.0f - 1.0f / (e + 1.0f));
}

// ---------------- transpose + fp32->bf16 convert: wt[n][k] = bf16(w[k][n]) ----
__global__ __launch_bounds__(256) void convT(const float* __restrict__ w,
                                             __hip_bfloat16* __restrict__ wt,
                                             int K, int N) {
  __shared__ float tile[32][33];
  int k0 = blockIdx.y * 32, n0 = blockIdx.x * 32;
  int tx = threadIdx.x & 31, ty = threadIdx.x >> 5;
#pragma unroll
  for (int i = 0; i < 4; ++i) {
    int r = ty + i * 8;
    tile[r][tx] = w[(size_t)(k0 + r) * N + n0 + tx];
  }
  __syncthreads();
#pragma unroll
  for (int i = 0; i < 4; ++i) {
    int r = ty + i * 8;
    wt[(size_t)(n0 + r) * K + k0 + tx] = __float2bfloat16(tile[tx][r]);
  }
}

// batched 1024x1024 transpose-convert: z selects {wq,wk,wv,wo} -> out + z*1Mi
__global__ __launch_bounds__(256) void convT4(const float* __restrict__ w0,
                                              const float* __restrict__ w1,
                                              const float* __restrict__ w2,
                                              const float* __restrict__ w3,
                                              __hip_bfloat16* __restrict__ out) {
  __shared__ float tile[32][33];
  int z = blockIdx.z;
  const float* w = (z == 0) ? w0 : (z == 1) ? w1 : (z == 2) ? w2 : w3;
  __hip_bfloat16* wt = out + (size_t)z * 1024 * 1024;
  int k0 = blockIdx.y * 32, n0 = blockIdx.x * 32;
  int tx = threadIdx.x & 31, ty = threadIdx.x >> 5;
#pragma unroll
  for (int i = 0; i < 4; ++i) {
    int r = ty + i * 8;
    tile[r][tx] = w[(size_t)(k0 + r) * 1024 + n0 + tx];
  }
  __syncthreads();
#pragma unroll
  for (int i = 0; i < 4; ++i) {
    int r = ty + i * 8;
    wt[(size_t)(n0 + r) * 1024 + k0 + tx] = __float2bfloat16(tile[tx][r]);
  }
}

// ---------------- LayerNorm (fp32 in -> bf16 out), one wave per row ----------
__global__ __launch_bounds__(256) void ln_bf16(const float* __restrict__ x,
                                               const float* __restrict__ g,
                                               const float* __restrict__ be,
                                               __hip_bfloat16* __restrict__ out) {
  int w = threadIdx.x >> 6, lane = threadIdx.x & 63;
  int row = blockIdx.x * 4 + w;
  const float* xr = x + (size_t)row * DD;
  float4 v[4];
  float sum = 0.f, sq = 0.f;
#pragma unroll
  for (int i = 0; i < 4; ++i) {
    v[i] = *(const float4*)(xr + lane * 4 + i * 256);
    sum += v[i].x + v[i].y + v[i].z + v[i].w;
    sq += v[i].x * v[i].x + v[i].y * v[i].y + v[i].z * v[i].z + v[i].w * v[i].w;
  }
#pragma unroll
  for (int off = 1; off < 64; off <<= 1) {
    sum += __shfl_xor(sum, off);
    sq += __shfl_xor(sq, off);
  }
  float mu = sum * (1.f / 1024.f);
  float var = sq * (1.f / 1024.f) - mu * mu;
  float rs = rsqrtf(var + 1e-12f);
  __hip_bfloat16* orow = out + (size_t)row * DD;
#pragma unroll
  for (int i = 0; i < 4; ++i) {
    int c = lane * 4 + i * 256;
    float4 gg = *(const float4*)(g + c);
    float4 bb = *(const float4*)(be + c);
    short4 o;
    o.x = f2bf((v[i].x - mu) * rs * gg.x + bb.x);
    o.y = f2bf((v[i].y - mu) * rs * gg.y + bb.y);
    o.z = f2bf((v[i].z - mu) * rs * gg.z + bb.z);
    o.w = f2bf((v[i].w - mu) * rs * gg.w + bb.w);
    *(short4*)((short*)orow + c) = o;
  }
}

// ---------------- GEMM: C[M,N] = A[M,K] (bf16) * BT[N,K]^T + epilogue --------
// 128x128 tile, BK=32, 4 waves. Double-buffered LDS, ONE barrier per K-step:
//   prologue: stage(tile0 -> buf0); barrier.
//   iter s:   stage(tile s+1 -> buf^1); ds_read buf; 16 MFMA; barrier.
// The barrier's implicit vmcnt(0)/lgkmcnt(0) drains next-tile loads AFTER
// they flew under this step's ds_read+MFMA. WAR on buf^1 is safe: iter s-1's
// ds_reads of it completed before the end-of-(s-1) barrier.
// Epilogues bounce through LDS (272B-stride rows) for coalesced 16B stores.
// EPI 1: +bias, fast-gelu -> bf16                      [FF1]
// EPI 5: QKV fused (N=3072): Q,K +bias -> bf16; V +bias -> bf16 transposed
// EPI 7: raw -> bf16 partial @ C0 + z*4Mi elems        [O-proj split-K]
// EPI 8: raw -> bf16 partial @ C0 + {0,4Mi,12Mi} elems [FF2 split-K]
template <int EPI>
__global__ __launch_bounds__(256, 4) void gemm_bt(
    const __hip_bfloat16* __restrict__ A, const __hip_bfloat16* __restrict__ BT,
    const float* __restrict__ bA, const float* __restrict__ bB,
    const float* __restrict__ bC,
    void* __restrict__ C0, void* __restrict__ C1, void* __restrict__ C2,
    int M, int N, int K, int kSplit) {
  __shared__ __align__(16) char smem[34816];  // buf0@0, buf1@16384; epi arena
  const int t = threadIdx.x, lane = t & 63, w = t >> 6;
  const int m0 = blockIdx.y * 128, n0 = blockIdx.x * 128;
  const int wm = (w >> 1) * 64, wn = (w & 1) * 64;
  const int row16 = lane & 15, grp = lane >> 4;
  const int arow = t >> 2, achunk = t & 3;
  f32x4 acc[4][4] = {};

  const int steps = K >> 5;
  const int z = blockIdx.z;
  const int sBeg = (z * steps) / kSplit, sEnd = ((z + 1) * steps) / kSplit;

  auto stage = [&](char* base, int s) {
    const int kt = s << 5;
#pragma unroll
    for (int j = 0; j < 2; ++j) {
      int r = arow + j * 64;
      gl_lds16(A + (size_t)(m0 + r) * K + kt + achunk * 8,
               base + r * 64 + achunk * 16);
      gl_lds16(BT + (size_t)(n0 + r) * K + kt + achunk * 8,
               base + 8192 + r * 64 + achunk * 16);
    }
  };

  stage(smem, sBeg);
  __syncthreads();

  for (int s = sBeg; s < sEnd; ++s) {
    const char* bufC = smem + ((s - sBeg) & 1) * 16384;
    if (s + 1 < sEnd) stage(smem + ((s - sBeg + 1) & 1) * 16384, s + 1);
    bf16x8 af[4], bfr[4];
#pragma unroll
    for (int f = 0; f < 4; ++f) {
      af[f] = *(const bf16x8*)(bufC + (wm + f * 16 + row16) * 64 + grp * 16);
      bfr[f] = *(const bf16x8*)(bufC + 8192 + (wn + f * 16 + row16) * 64 + grp * 16);
    }
#pragma unroll
    for (int mf = 0; mf < 4; ++mf)
#pragma unroll
      for (int nf = 0; nf < 4; ++nf)
        acc[mf][nf] =
            __builtin_amdgcn_mfma_f32_16x16x32_bf16(af[mf], bfr[nf], acc[mf][nf], 0, 0, 0);
    __syncthreads();
  }

  // ---------------- V section of QKV: transposed bounce ----------------
  if constexpr (EPI == 5) {
    if (n0 >= 2048) {
#pragma unroll
      for (int nf = 0; nf < 4; ++nf) {
        int vloc = wn + nf * 16 + row16;           // local vr 0..127
        float bv = bC[n0 - 2048 + vloc];
#pragma unroll
        for (int mf = 0; mf < 4; ++mf) {
          int tloc = wm + mf * 16 + grp * 4;       // local token
          f32x4 a = acc[mf][nf];
          *(uint2*)(smem + vloc * 272 + tloc * 2) =
              make_uint2(pk2(a[0] + bv, a[1] + bv), pk2(a[2] + bv, a[3] + bv));
        }
      }
      __syncthreads();
      int vrBase = ((m0 >> 11) << 10) + (n0 - 2048);
      int mcol = m0 & 2047;
#pragma unroll
      for (int i = 0; i < 8; ++i) {
        int c = t + i * 256;
        int vr = c >> 4, tc = c & 15;
        u32x4 vv = *(const u32x4*)(smem + vr * 272 + tc * 16);
        *(u32x4*)((__hip_bfloat16*)C2 + (size_t)(vrBase + vr) * 2048 + mcol + tc * 8) = vv;
      }
      return;
    }
  }

  // ---------------- row-major bounce (EPI 1, 5-Q/K, 7, 8) ----------------
  __hip_bfloat16* outP = nullptr;
  int ldO = N, colB = n0;
  const float* bp = nullptr;
  if constexpr (EPI == 1) { outP = (__hip_bfloat16*)C0; bp = bA; }
  if constexpr (EPI == 5) {
    const bool isK = n0 >= 1024;
    outP = (__hip_bfloat16*)(isK ? C1 : C0);
    bp = isK ? bB : bA;
    ldO = 1024; colB = n0 & 1023;
  }
  if constexpr (EPI == 7) outP = (__hip_bfloat16*)C0 + (size_t)z * 4194304ull;
  if constexpr (EPI == 8)
    outP = (__hip_bfloat16*)C0 + ((z == 0) ? 0ull : ((z == 1) ? 4194304ull : 12582912ull));

#pragma unroll
  for (int nf = 0; nf < 4; ++nf) {
    int nn = wn + nf * 16 + row16;
    float bv = bp ? bp[colB + nn] : 0.f;
#pragma unroll
    for (int mf = 0; mf < 4; ++mf) {
      int mloc = wm + mf * 16 + grp * 4;
      f32x4 a = acc[mf][nf];
#pragma unroll
      for (int r = 0; r < 4; ++r) {
        float v = a[r] + bv;
        if constexpr (EPI == 1) v = gelu_fast(v);
        *(short*)(smem + (mloc + r) * 272 + nn * 2) = f2bf(v);
      }
    }
  }
  __syncthreads();
#pragma unroll
  for (int i = 0; i < 8; ++i) {
    int c = t + i * 256;
    int mmr = c >> 4, nc = c & 15;
    u32x4 vv = *(const u32x4*)(smem + mmr * 272 + nc * 16);
    *(u32x4*)(outP + (size_t)(m0 + mmr) * ldO + colB + nc * 8) = vv;
  }
}

// ---------------- FF2 split-K reduce: out = h1 + b2 + sum(3 partials) --------
__global__ __launch_bounds__(256) void reduce3(const __hip_bfloat16* __restrict__ p0,
                                               const __hip_bfloat16* __restrict__ p1,
                                               const __hip_bfloat16* __restrict__ p2,
                                               const float* __restrict__ h1,
                                               const float* __restrict__ b2,
                                               float* __restrict__ out) {
  int idx = (blockIdx.x * 256 + threadIdx.x) * 8;
  int n = idx & 1023;
  bf16x8 a = *(const bf16x8*)(p0 + idx);
  bf16x8 b = *(const bf16x8*)(p1 + idx);
  bf16x8 c = *(const bf16x8*)(p2 + idx);
  float4 hA = *(const float4*)(h1 + idx), hB = *(const float4*)(h1 + idx + 4);
  float4 bA = *(const float4*)(b2 + n), bB = *(const float4*)(b2 + n + 4);
  float o[8];
#pragma unroll
  for (int j = 0; j < 8; ++j) o[j] = bf2f(a[j]) + bf2f(b[j]) + bf2f(c[j]);
  float4 r0 = make_float4(o[0] + hA.x + bA.x, o[1] + hA.y + bA.y,
                          o[2] + hA.z + bA.z, o[3] + hA.w + bA.w);
  float4 r1 = make_float4(o[4] + hB.x + bB.x, o[5] + hB.y + bB.y,
                          o[6] + hB.z + bB.z, o[7] + hB.w + bB.w);
  *(float4*)(out + idx) = r0;
  *(float4*)(out + idx + 4) = r1;
}

// -------- fused O-proj reduce + LN2: h1 = x+bo+sum(4 partials); h2 = LN(h1) --
__global__ __launch_bounds__(256) void reduce4_ln(
    const __hip_bfloat16* __restrict__ p0, const __hip_bfloat16* __restrict__ p1,
    const __hip_bfloat16* __restrict__ p2, const __hip_bfloat16* __restrict__ p3,
    const float* __restrict__ x, const float* __restrict__ bo,
    const float* __restrict__ g, const float* __restrict__ be,
    float* __restrict__ h1, __hip_bfloat16* __restrict__ h2) {
  __shared__ float red[4][2];
  const int tid = threadIdx.x;
  const int rowHalf = tid >> 7, tloc = tid & 127, wv = tid >> 6;
  const size_t idx = ((size_t)blockIdx.x * 2 + rowHalf) * 1024 + tloc * 8;
  const int n = tloc * 8;
  bf16x8 a = *(const bf16x8*)(p0 + idx);
  bf16x8 b = *(const bf16x8*)(p1 + idx);
  bf16x8 c = *(const bf16x8*)(p2 + idx);
  bf16x8 d = *(const bf16x8*)(p3 + idx);
  float4 xA = *(const float4*)(x + idx), xB = *(const float4*)(x + idx + 4);
  float4 bA = *(const float4*)(bo + n), bB = *(const float4*)(bo + n + 4);
  float o[8];
#pragma unroll
  for (int j = 0; j < 8; ++j)
    o[j] = (bf2f(a[j]) + bf2f(b[j])) + (bf2f(c[j]) + bf2f(d[j]));
  o[0] += xA.x + bA.x; o[1] += xA.y + bA.y; o[2] += xA.z + bA.z; o[3] += xA.w + bA.w;
  o[4] += xB.x + bB.x; o[5] += xB.y + bB.y; o[6] += xB.z + bB.z; o[7] += xB.w + bB.w;
  *(float4*)(h1 + idx) = make_float4(o[0], o[1], o[2], o[3]);
  *(float4*)(h1 + idx + 4) = make_float4(o[4], o[5], o[6], o[7]);
  float s = 0.f, sq = 0.f;
#pragma unroll
  for (int j = 0; j < 8; ++j) { s += o[j]; sq += o[j] * o[j]; }
#pragma unroll
  for (int off = 1; off < 64; off <<= 1) {
    s += __shfl_xor(s, off);
    sq += __shfl_xor(sq, off);
  }
  if ((tid & 63) == 0) { red[wv][0] = s; red[wv][1] = sq; }
  __syncthreads();
  float S = red[rowHalf * 2][0] + red[rowHalf * 2 + 1][0];
  float SQ = red[rowHalf * 2][1] + red[rowHalf * 2 + 1][1];
  float mu = S * (1.f / 1024.f);
  float var = SQ * (1.f / 1024.f) - mu * mu;
  float rs = rsqrtf(var + 1e-12f);
  float4 gA = *(const float4*)(g + n), gB = *(const float4*)(g + n + 4);
  float4 eA = *(const float4*)(be + n), eB = *(const float4*)(be + n + 4);
  u32x4 pkd;
  pkd[0] = pk2((o[0] - mu) * rs * gA.x + eA.x, (o[1] - mu) * rs * gA.y + eA.y);
  pkd[1] = pk2((o[2] - mu) * rs * gA.z + eA.z, (o[3] - mu) * rs * gA.w + eA.w);
  pkd[2] = pk2((o[4] - mu) * rs * gB.x + eB.x, (o[5] - mu) * rs * gB.y + eB.y);
  pkd[3] = pk2((o[6] - mu) * rs * gB.z + eB.z, (o[7] - mu) * rs * gB.w + eB.w);
  *(u32x4*)((short*)h2 + idx) = pkd;
}

// ---------------- Flash attention, split-KV=2: partial ctx + (m,l) ----------
// 1-D grid of 512; i%8 groups one (bh,z)'s q0-blocks onto one XCD for K/V L2.
// launch_bounds(512,4): cap regs at 128/wave -> 16 waves/CU.
__global__ __launch_bounds__(512, 4) void flash_attn2(
    const __hip_bfloat16* __restrict__ Q,
    const __hip_bfloat16* __restrict__ Kg,
    const __hip_bfloat16* __restrict__ VTg,
    const float* __restrict__ mask,
    __hip_bfloat16* __restrict__ pctx0,
    __hip_bfloat16* __restrict__ pctx1,
    float2* __restrict__ ml) {
  __shared__ __align__(16) char lds[33280];
  const int t = threadIdx.x, lane = t & 63, w = t >> 6;
  const int l31 = lane & 31, hi = lane >> 5;
  const int i = blockIdx.x;
  const int xcd = i & 7, j = i >> 3;
  const int q0i = j & 7, pg = j >> 3;
  const int p = pg * 8 + xcd;
  const int bh = p >> 1, z = p & 1;
  const int q0 = q0i * 256;
  const int b = bh >> 4, h = bh & 15;
  const int kvBase = z * (SS / 2);
  __hip_bfloat16* pctx = z ? pctx1 : pctx0;
  const int qrow = q0 + w * 32 + l31;

  bf16x8 qf[4];
  {
    const __hip_bfloat16* qp = Q + ((size_t)(b * SS + qrow)) * DD + h * HDIM + hi * 8;
    qf[0] = *(const bf16x8*)(qp);
    qf[1] = *(const bf16x8*)(qp + 16);
    qf[2] = *(const bf16x8*)(qp + 32);
    qf[3] = *(const bf16x8*)(qp + 48);
  }
  f32x16 ctx0 = {}, ctx1 = {};
  float m = -1e30f, l = 0.f, mC = -1.44e30f;

  auto stage = [&](int buf, int kv0) {
    int r = t >> 3, c = t & 7;
    gl_lds16(Kg + ((size_t)(b * SS + kv0 + r)) * DD + h * HDIM + ((c ^ (r & 7)) * 8),
             lds + buf * 8192 + t * 16);
    gl_lds16(VTg + ((size_t)(bh * 64 + r)) * 2048 + kv0 + ((c ^ (r & 7)) * 8),
             lds + 16384 + buf * 8192 + t * 16);
    if (t < 64) *(float*)(lds + 32768 + buf * 256 + t * 4) = mask[b * SS + kv0 + t];
  };

  stage(0, kvBase);
  const int NIT = SS / 128;
  for (int it = 0; it < NIT; ++it) {
    __syncthreads();
    if (it + 1 < NIT) stage((it + 1) & 1, kvBase + (it + 1) * 64);
    const char* Kb = lds + (it & 1) * 8192;
    const char* Vb = lds + 16384 + (it & 1) * 8192;
    const float* mk = (const float*)(lds + 32768 + (it & 1) * 256);

    f32x16 s0 = {}, s1 = {};
#pragma unroll
    for (int kc = 0; kc < 4; ++kc) {
      int c = kc * 2 + hi;
      int r0 = l31, r1 = 32 + l31;
      bf16x8 ka0 = *(const bf16x8*)(Kb + r0 * 128 + ((c ^ (r0 & 7)) << 4));
      bf16x8 ka1 = *(const bf16x8*)(Kb + r1 * 128 + ((c ^ (r1 & 7)) << 4));
      s0 = __builtin_amdgcn_mfma_f32_32x32x16_bf16(ka0, qf[kc], s0, 0, 0, 0);
      s1 = __builtin_amdgcn_mfma_f32_32x32x16_bf16(ka1, qf[kc], s1, 0, 0, 0);
    }
#pragma unroll
    for (int g = 0; g < 4; ++g) {
      float4 mg0 = *(const float4*)(mk + g * 8 + hi * 4);
      float4 mg1 = *(const float4*)(mk + 32 + g * 8 + hi * 4);
      const float* m0p = (const float*)&mg0;
      const float* m1p = (const float*)&mg1;
#pragma unroll
      for (int i2 = 0; i2 < 4; ++i2) {
        s0[g * 4 + i2] = fmaf(s0[g * 4 + i2], 0.125f, m0p[i2]);
        s1[g * 4 + i2] = fmaf(s1[g * 4 + i2], 0.125f, m1p[i2]);
      }
    }
    float pmax;
    {
      f32x16 q8;
#pragma unroll
      for (int r = 0; r < 16; ++r) q8[r] = fmaxf(s0[r], s1[r]);
#pragma unroll
      for (int r = 0; r < 8; ++r) q8[r] = fmaxf(q8[r], q8[r + 8]);
#pragma unroll
      for (int r = 0; r < 4; ++r) q8[r] = fmaxf(q8[r], q8[r + 4]);
      pmax = fmaxf(fmaxf(q8[0], q8[1]), fmaxf(q8[2], q8[3]));
      pmax = fmaxf(pmax, __shfl_xor(pmax, 32));
    }
    if (__any(pmax > m + 8.0f)) {
      float mnew = fmaxf(m, pmax);
      float fac = EXP2((m - mnew) * LOG2E);
      l *= fac;
#pragma unroll
      for (int r = 0; r < 16; ++r) { ctx0[r] *= fac; ctx1[r] *= fac; }
      m = mnew;
      mC = m * LOG2E;
    }
    float rsA = 0.f, rsB = 0.f;
#pragma unroll
    for (int r = 0; r < 16; ++r) {
      s0[r] = EXP2(fmaf(s0[r], LOG2E, -mC));
      s1[r] = EXP2(fmaf(s1[r], LOG2E, -mC));
      rsA += s0[r];
      rsB += s1[r];
    }
    rsA += rsB;
    rsA += __shfl_xor(rsA, 32);
    l += rsA;

    unsigned W0[8], W1[8];
#pragma unroll
    for (int g = 0; g < 4; ++g) {
      W0[g * 2] = pk2(s0[g * 4 + 0], s0[g * 4 + 1]);
      W0[g * 2 + 1] = pk2(s0[g * 4 + 2], s0[g * 4 + 3]);
      W1[g * 2] = pk2(s1[g * 4 + 0], s1[g * 4 + 1]);
      W1[g * 2 + 1] = pk2(s1[g * 4 + 2], s1[g * 4 + 3]);
    }
    unsigned swA0 = __shfl_xor(hi ? W0[0] : W0[2], 32);
    unsigned swA1 = __shfl_xor(hi ? W0[1] : W0[3], 32);
    unsigned swB0 = __shfl_xor(hi ? W0[4] : W0[6], 32);
    unsigned swB1 = __shfl_xor(hi ? W0[5] : W0[7], 32);
    unsigned swC0 = __shfl_xor(hi ? W1[0] : W1[2], 32);
    unsigned swC1 = __shfl_xor(hi ? W1[1] : W1[3], 32);
    unsigned swD0 = __shfl_xor(hi ? W1[4] : W1[6], 32);
    unsigned swD1 = __shfl_xor(hi ? W1[5] : W1[7], 32);
    u32x4 pb[4];
    pb[0] = hi ? (u32x4){swA0, swA1, W0[2], W0[3]} : (u32x4){W0[0], W0[1], swA0, swA1};
    pb[1] = hi ? (u32x4){swB0, swB1, W0[6], W0[7]} : (u32x4){W0[4], W0[5], swB0, swB1};
    pb[2] = hi ? (u32x4){swC0, swC1, W1[2], W1[3]} : (u32x4){W1[0], W1[1], swC0, swC1};
    pb[3] = hi ? (u32x4){swD0, swD1, W1[6], W1[7]} : (u32x4){W1[4], W1[5], swD0, swD1};

#pragma unroll
    for (int kc = 0; kc < 4; ++kc) {
      bf16x8 pbf = __builtin_bit_cast(bf16x8, pb[kc]);
      int c = kc * 2 + hi;
      int r0 = l31, r1 = 32 + l31;
      bf16x8 va0 = *(const bf16x8*)(Vb + r0 * 128 + ((c ^ (r0 & 7)) << 4));
      bf16x8 va1 = *(const bf16x8*)(Vb + r1 * 128 + ((c ^ (r1 & 7)) << 4));
      ctx0 = __builtin_amdgcn_mfma_f32_32x32x16_bf16(va0, pbf, ctx0, 0, 0, 0);
      ctx1 = __builtin_amdgcn_mfma_f32_32x32x16_bf16(va1, pbf, ctx1, 0, 0, 0);
    }
  }

  if (hi == 0) ml[((size_t)z * NTOK + b * SS + qrow) * HH + h] = make_float2(m, l);

  __syncthreads();
  {
    int row = w * 32 + l31;
#pragma unroll
    for (int dt = 0; dt < 2; ++dt) {
#pragma unroll
      for (int g = 0; g < 4; ++g) {
        unsigned lo2 = dt ? pk2(ctx1[g * 4 + 0], ctx1[g * 4 + 1]) : pk2(ctx0[g * 4 + 0], ctx0[g * 4 + 1]);
        unsigned hi2 = dt ? pk2(ctx1[g * 4 + 2], ctx1[g * 4 + 3]) : pk2(ctx0[g * 4 + 2], ctx0[g * 4 + 3]);
        int c = dt * 4 + g;
        *(uint2*)(lds + row * 128 + ((c ^ (row & 7)) << 4) + hi * 8) = make_uint2(lo2, hi2);
      }
    }
  }
  __syncthreads();
  {
    int r = t >> 1;
    size_t tok = (size_t)(b * SS + q0 + r);
#pragma unroll
    for (int i2 = 0; i2 < 4; ++i2) {
      int c = (t & 1) * 4 + i2;
      u32x4 vv = *(const u32x4*)(lds + r * 128 + ((c ^ (r & 7)) << 4));
      *(u32x4*)((short*)pctx + tok * DD + h * HDIM + c * 8) = vv;
    }
  }
}

// ---------------- merge two KV-half partials -> ctxb (bf16) ------------------
__global__ __launch_bounds__(256) void mergeAttn(
    const __hip_bfloat16* __restrict__ p0, const __hip_bfloat16* __restrict__ p1,
    const float2* __restrict__ ml, __hip_bfloat16* __restrict__ out) {
  int tok = blockIdx.x, tid = threadIdx.x;
  int h = tid >> 4;
  float2 a = ml[(size_t)tok * HH + h];
  float2 b = ml[(size_t)(NTOK + tok) * HH + h];
  float M = fmaxf(a.x, b.x);
  float w0 = EXP2((a.x - M) * LOG2E), w1 = EXP2((b.x - M) * LOG2E);
  float inv = 1.0f / (w0 * a.y + w1 * b.y);
  w0 *= inv; w1 *= inv;
  size_t idx = (size_t)tok * DD + tid * 4;
  short4 c0 = *(const short4*)((const short*)p0 + idx);
  short4 c1 = *(const short4*)((const short*)p1 + idx);
  unsigned lo = pk2(w0 * bf2f(c0.x) + w1 * bf2f(c1.x),
                    w0 * bf2f(c0.y) + w1 * bf2f(c1.y));
  unsigned hi2 = pk2(w0 * bf2f(c0.z) + w1 * bf2f(c1.z),
                     w0 * bf2f(c0.w) + w1 * bf2f(c1.w));
  *(uint2*)((short*)out + idx) = make_uint2(lo, hi2);
}

// ---------------- host-side orchestration ------------------------------------
extern "C" void kernel_launch(void* const* d_in, const int* in_sizes, int n_in,
                              void* d_out, int out_size, void* d_ws, size_t ws_size,
                              hipStream_t stream) {
  const float* x = (const float*)d_in[0];
  const float* mask = (const float*)d_in[1];
  const float* wq = (const float*)d_in[2];
  const float* bq = (const float*)d_in[3];
  const float* wk = (const float*)d_in[4];
  const float* bk = (const float*)d_in[5];
  const float* wv = (const float*)d_in[6];
  const float* bv = (const float*)d_in[7];
  const float* wo = (const float*)d_in[8];
  const float* bo = (const float*)d_in[9];
  const float* w1 = (const float*)d_in[10];
  const float* b1 = (const float*)d_in[11];
  const float* w2 = (const float*)d_in[12];
  const float* b2 = (const float*)d_in[13];
  const float* g1 = (const float*)d_in[14];
  const float* be1 = (const float*)d_in[15];
  const float* g2 = (const float*)d_in[16];
  const float* be2 = (const float*)d_in[17];

  char* ws = (char*)d_ws;
  const size_t MB = 1024ull * 1024ull;
  __hip_bfloat16* wqkvT = (__hip_bfloat16*)(ws + 0 * MB);
  __hip_bfloat16* woT = (__hip_bfloat16*)(ws + 6 * MB);
  __hip_bfloat16* w1T = (__hip_bfloat16*)(ws + 8 * MB);
  __hip_bfloat16* w2T = (__hip_bfloat16*)(ws + 16 * MB);
  __hip_bfloat16* xn = (__hip_bfloat16*)(ws + 24 * MB);     // later h2
  __hip_bfloat16* qb = (__hip_bfloat16*)(ws + 32 * MB);
  __hip_bfloat16* kb = (__hip_bfloat16*)(ws + 40 * MB);
  __hip_bfloat16* vtb = (__hip_bfloat16*)(ws + 48 * MB);    // V^T [32][64][2048]
  __hip_bfloat16* ctxb = (__hip_bfloat16*)(ws + 56 * MB);
  float* h1 = (float*)(ws + 64 * MB);
  __hip_bfloat16* h2 = xn;
  __hip_bfloat16* a1 = qb;
  __hip_bfloat16* pctx0 = (__hip_bfloat16*)(ws + 24 * MB);
  __hip_bfloat16* pctx1 = (__hip_bfloat16*)(ws + 64 * MB);
  float2* mlbuf = (float2*)(ws + 72 * MB);

  convT4<<<dim3(32, 32, 4), 256, 0, stream>>>(wq, wk, wv, wo, wqkvT);
  convT<<<dim3(128, 32), 256, 0, stream>>>(w1, w1T, 1024, 4096);
  convT<<<dim3(32, 128), 256, 0, stream>>>(w2, w2T, 4096, 1024);

  ln_bf16<<<1024, 256, 0, stream>>>(x, g1, be1, xn);

  // fused QKV: M=4096, N=3072, K=1024 -> 768 blocks (3/CU)
  gemm_bt<5><<<dim3(24, 32), 256, 0, stream>>>(
      xn, wqkvT, bq, bk, bv, qb, kb, vtb, NTOK, 3072, 1024, 1);

  // flash attention split-KV=2 (XCD-grouped 1-D grid) -> partials, then merge
  flash_attn2<<<512, 512, 0, stream>>>(qb, kb, vtb, mask, pctx0, pctx1, mlbuf);
  mergeAttn<<<4096, 256, 0, stream>>>(pctx0, pctx1, mlbuf, ctxb);

  // O-proj split-K=4 -> bf16 partials @ 24+8z MB (1024 blocks)
  gemm_bt<7><<<dim3(8, 32, 4), 256, 0, stream>>>(
      ctxb, woT, nullptr, nullptr, nullptr, ws + 24 * MB, nullptr, nullptr,
      NTOK, 1024, 1024, 4);

  // fused reduce4 + LN2 -> h1 (f32) and h2 (bf16)
  reduce4_ln<<<2048, 256, 0, stream>>>((__hip_bfloat16*)(ws + 24 * MB),
                                       (__hip_bfloat16*)(ws + 32 * MB),
                                       (__hip_bfloat16*)(ws + 40 * MB),
                                       (__hip_bfloat16*)(ws + 48 * MB),
                                       x, bo, g2, be2, h1, h2);

  // FF1 + fast gelu: M=4096, N=4096, K=1024 -> 1024 blocks
  gemm_bt<1><<<dim3(32, 32), 256, 0, stream>>>(
      h2, w1T, b1, nullptr, nullptr, a1, nullptr, nullptr, NTOK, FFD, 1024, 1);

  // FF2 split-K=3 -> bf16 partials @ 0/8/24 MB (768 blocks)
  gemm_bt<8><<<dim3(8, 32, 3), 256, 0, stream>>>(
      a1, w2T, nullptr, nullptr, nullptr, ws, nullptr, nullptr,
      NTOK, 1024, FFD, 3);

  reduce3<<<2048, 256, 0, stream>>>((__hip_bfloat16*)(ws + 0 * MB),
                                    (__hip_bfloat16*)(ws + 8 * MB),
                                    (__hip_bfloat16*)(ws + 24 * MB),
                                    h1, b2, (float*)d_out);
}

// Round 12
// 258.281 us; speedup vs baseline: 1.1145x; 1.0051x over previous
//
#include <hip/hip_runtime.h>
#include <hip/hip_bf16.h>
#include <math.h>

// Transformer layer: B=2 S=2048 D=1024 H=16 HD=64 FF=4096, fp32 I/O.
// Heavy GEMMs: 128x128 bf16 MFMA tiles, BK=64 double-buffered (64KB LDS,
// 2 blocks/CU), XOR-swizzled staging, stage-early single-barrier K-loop.
// Attention: flash split-KV=2 (128-reg cap, XCD-grouped) + merge. Fused LN2.

#define BB 2
#define SS 2048
#define DD 1024
#define HH 16
#define HDIM 64
#define FFD 4096
#define NTOK (BB*SS)
#define LOG2E 1.4426950408889634f

typedef __attribute__((ext_vector_type(8))) short bf16x8;
typedef __attribute__((ext_vector_type(4))) float f32x4;
typedef __attribute__((ext_vector_type(16))) float f32x16;
typedef __attribute__((ext_vector_type(4))) unsigned int u32x4;

#if __has_builtin(__builtin_amdgcn_exp2f)
#define EXP2(x) __builtin_amdgcn_exp2f(x)
#else
#define EXP2(x) exp2f(x)
#endif

__device__ __forceinline__ void gl_lds16(const void* g, void* l) {
  __builtin_amdgcn_global_load_lds(
      (const __attribute__((address_space(1))) unsigned int*)g,
      (__attribute__((address_space(3))) unsigned int*)l, 16, 0, 0);
}

// RNE float->bf16 bits (finite inputs only)
__device__ __forceinline__ short f2bf(float f) {
  unsigned int u = __builtin_bit_cast(unsigned int, f);
  unsigned int r = (u + 0x7fffu + ((u >> 16) & 1u)) >> 16;
  return (short)r;
}
__device__ __forceinline__ float bf2f(short s) {
  return __builtin_bit_cast(float, ((unsigned)(unsigned short)s) << 16);
}
// packed pair via HW cvt (RNE)
__device__ __forceinline__ unsigned pk2(float lo, float hi) {
  unsigned r;
  asm("v_cvt_pk_bf16_f32 %0, %1, %2" : "=v"(r) : "v"(lo), "v"(hi));
  return r;
}
// gelu, tanh form via exp2 (max dev vs erf-gelu ~3e-4)
__device__ __forceinline__ float gelu_fast(float v) {
  float v2 = v * v;
  float u = v * (0.7978845608028654f + 0.03567740814183427f * v2);
  float e = EXP2(u * 2.8853900817779268f);  // e^(2u)
  return v * (1.0f - 1.0f / (e + 1.0f));
}

// ---------------- transpose + fp32->bf16 convert: wt[n][k] = bf16(w[k][n]) ----
__global__ __launch_bounds__(256) void convT(const float* __restrict__ w,
                                             __hip_bfloat16* __restrict__ wt,
                                             int K, int N) {
  __shared__ float tile[32][33];
  int k0 = blockIdx.y * 32, n0 = blockIdx.x * 32;
  int tx = threadIdx.x & 31, ty = threadIdx.x >> 5;
#pragma unroll
  for (int i = 0; i < 4; ++i) {
    int r = ty + i * 8;
    tile[r][tx] = w[(size_t)(k0 + r) * N + n0 + tx];
  }
  __syncthreads();
#pragma unroll
  for (int i = 0; i < 4; ++i) {
    int r = ty + i * 8;
    wt[(size_t)(n0 + r) * K + k0 + tx] = __float2bfloat16(tile[tx][r]);
  }
}

// batched 1024x1024 transpose-convert: z selects {wq,wk,wv,wo} -> out + z*1Mi
__global__ __launch_bounds__(256) void convT4(const float* __restrict__ w0,
                                              const float* __restrict__ w1,
                                              const float* __restrict__ w2,
                                              const float* __restrict__ w3,
                                              __hip_bfloat16* __restrict__ out) {
  __shared__ float tile[32][33];
  int z = blockIdx.z;
  const float* w = (z == 0) ? w0 : (z == 1) ? w1 : (z == 2) ? w2 : w3;
  __hip_bfloat16* wt = out + (size_t)z * 1024 * 1024;
  int k0 = blockIdx.y * 32, n0 = blockIdx.x * 32;
  int tx = threadIdx.x & 31, ty = threadIdx.x >> 5;
#pragma unroll
  for (int i = 0; i < 4; ++i) {
    int r = ty + i * 8;
    tile[r][tx] = w[(size_t)(k0 + r) * 1024 + n0 + tx];
  }
  __syncthreads();
#pragma unroll
  for (int i = 0; i < 4; ++i) {
    int r = ty + i * 8;
    wt[(size_t)(n0 + r) * 1024 + k0 + tx] = __float2bfloat16(tile[tx][r]);
  }
}

// ---------------- LayerNorm (fp32 in -> bf16 out), one wave per row ----------
__global__ __launch_bounds__(256) void ln_bf16(const float* __restrict__ x,
                                               const float* __restrict__ g,
                                               const float* __restrict__ be,
                                               __hip_bfloat16* __restrict__ out) {
  int w = threadIdx.x >> 6, lane = threadIdx.x & 63;
  int row = blockIdx.x * 4 + w;
  const float* xr = x + (size_t)row * DD;
  float4 v[4];
  float sum = 0.f, sq = 0.f;
#pragma unroll
  for (int i = 0; i < 4; ++i) {
    v[i] = *(const float4*)(xr + lane * 4 + i * 256);
    sum += v[i].x + v[i].y + v[i].z + v[i].w;
    sq += v[i].x * v[i].x + v[i].y * v[i].y + v[i].z * v[i].z + v[i].w * v[i].w;
  }
#pragma unroll
  for (int off = 1; off < 64; off <<= 1) {
    sum += __shfl_xor(sum, off);
    sq += __shfl_xor(sq, off);
  }
  float mu = sum * (1.f / 1024.f);
  float var = sq * (1.f / 1024.f) - mu * mu;
  float rs = rsqrtf(var + 1e-12f);
  __hip_bfloat16* orow = out + (size_t)row * DD;
#pragma unroll
  for (int i = 0; i < 4; ++i) {
    int c = lane * 4 + i * 256;
    float4 gg = *(const float4*)(g + c);
    float4 bb = *(const float4*)(be + c);
    short4 o;
    o.x = f2bf((v[i].x - mu) * rs * gg.x + bb.x);
    o.y = f2bf((v[i].y - mu) * rs * gg.y + bb.y);
    o.z = f2bf((v[i].z - mu) * rs * gg.z + bb.z);
    o.w = f2bf((v[i].w - mu) * rs * gg.w + bb.w);
    *(short4*)((short*)orow + c) = o;
  }
}

// ---------------- GEMM: C[M,N] = A[M,K] (bf16) * BT[N,K]^T + epilogue --------
// 128x128 tile, BK=64, 4 waves, double-buffered 64KB LDS, ONE barrier/step:
//   prologue: stage(tile0 -> buf0); barrier.
//   iter s:   stage(tile s+1 -> buf^1); ds_read buf (XOR-swizzled); 32 MFMA;
//             barrier (drains next-tile loads after they flew under compute).
// [128][64]-bf16 rows are 128B = 32 banks, so reads are chunk-XOR-swizzled
// (chunk ^= row&7) with pre-swizzled GLOBAL source + linear LDS dest (T2).
// Epilogues bounce through LDS (272B-stride rows) for coalesced 16B stores.
// EPI 1: +bias, fast-gelu -> bf16                      [FF1]
// EPI 5: QKV fused (N=3072): Q,K +bias -> bf16; V +bias -> bf16 transposed
// EPI 7: raw -> bf16 partial @ C0 + z*4Mi elems        [O-proj split-K]
// EPI 8: raw -> bf16 partial @ C0 + {0,4Mi,12Mi} elems [FF2 split-K]
template <int EPI>
__global__ __launch_bounds__(256, 2) void gemm_bt(
    const __hip_bfloat16* __restrict__ A, const __hip_bfloat16* __restrict__ BT,
    const float* __restrict__ bA, const float* __restrict__ bB,
    const float* __restrict__ bC,
    void* __restrict__ C0, void* __restrict__ C1, void* __restrict__ C2,
    int M, int N, int K, int kSplit) {
  __shared__ __align__(16) char smem[65536];  // buf b: A@b*32768, B@+16384
  const int t = threadIdx.x, lane = t & 63, w = t >> 6;
  const int m0 = blockIdx.y * 128, n0 = blockIdx.x * 128;
  const int wm = (w >> 1) * 64, wn = (w & 1) * 64;
  const int row16 = lane & 15, grp = lane >> 4;
  const int c4 = t & 7, srow = t >> 3;
  f32x4 acc[4][4] = {};

  const int steps = K >> 6;
  const int z = blockIdx.z;
  const int sBeg = (z * steps) / kSplit, sEnd = ((z + 1) * steps) / kSplit;

  auto stage = [&](char* base, int s) {
    const int kt = s << 6;
#pragma unroll
    for (int j = 0; j < 4; ++j) {
      int r = srow + j * 32;
      int cc = (c4 ^ (r & 7)) * 8;
      gl_lds16(A + (size_t)(m0 + r) * K + kt + cc, base + r * 128 + c4 * 16);
      gl_lds16(BT + (size_t)(n0 + r) * K + kt + cc,
               base + 16384 + r * 128 + c4 * 16);
    }
  };

  stage(smem, sBeg);
  __syncthreads();

  for (int s = sBeg; s < sEnd; ++s) {
    const char* buf = smem + ((s - sBeg) & 1) * 32768;
    if (s + 1 < sEnd) stage(smem + ((s - sBeg + 1) & 1) * 32768, s + 1);
#pragma unroll
    for (int kc = 0; kc < 2; ++kc) {
      bf16x8 af[4], bfr[4];
#pragma unroll
      for (int f = 0; f < 4; ++f) {
        int ra = wm + f * 16 + row16;
        int rb = wn + f * 16 + row16;
        af[f] = *(const bf16x8*)(buf + ra * 128 + (((kc * 4 + grp) ^ (ra & 7)) << 4));
        bfr[f] = *(const bf16x8*)(buf + 16384 + rb * 128 + (((kc * 4 + grp) ^ (rb & 7)) << 4));
      }
#pragma unroll
      for (int mf = 0; mf < 4; ++mf)
#pragma unroll
        for (int nf = 0; nf < 4; ++nf)
          acc[mf][nf] =
              __builtin_amdgcn_mfma_f32_16x16x32_bf16(af[mf], bfr[nf], acc[mf][nf], 0, 0, 0);
    }
    __syncthreads();
  }

  // ---------------- V section of QKV: transposed bounce ----------------
  if constexpr (EPI == 5) {
    if (n0 >= 2048) {
#pragma unroll
      for (int nf = 0; nf < 4; ++nf) {
        int vloc = wn + nf * 16 + row16;           // local vr 0..127
        float bv = bC[n0 - 2048 + vloc];
#pragma unroll
        for (int mf = 0; mf < 4; ++mf) {
          int tloc = wm + mf * 16 + grp * 4;       // local token
          f32x4 a = acc[mf][nf];
          *(uint2*)(smem + vloc * 272 + tloc * 2) =
              make_uint2(pk2(a[0] + bv, a[1] + bv), pk2(a[2] + bv, a[3] + bv));
        }
      }
      __syncthreads();
      int vrBase = ((m0 >> 11) << 10) + (n0 - 2048);
      int mcol = m0 & 2047;
#pragma unroll
      for (int i = 0; i < 8; ++i) {
        int c = t + i * 256;
        int vr = c >> 4, tc = c & 15;
        u32x4 vv = *(const u32x4*)(smem + vr * 272 + tc * 16);
        *(u32x4*)((__hip_bfloat16*)C2 + (size_t)(vrBase + vr) * 2048 + mcol + tc * 8) = vv;
      }
      return;
    }
  }

  // ---------------- row-major bounce (EPI 1, 5-Q/K, 7, 8) ----------------
  __hip_bfloat16* outP = nullptr;
  int ldO = N, colB = n0;
  const float* bp = nullptr;
  if constexpr (EPI == 1) { outP = (__hip_bfloat16*)C0; bp = bA; }
  if constexpr (EPI == 5) {
    const bool isK = n0 >= 1024;
    outP = (__hip_bfloat16*)(isK ? C1 : C0);
    bp = isK ? bB : bA;
    ldO = 1024; colB = n0 & 1023;
  }
  if constexpr (EPI == 7) outP = (__hip_bfloat16*)C0 + (size_t)z * 4194304ull;
  if constexpr (EPI == 8)
    outP = (__hip_bfloat16*)C0 + ((z == 0) ? 0ull : ((z == 1) ? 4194304ull : 12582912ull));

#pragma unroll
  for (int nf = 0; nf < 4; ++nf) {
    int nn = wn + nf * 16 + row16;
    float bv = bp ? bp[colB + nn] : 0.f;
#pragma unroll
    for (int mf = 0; mf < 4; ++mf) {
      int mloc = wm + mf * 16 + grp * 4;
      f32x4 a = acc[mf][nf];
#pragma unroll
      for (int r = 0; r < 4; ++r) {
        float v = a[r] + bv;
        if constexpr (EPI == 1) v = gelu_fast(v);
        *(short*)(smem + (mloc + r) * 272 + nn * 2) = f2bf(v);
      }
    }
  }
  __syncthreads();
#pragma unroll
  for (int i = 0; i < 8; ++i) {
    int c = t + i * 256;
    int mmr = c >> 4, nc = c & 15;
    u32x4 vv = *(const u32x4*)(smem + mmr * 272 + nc * 16);
    *(u32x4*)(outP + (size_t)(m0 + mmr) * ldO + colB + nc * 8) = vv;
  }
}

// ---------------- FF2 split-K reduce: out = h1 + b2 + sum(3 partials) --------
__global__ __launch_bounds__(256) void reduce3(const __hip_bfloat16* __restrict__ p0,
                                               const __hip_bfloat16* __restrict__ p1,
                                               const __hip_bfloat16* __restrict__ p2,
                                               const float* __restrict__ h1,
                                               const float* __restrict__ b2,
                                               float* __restrict__ out) {
  int idx = (blockIdx.x * 256 + threadIdx.x) * 8;
  int n = idx & 1023;
  bf16x8 a = *(const bf16x8*)(p0 + idx);
  bf16x8 b = *(const bf16x8*)(p1 + idx);
  bf16x8 c = *(const bf16x8*)(p2 + idx);
  float4 hA = *(const float4*)(h1 + idx), hB = *(const float4*)(h1 + idx + 4);
  float4 bA = *(const float4*)(b2 + n), bB = *(const float4*)(b2 + n + 4);
  float o[8];
#pragma unroll
  for (int j = 0; j < 8; ++j) o[j] = bf2f(a[j]) + bf2f(b[j]) + bf2f(c[j]);
  float4 r0 = make_float4(o[0] + hA.x + bA.x, o[1] + hA.y + bA.y,
                          o[2] + hA.z + bA.z, o[3] + hA.w + bA.w);
  float4 r1 = make_float4(o[4] + hB.x + bB.x, o[5] + hB.y + bB.y,
                          o[6] + hB.z + bB.z, o[7] + hB.w + bB.w);
  *(float4*)(out + idx) = r0;
  *(float4*)(out + idx + 4) = r1;
}

// -------- fused O-proj reduce + LN2: h1 = x+bo+sum(4 partials); h2 = LN(h1) --
__global__ __launch_bounds__(256) void reduce4_ln(
    const __hip_bfloat16* __restrict__ p0, const __hip_bfloat16* __restrict__ p1,
    const __hip_bfloat16* __restrict__ p2, const __hip_bfloat16* __restrict__ p3,
    const float* __restrict__ x, const float* __restrict__ bo,
    const float* __restrict__ g, const float* __restrict__ be,
    float* __restrict__ h1, __hip_bfloat16* __restrict__ h2) {
  __shared__ float red[4][2];
  const int tid = threadIdx.x;
  const int rowHalf = tid >> 7, tloc = tid & 127, wv = tid >> 6;
  const size_t idx = ((size_t)blockIdx.x * 2 + rowHalf) * 1024 + tloc * 8;
  const int n = tloc * 8;
  bf16x8 a = *(const bf16x8*)(p0 + idx);
  bf16x8 b = *(const bf16x8*)(p1 + idx);
  bf16x8 c = *(const bf16x8*)(p2 + idx);
  bf16x8 d = *(const bf16x8*)(p3 + idx);
  float4 xA = *(const float4*)(x + idx), xB = *(const float4*)(x + idx + 4);
  float4 bA = *(const float4*)(bo + n), bB = *(const float4*)(bo + n + 4);
  float o[8];
#pragma unroll
  for (int j = 0; j < 8; ++j)
    o[j] = (bf2f(a[j]) + bf2f(b[j])) + (bf2f(c[j]) + bf2f(d[j]));
  o[0] += xA.x + bA.x; o[1] += xA.y + bA.y; o[2] += xA.z + bA.z; o[3] += xA.w + bA.w;
  o[4] += xB.x + bB.x; o[5] += xB.y + bB.y; o[6] += xB.z + bB.z; o[7] += xB.w + bB.w;
  *(float4*)(h1 + idx) = make_float4(o[0], o[1], o[2], o[3]);
  *(float4*)(h1 + idx + 4) = make_float4(o[4], o[5], o[6], o[7]);
  float s = 0.f, sq = 0.f;
#pragma unroll
  for (int j = 0; j < 8; ++j) { s += o[j]; sq += o[j] * o[j]; }
#pragma unroll
  for (int off = 1; off < 64; off <<= 1) {
    s += __shfl_xor(s, off);
    sq += __shfl_xor(sq, off);
  }
  if ((tid & 63) == 0) { red[wv][0] = s; red[wv][1] = sq; }
  __syncthreads();
  float S = red[rowHalf * 2][0] + red[rowHalf * 2 + 1][0];
  float SQ = red[rowHalf * 2][1] + red[rowHalf * 2 + 1][1];
  float mu = S * (1.f / 1024.f);
  float var = SQ * (1.f / 1024.f) - mu * mu;
  float rs = rsqrtf(var + 1e-12f);
  float4 gA = *(const float4*)(g + n), gB = *(const float4*)(g + n + 4);
  float4 eA = *(const float4*)(be + n), eB = *(const float4*)(be + n + 4);
  u32x4 pkd;
  pkd[0] = pk2((o[0] - mu) * rs * gA.x + eA.x, (o[1] - mu) * rs * gA.y + eA.y);
  pkd[1] = pk2((o[2] - mu) * rs * gA.z + eA.z, (o[3] - mu) * rs * gA.w + eA.w);
  pkd[2] = pk2((o[4] - mu) * rs * gB.x + eB.x, (o[5] - mu) * rs * gB.y + eB.y);
  pkd[3] = pk2((o[6] - mu) * rs * gB.z + eB.z, (o[7] - mu) * rs * gB.w + eB.w);
  *(u32x4*)((short*)h2 + idx) = pkd;
}

// ---------------- Flash attention, split-KV=2: partial ctx + (m,l) ----------
// 1-D grid of 512; i%8 groups one (bh,z)'s q0-blocks onto one XCD for K/V L2.
// launch_bounds(512,4): cap regs at 128/wave -> 16 waves/CU.
__global__ __launch_bounds__(512, 4) void flash_attn2(
    const __hip_bfloat16* __restrict__ Q,
    const __hip_bfloat16* __restrict__ Kg,
    const __hip_bfloat16* __restrict__ VTg,
    const float* __restrict__ mask,
    __hip_bfloat16* __restrict__ pctx0,
    __hip_bfloat16* __restrict__ pctx1,
    float2* __restrict__ ml) {
  __shared__ __align__(16) char lds[33280];
  const int t = threadIdx.x, lane = t & 63, w = t >> 6;
  const int l31 = lane & 31, hi = lane >> 5;
  const int i = blockIdx.x;
  const int xcd = i & 7, j = i >> 3;
  const int q0i = j & 7, pg = j >> 3;
  const int p = pg * 8 + xcd;
  const int bh = p >> 1, z = p & 1;
  const int q0 = q0i * 256;
  const int b = bh >> 4, h = bh & 15;
  const int kvBase = z * (SS / 2);
  __hip_bfloat16* pctx = z ? pctx1 : pctx0;
  const int qrow = q0 + w * 32 + l31;

  bf16x8 qf[4];
  {
    const __hip_bfloat16* qp = Q + ((size_t)(b * SS + qrow)) * DD + h * HDIM + hi * 8;
    qf[0] = *(const bf16x8*)(qp);
    qf[1] = *(const bf16x8*)(qp + 16);
    qf[2] = *(const bf16x8*)(qp + 32);
    qf[3] = *(const bf16x8*)(qp + 48);
  }
  f32x16 ctx0 = {}, ctx1 = {};
  float m = -1e30f, l = 0.f, mC = -1.44e30f;

  auto stage = [&](int buf, int kv0) {
    int r = t >> 3, c = t & 7;
    gl_lds16(Kg + ((size_t)(b * SS + kv0 + r)) * DD + h * HDIM + ((c ^ (r & 7)) * 8),
             lds + buf * 8192 + t * 16);
    gl_lds16(VTg + ((size_t)(bh * 64 + r)) * 2048 + kv0 + ((c ^ (r & 7)) * 8),
             lds + 16384 + buf * 8192 + t * 16);
    if (t < 64) *(float*)(lds + 32768 + buf * 256 + t * 4) = mask[b * SS + kv0 + t];
  };

  stage(0, kvBase);
  const int NIT = SS / 128;
  for (int it = 0; it < NIT; ++it) {
    __syncthreads();
    if (it + 1 < NIT) stage((it + 1) & 1, kvBase + (it + 1) * 64);
    const char* Kb = lds + (it & 1) * 8192;
    const char* Vb = lds + 16384 + (it & 1) * 8192;
    const float* mk = (const float*)(lds + 32768 + (it & 1) * 256);

    f32x16 s0 = {}, s1 = {};
#pragma unroll
    for (int kc = 0; kc < 4; ++kc) {
      int c = kc * 2 + hi;
      int r0 = l31, r1 = 32 + l31;
      bf16x8 ka0 = *(const bf16x8*)(Kb + r0 * 128 + ((c ^ (r0 & 7)) << 4));
      bf16x8 ka1 = *(const bf16x8*)(Kb + r1 * 128 + ((c ^ (r1 & 7)) << 4));
      s0 = __builtin_amdgcn_mfma_f32_32x32x16_bf16(ka0, qf[kc], s0, 0, 0, 0);
      s1 = __builtin_amdgcn_mfma_f32_32x32x16_bf16(ka1, qf[kc], s1, 0, 0, 0);
    }
#pragma unroll
    for (int g = 0; g < 4; ++g) {
      float4 mg0 = *(const float4*)(mk + g * 8 + hi * 4);
      float4 mg1 = *(const float4*)(mk + 32 + g * 8 + hi * 4);
      const float* m0p = (const float*)&mg0;
      const float* m1p = (const float*)&mg1;
#pragma unroll
      for (int i2 = 0; i2 < 4; ++i2) {
        s0[g * 4 + i2] = fmaf(s0[g * 4 + i2], 0.125f, m0p[i2]);
        s1[g * 4 + i2] = fmaf(s1[g * 4 + i2], 0.125f, m1p[i2]);
      }
    }
    float pmax;
    {
      f32x16 q8;
#pragma unroll
      for (int r = 0; r < 16; ++r) q8[r] = fmaxf(s0[r], s1[r]);
#pragma unroll
      for (int r = 0; r < 8; ++r) q8[r] = fmaxf(q8[r], q8[r + 8]);
#pragma unroll
      for (int r = 0; r < 4; ++r) q8[r] = fmaxf(q8[r], q8[r + 4]);
      pmax = fmaxf(fmaxf(q8[0], q8[1]), fmaxf(q8[2], q8[3]));
      pmax = fmaxf(pmax, __shfl_xor(pmax, 32));
    }
    if (__any(pmax > m + 8.0f)) {
      float mnew = fmaxf(m, pmax);
      float fac = EXP2((m - mnew) * LOG2E);
      l *= fac;
#pragma unroll
      for (int r = 0; r < 16; ++r) { ctx0[r] *= fac; ctx1[r] *= fac; }
      m = mnew;
      mC = m * LOG2E;
    }
    float rsA = 0.f, rsB = 0.f;
#pragma unroll
    for (int r = 0; r < 16; ++r) {
      s0[r] = EXP2(fmaf(s0[r], LOG2E, -mC));
      s1[r] = EXP2(fmaf(s1[r], LOG2E, -mC));
      rsA += s0[r];
      rsB += s1[r];
    }
    rsA += rsB;
    rsA += __shfl_xor(rsA, 32);
    l += rsA;

    unsigned W0[8], W1[8];
#pragma unroll
    for (int g = 0; g < 4; ++g) {
      W0[g * 2] = pk2(s0[g * 4 + 0], s0[g * 4 + 1]);
      W0[g * 2 + 1] = pk2(s0[g * 4 + 2], s0[g * 4 + 3]);
      W1[g * 2] = pk2(s1[g * 4 + 0], s1[g * 4 + 1]);
      W1[g * 2 + 1] = pk2(s1[g * 4 + 2], s1[g * 4 + 3]);
    }
    unsigned swA0 = __shfl_xor(hi ? W0[0] : W0[2], 32);
    unsigned swA1 = __shfl_xor(hi ? W0[1] : W0[3], 32);
    unsigned swB0 = __shfl_xor(hi ? W0[4] : W0[6], 32);
    unsigned swB1 = __shfl_xor(hi ? W0[5] : W0[7], 32);
    unsigned swC0 = __shfl_xor(hi ? W1[0] : W1[2], 32);
    unsigned swC1 = __shfl_xor(hi ? W1[1] : W1[3], 32);
    unsigned swD0 = __shfl_xor(hi ? W1[4] : W1[6], 32);
    unsigned swD1 = __shfl_xor(hi ? W1[5] : W1[7], 32);
    u32x4 pb[4];
    pb[0] = hi ? (u32x4){swA0, swA1, W0[2], W0[3]} : (u32x4){W0[0], W0[1], swA0, swA1};
    pb[1] = hi ? (u32x4){swB0, swB1, W0[6], W0[7]} : (u32x4){W0[4], W0[5], swB0, swB1};
    pb[2] = hi ? (u32x4){swC0, swC1, W1[2], W1[3]} : (u32x4){W1[0], W1[1], swC0, swC1};
    pb[3] = hi ? (u32x4){swD0, swD1, W1[6], W1[7]} : (u32x4){W1[4], W1[5], swD0, swD1};

#pragma unroll
    for (int kc = 0; kc < 4; ++kc) {
      bf16x8 pbf = __builtin_bit_cast(bf16x8, pb[kc]);
      int c = kc * 2 + hi;
      int r0 = l31, r1 = 32 + l31;
      bf16x8 va0 = *(const bf16x8*)(Vb + r0 * 128 + ((c ^ (r0 & 7)) << 4));
      bf16x8 va1 = *(const bf16x8*)(Vb + r1 * 128 + ((c ^ (r1 & 7)) << 4));
      ctx0 = __builtin_amdgcn_mfma_f32_32x32x16_bf16(va0, pbf, ctx0, 0, 0, 0);
      ctx1 = __builtin_amdgcn_mfma_f32_32x32x16_bf16(va1, pbf, ctx1, 0, 0, 0);
    }
  }

  if (hi == 0) ml[((size_t)z * NTOK + b * SS + qrow) * HH + h] = make_float2(m, l);

  __syncthreads();
  {
    int row = w * 32 + l31;
#pragma unroll
    for (int dt = 0; dt < 2; ++dt) {
#pragma unroll
      for (int g = 0; g < 4; ++g) {
        unsigned lo2 = dt ? pk2(ctx1[g * 4 + 0], ctx1[g * 4 + 1]) : pk2(ctx0[g * 4 + 0], ctx0[g * 4 + 1]);
        unsigned hi2 = dt ? pk2(ctx1[g * 4 + 2], ctx1[g * 4 + 3]) : pk2(ctx0[g * 4 + 2], ctx0[g * 4 + 3]);
        int c = dt * 4 + g;
        *(uint2*)(lds + row * 128 + ((c ^ (row & 7)) << 4) + hi * 8) = make_uint2(lo2, hi2);
      }
    }
  }
  __syncthreads();
  {
    int r = t >> 1;
    size_t tok = (size_t)(b * SS + q0 + r);
#pragma unroll
    for (int i2 = 0; i2 < 4; ++i2) {
      int c = (t & 1) * 4 + i2;
      u32x4 vv = *(const u32x4*)(lds + r * 128 + ((c ^ (r & 7)) << 4));
      *(u32x4*)((short*)pctx + tok * DD + h * HDIM + c * 8) = vv;
    }
  }
}

// ---------------- merge two KV-half partials -> ctxb (bf16) ------------------
__global__ __launch_bounds__(256) void mergeAttn(
    const __hip_bfloat16* __restrict__ p0, const __hip_bfloat16* __restrict__ p1,
    const float2* __restrict__ ml, __hip_bfloat16* __restrict__ out) {
  int tok = blockIdx.x, tid = threadIdx.x;
  int h = tid >> 4;
  float2 a = ml[(size_t)tok * HH + h];
  float2 b = ml[(size_t)(NTOK + tok) * HH + h];
  float M = fmaxf(a.x, b.x);
  float w0 = EXP2((a.x - M) * LOG2E), w1 = EXP2((b.x - M) * LOG2E);
  float inv = 1.0f / (w0 * a.y + w1 * b.y);
  w0 *= inv; w1 *= inv;
  size_t idx = (size_t)tok * DD + tid * 4;
  short4 c0 = *(const short4*)((const short*)p0 + idx);
  short4 c1 = *(const short4*)((const short*)p1 + idx);
  unsigned lo = pk2(w0 * bf2f(c0.x) + w1 * bf2f(c1.x),
                    w0 * bf2f(c0.y) + w1 * bf2f(c1.y));
  unsigned hi2 = pk2(w0 * bf2f(c0.z) + w1 * bf2f(c1.z),
                     w0 * bf2f(c0.w) + w1 * bf2f(c1.w));
  *(uint2*)((short*)out + idx) = make_uint2(lo, hi2);
}

// ---------------- host-side orchestration ------------------------------------
extern "C" void kernel_launch(void* const* d_in, const int* in_sizes, int n_in,
                              void* d_out, int out_size, void* d_ws, size_t ws_size,
                              hipStream_t stream) {
  const float* x = (const float*)d_in[0];
  const float* mask = (const float*)d_in[1];
  const float* wq = (const float*)d_in[2];
  const float* bq = (const float*)d_in[3];
  const float* wk = (const float*)d_in[4];
  const float* bk = (const float*)d_in[5];
  const float* wv = (const float*)d_in[6];
  const float* bv = (const float*)d_in[7];
  const float* wo = (const float*)d_in[8];
  const float* bo = (const float*)d_in[9];
  const float* w1 = (const float*)d_in[10];
  const float* b1 = (const float*)d_in[11];
  const float* w2 = (const float*)d_in[12];
  const float* b2 = (const float*)d_in[13];
  const float* g1 = (const float*)d_in[14];
  const float* be1 = (const float*)d_in[15];
  const float* g2 = (const float*)d_in[16];
  const float* be2 = (const float*)d_in[17];

  char* ws = (char*)d_ws;
  const size_t MB = 1024ull * 1024ull;
  __hip_bfloat16* wqkvT = (__hip_bfloat16*)(ws + 0 * MB);
  __hip_bfloat16* woT = (__hip_bfloat16*)(ws + 6 * MB);
  __hip_bfloat16* w1T = (__hip_bfloat16*)(ws + 8 * MB);
  __hip_bfloat16* w2T = (__hip_bfloat16*)(ws + 16 * MB);
  __hip_bfloat16* xn = (__hip_bfloat16*)(ws + 24 * MB);     // later h2
  __hip_bfloat16* qb = (__hip_bfloat16*)(ws + 32 * MB);
  __hip_bfloat16* kb = (__hip_bfloat16*)(ws + 40 * MB);
  __hip_bfloat16* vtb = (__hip_bfloat16*)(ws + 48 * MB);    // V^T [32][64][2048]
  __hip_bfloat16* ctxb = (__hip_bfloat16*)(ws + 56 * MB);
  float* h1 = (float*)(ws + 64 * MB);
  __hip_bfloat16* h2 = xn;
  __hip_bfloat16* a1 = qb;
  __hip_bfloat16* pctx0 = (__hip_bfloat16*)(ws + 24 * MB);
  __hip_bfloat16* pctx1 = (__hip_bfloat16*)(ws + 64 * MB);
  float2* mlbuf = (float2*)(ws + 72 * MB);

  convT4<<<dim3(32, 32, 4), 256, 0, stream>>>(wq, wk, wv, wo, wqkvT);
  convT<<<dim3(128, 32), 256, 0, stream>>>(w1, w1T, 1024, 4096);
  convT<<<dim3(32, 128), 256, 0, stream>>>(w2, w2T, 4096, 1024);

  ln_bf16<<<1024, 256, 0, stream>>>(x, g1, be1, xn);

  // fused QKV: M=4096, N=3072, K=1024 -> 768 blocks
  gemm_bt<5><<<dim3(24, 32), 256, 0, stream>>>(
      xn, wqkvT, bq, bk, bv, qb, kb, vtb, NTOK, 3072, 1024, 1);

  // flash attention split-KV=2 (XCD-grouped 1-D grid) -> partials, then merge
  flash_attn2<<<512, 512, 0, stream>>>(qb, kb, vtb, mask, pctx0, pctx1, mlbuf);
  mergeAttn<<<4096, 256, 0, stream>>>(pctx0, pctx1, mlbuf, ctxb);

  // O-proj split-K=4 -> bf16 partials @ 24+8z MB (1024 blocks)
  gemm_bt<7><<<dim3(8, 32, 4), 256, 0, stream>>>(
      ctxb, woT, nullptr, nullptr, nullptr, ws + 24 * MB, nullptr, nullptr,
      NTOK, 1024, 1024, 4);

  // fused reduce4 + LN2 -> h1 (f32) and h2 (bf16)
  reduce4_ln<<<2048, 256, 0, stream>>>((__hip_bfloat16*)(ws + 24 * MB),
                                       (__hip_bfloat16*)(ws + 32 * MB),
                                       (__hip_bfloat16*)(ws + 40 * MB),
                                       (__hip_bfloat16*)(ws + 48 * MB),
                                       x, bo, g2, be2, h1, h2);

  // FF1 + fast gelu: M=4096, N=4096, K=1024 -> 1024 blocks
  gemm_bt<1><<<dim3(32, 32), 256, 0, stream>>>(
      h2, w1T, b1, nullptr, nullptr, a1, nullptr, nullptr, NTOK, FFD, 1024, 1);

  // FF2 split-K=3 -> bf16 partials @ 0/8/24 MB (768 blocks)
  gemm_bt<8><<<dim3(8, 32, 3), 256, 0, stream>>>(
      a1, w2T, nullptr, nullptr, nullptr, ws, nullptr, nullptr,
      NTOK, 1024, FFD, 3);

  reduce3<<<2048, 256, 0, stream>>>((__hip_bfloat16*)(ws + 0 * MB),
                                    (__hip_bfloat16*)(ws + 8 * MB),
                                    (__hip_bfloat16*)(ws + 24 * MB),
                                    h1, b2, (float*)d_out);
}